// Round 1
// 378.761 us; speedup vs baseline: 1.3625x; 1.3625x over previous
//
#include <hip/hip_runtime.h>
#include <hip/hip_bf16.h>

#define S_LEN 4096
#define D_MODEL 512
#define DKV 64
#define B_N 4
#define STR 72   // LDS row stride (elems) in attn kernel: 144 B = 16B-aligned, breaks 16-way bank conflicts

typedef __hip_bfloat16 bf16;
typedef __attribute__((ext_vector_type(8))) short short8;   // 8 bf16 (4 VGPRs)
typedef __attribute__((ext_vector_type(4))) float floatx4;  // MFMA C/D

#define MFMA(a, b, c) __builtin_amdgcn_mfma_f32_16x16x32_bf16(a, b, c, 0, 0, 0)

__device__ __forceinline__ float b2f(bf16 v) { return __bfloat162float(v); }

__device__ __forceinline__ unsigned short f2bits(float v) {
    union { bf16 h; unsigned short u; } cv;
    cv.h = __float2bfloat16(v);
    return cv.u;
}
__device__ __forceinline__ float bits2f(unsigned short u) {
    union { bf16 h; unsigned short u; } cv;
    cv.u = u;
    return b2f(cv.h);
}

// ---------------------------------------------------------------------------
// Kernel 0: dtype detect (kept — it picked the right path).
// ---------------------------------------------------------------------------
__global__ __launch_bounds__(64) void detect_kernel(const void* x, int* flag) {
    const int lane = threadIdx.x;
    const bf16* xb = (const bf16*)x;
    int bad = 0;
    for (int k = lane; k < 4096; k += 64) {
        float v = fabsf(b2f(xb[2 * k]));
        if (!(v < 64.f)) bad++;
    }
    #pragma unroll
    for (int off = 32; off >= 1; off >>= 1) bad += __shfl_xor(bad, off);
    if (lane == 0) *flag = (bad > 100) ? 1 : 0;
}

// ---------------------------------------------------------------------------
// Kernel 1a: W prep — transpose Wq/Wk/Wv to Wt[c][k] (c in 0..191: Q|K|V) as
// bf16 hi/lo split; gather biases to fp32. 384 KB total, L2-resident after.
// ---------------------------------------------------------------------------
__global__ __launch_bounds__(512) void wprep_kernel(
    const void* __restrict__ Wq, const void* __restrict__ bq,
    const void* __restrict__ Wk, const void* __restrict__ bk,
    const void* __restrict__ Wv, const void* __restrict__ bv,
    bf16* __restrict__ Wth, bf16* __restrict__ Wtl, float* __restrict__ ball,
    const int* __restrict__ flag)
{
    const int c = blockIdx.x;          // 0..191 output column
    const int d = threadIdx.x;         // 0..511 reduction dim
    const int g = c >> 6;              // 0=Q 1=K 2=V
    const int cc = c & 63;
    const void* W    = (g == 0) ? Wq : (g == 1) ? Wk : Wv;
    const void* bias = (g == 0) ? bq : (g == 1) ? bk : bv;
    const int f32 = *flag;

    const float v = f32 ? ((const float*)W)[d * DKV + cc]
                        : b2f(((const bf16*)W)[d * DKV + cc]);
    const unsigned short hb = f2bits(v);
    Wth[c * D_MODEL + d] = *(const bf16*)&hb;
    const unsigned short lb = f2bits(v - bits2f(hb));
    Wtl[c * D_MODEL + d] = *(const bf16*)&lb;
    if (d == 0)
        ball[c] = f32 ? ((const float*)bias)[cc] : b2f(((const bf16*)bias)[cc]);
}

// ---------------------------------------------------------------------------
// Kernel 1b: fused QKV projection as MFMA GEMM with bf16 hi/lo split.
// 256 blocks x 4 waves; block stages 64x512 x-tile to LDS (hi/lo, XOR-swizzled
// 16B slots). Wave w computes rows [w*16, w*16+16) x all 192 cols:
// 12 C-tiles x 16 k-steps x 3 split-terms = 576 MFMAs/wave.
// Frag layout (same as attn, verified): A[m=lane&15][k=quad*8+j];
// B[k=quad*8+j][n=lane&15]; C/D col=lane&15, row=quad*4+reg.
// ---------------------------------------------------------------------------
__global__ __launch_bounds__(256) void qkv_mfma(
    const void* __restrict__ x,
    const bf16* __restrict__ Wth, const bf16* __restrict__ Wtl,
    const float* __restrict__ ball,
    bf16* __restrict__ Qb, bf16* __restrict__ Kb, bf16* __restrict__ Vt,
    const int* __restrict__ flag)
{
    __shared__ unsigned short hiA[64 * D_MODEL];   // 64 KB
    __shared__ unsigned short loA[64 * D_MODEL];   // 64 KB
    const int tid = threadIdx.x;
    const int rowBase = blockIdx.x * 64;
    const int f32 = *flag;

    union Pack8 { uint4 u; unsigned short s[8]; };

    // stage x tile: 8-elem chunks, swizzle byte ^= (row&7)<<4 within each row
    if (f32) {
        const float* xr = (const float*)x + (size_t)rowBase * D_MODEL;
        #pragma unroll
        for (int i = 0; i < 16; ++i) {
            const int idx = tid + 256 * i;       // chunk id, 8 elems each
            const int r = idx >> 6;              // 64 chunks per row
            const int c0 = (idx & 63) << 3;
            const float4 v0 = *(const float4*)&xr[r * D_MODEL + c0];
            const float4 v1 = *(const float4*)&xr[r * D_MODEL + c0 + 4];
            const float vv[8] = {v0.x, v0.y, v0.z, v0.w, v1.x, v1.y, v1.z, v1.w};
            Pack8 ph, pl;
            #pragma unroll
            for (int j = 0; j < 8; ++j) {
                const unsigned short hb = f2bits(vv[j]);
                ph.s[j] = hb;
                pl.s[j] = f2bits(vv[j] - bits2f(hb));
            }
            const int boff = (c0 * 2) ^ ((r & 7) << 4);
            *(uint4*)((char*)hiA + r * 1024 + boff) = ph.u;
            *(uint4*)((char*)loA + r * 1024 + boff) = pl.u;
        }
    } else {
        const unsigned short* xr = (const unsigned short*)x + (size_t)rowBase * D_MODEL;
        const uint4 z = {0u, 0u, 0u, 0u};
        #pragma unroll
        for (int i = 0; i < 16; ++i) {
            const int idx = tid + 256 * i;
            const int r = idx >> 6;
            const int c0 = (idx & 63) << 3;
            const uint4 hv = *(const uint4*)&xr[r * D_MODEL + c0];
            const int boff = (c0 * 2) ^ ((r & 7) << 4);
            *(uint4*)((char*)hiA + r * 1024 + boff) = hv;
            *(uint4*)((char*)loA + r * 1024 + boff) = z;
        }
    }
    __syncthreads();

    const int lane = tid & 63;
    const int w    = tid >> 6;
    const int quad = lane >> 4;
    const int l15  = lane & 15;
    const int arow = w * 16 + l15;
    const char* hib = (const char*)hiA + arow * 1024;
    const char* lob = (const char*)loA + arow * 1024;
    const int swz = (arow & 7) << 4;

    floatx4 acc[12];
    #pragma unroll
    for (int ct = 0; ct < 12; ++ct) acc[ct] = (floatx4){0.f, 0.f, 0.f, 0.f};

    const int wofs = l15 * D_MODEL + quad * 8;   // per-lane base into Wt[c][k]

    for (int kt = 0; kt < 16; ++kt) {
        const int boff = (kt * 64 + quad * 16) ^ swz;   // byte offset in row
        const short8 ah = *(const short8*)(hib + boff);
        const short8 al = *(const short8*)(lob + boff);
        const bf16* wh = Wth + wofs + kt * 32;
        const bf16* wl = Wtl + wofs + kt * 32;
        #pragma unroll
        for (int ct = 0; ct < 12; ++ct) {
            const short8 bh = *(const short8*)(wh + ct * 16 * D_MODEL);
            const short8 bl = *(const short8*)(wl + ct * 16 * D_MODEL);
            acc[ct] = MFMA(ah, bh, acc[ct]);
            acc[ct] = MFMA(ah, bl, acc[ct]);
            acc[ct] = MFMA(al, bh, acc[ct]);
        }
    }

    // epilogue: + bias, round to bf16, scatter into Q / K / V^T layouts
    #pragma unroll
    for (int ct = 0; ct < 12; ++ct) {
        const int gc = ct * 16 + l15;            // 0..191
        const float bias = ball[gc];
        #pragma unroll
        for (int r = 0; r < 4; ++r) {
            const int gr = rowBase + w * 16 + quad * 4 + r;
            const bf16 o = __float2bfloat16(acc[ct][r] + bias);
            if (gc < 64)       Qb[(size_t)gr * DKV + gc] = o;
            else if (gc < 128) Kb[(size_t)gr * DKV + (gc - 64)] = o;
            else {
                const int bb = gr >> 12, s = gr & (S_LEN - 1);
                Vt[((size_t)bb * DKV + (gc - 128)) * S_LEN + s] = o;
            }
        }
    }
}

// ---------------------------------------------------------------------------
// Kernel 2: MFMA flash attention (unchanged). BM=32 Q-rows/block, 4 waves,
// BN=64 keys/iter.
// ---------------------------------------------------------------------------
__global__ __launch_bounds__(256) void attn_mfma(
    const bf16* __restrict__ Qg, const bf16* __restrict__ Kg,
    const bf16* __restrict__ Vtg, float* __restrict__ O)
{
    const int bid = blockIdx.x;
    const int b = bid >> 7;
    const int t = 127 - (bid & 127);     // longest tiles dispatch first
    const int rowBase = t * 32;
    const int tid = threadIdx.x;
    const int lane = tid & 63;
    const int w  = tid >> 6;
    const int wr = w & 1;
    const int wc = w >> 1;
    const int quad = lane >> 4;
    const int l15  = lane & 15;

    __shared__ bf16 Kl[64 * STR];        // [key][dim]
    __shared__ bf16 Vl[64 * STR];        // [vdim][key]
    __shared__ bf16 Pl[32 * STR];        // [row][key]; doubles as Q staging
    __shared__ float redm[2][32];
    __shared__ float reds[2][32];

    const bf16* Qb = Qg + ((size_t)b * S_LEN + rowBase) * DKV;
    const bf16* Kb = Kg + (size_t)b * S_LEN * DKV;
    const bf16* Vb = Vtg + (size_t)b * DKV * S_LEN;

    // stage Q tile (32x64) into Pl, load A-fragments once
    {
        const int r = tid >> 3, d0 = (tid & 7) * 8;
        *(uint4*)&Pl[r * STR + d0] = *(const uint4*)&Qb[r * DKV + d0];
    }
    __syncthreads();
    short8 qf0, qf1;
    {
        const int qoff = (wr * 16 + l15) * STR + quad * 8;
        qf0 = *(const short8*)&Pl[qoff];
        qf1 = *(const short8*)&Pl[qoff + 32];
    }

    floatx4 acc0 = {0.f, 0.f, 0.f, 0.f}, acc1 = {0.f, 0.f, 0.f, 0.f};
    float m_run[4], l_run[4];
    #pragma unroll
    for (int r = 0; r < 4; ++r) { m_run[r] = -1e30f; l_run[r] = 0.f; }

    const int ktMax = (rowBase + 31) >> 6;
    const float cs = 0.18033688f;        // 0.125 * log2(e): exp2 domain

    for (int kt = 0; kt <= ktMax; ++kt) {
        __syncthreads();                 // prior-iter LDS reads (and Q-frag reads) done
        {   // stage K tile + Vt tile (8 KB each), 2x16B per thread each
            const int kk = tid >> 2, d0 = (tid & 3) * 16;
            const uint4* ks = (const uint4*)&Kb[((size_t)(kt * 64 + kk)) * DKV + d0];
            uint4* kd = (uint4*)&Kl[kk * STR + d0];
            kd[0] = ks[0]; kd[1] = ks[1];
            const uint4* vs = (const uint4*)&Vb[(size_t)kk * S_LEN + kt * 64 + d0];
            uint4* vd = (uint4*)&Vl[kk * STR + d0];
            vd[0] = vs[0]; vd[1] = vs[1];
        }
        __syncthreads();

        // S = Q K^T : two 16x16 tiles per wave (K=64 over 2 MFMAs each)
        floatx4 s0 = {0.f, 0.f, 0.f, 0.f}, s1 = {0.f, 0.f, 0.f, 0.f};
        {
            const int qk = quad * 8;
            const int key0 = (wc * 32 + l15) * STR;
            const int key1 = key0 + 16 * STR;
            short8 b00 = *(const short8*)&Kl[key0 + qk];
            short8 b01 = *(const short8*)&Kl[key0 + qk + 32];
            short8 b10 = *(const short8*)&Kl[key1 + qk];
            short8 b11 = *(const short8*)&Kl[key1 + qk + 32];
            s0 = MFMA(qf0, b00, s0);
            s0 = MFMA(qf1, b01, s0);
            s1 = MFMA(qf0, b10, s1);
            s1 = MFMA(qf1, b11, s1);
        }
        #pragma unroll
        for (int r = 0; r < 4; ++r) { s0[r] *= cs; s1[r] *= cs; }
        if (kt == ktMax) {               // causal mask, uniform branch
            const int rowg = rowBase + wr * 16 + quad * 4;
            const int k0g = kt * 64 + wc * 32 + l15;
            #pragma unroll
            for (int r = 0; r < 4; ++r) {
                if (k0g > rowg + r)      s0[r] = -1e30f;
                if (k0g + 16 > rowg + r) s1[r] = -1e30f;
            }
        }
        // per-row max over this wave's 32 cols (16-lane butterfly)
        float m4[4];
        #pragma unroll
        for (int r = 0; r < 4; ++r) m4[r] = fmaxf(s0[r], s1[r]);
        #pragma unroll
        for (int off = 1; off < 16; off <<= 1) {
            #pragma unroll
            for (int r = 0; r < 4; ++r) m4[r] = fmaxf(m4[r], __shfl_xor(m4[r], off));
        }
        if (l15 == 0) {
            #pragma unroll
            for (int r = 0; r < 4; ++r) redm[wc][wr * 16 + quad * 4 + r] = m4[r];
        }
        __syncthreads();
        float alpha[4], mnew[4];
        #pragma unroll
        for (int r = 0; r < 4; ++r) {
            const int row = wr * 16 + quad * 4 + r;
            const float mm = fmaxf(redm[0][row], redm[1][row]);
            mnew[r] = fmaxf(m_run[r], mm);
            alpha[r] = exp2f(m_run[r] - mnew[r]);   // -1e30 first iter -> 0
            m_run[r] = mnew[r];
        }
        float ps[4];
        #pragma unroll
        for (int r = 0; r < 4; ++r) {
            const float p0 = exp2f(s0[r] - mnew[r]);
            const float p1 = exp2f(s1[r] - mnew[r]);
            s0[r] = p0; s1[r] = p1;
            ps[r] = p0 + p1;
        }
        #pragma unroll
        for (int off = 1; off < 16; off <<= 1) {
            #pragma unroll
            for (int r = 0; r < 4; ++r) ps[r] += __shfl_xor(ps[r], off);
        }
        if (l15 == 0) {
            #pragma unroll
            for (int r = 0; r < 4; ++r) reds[wc][wr * 16 + quad * 4 + r] = ps[r];
        }
        // rescale O-acc, write P (bf16) to LDS
        #pragma unroll
        for (int r = 0; r < 4; ++r) {
            acc0[r] *= alpha[r]; acc1[r] *= alpha[r];
            const int poff = (wr * 16 + quad * 4 + r) * STR + wc * 32 + l15;
            Pl[poff]      = __float2bfloat16(s0[r]);
            Pl[poff + 16] = __float2bfloat16(s1[r]);
        }
        __syncthreads();
        #pragma unroll
        for (int r = 0; r < 4; ++r) {
            const int row = wr * 16 + quad * 4 + r;
            l_run[r] = l_run[r] * alpha[r] + reds[0][row] + reds[1][row];
        }
        // O += P V : two 16x16 tiles per wave (K=64 keys over 2 MFMAs each)
        {
            const int pk = quad * 8;
            const int prow = (wr * 16 + l15) * STR;
            const int v0 = (wc * 32 + l15) * STR;
            const int v1 = v0 + 16 * STR;
            short8 pa0 = *(const short8*)&Pl[prow + pk];
            short8 pa1 = *(const short8*)&Pl[prow + pk + 32];
            short8 vb00 = *(const short8*)&Vl[v0 + pk];
            short8 vb01 = *(const short8*)&Vl[v0 + pk + 32];
            short8 vb10 = *(const short8*)&Vl[v1 + pk];
            short8 vb11 = *(const short8*)&Vl[v1 + pk + 32];
            acc0 = MFMA(pa0, vb00, acc0);
            acc0 = MFMA(pa1, vb01, acc0);
            acc1 = MFMA(pa0, vb10, acc1);
            acc1 = MFMA(pa1, vb11, acc1);
        }
    }
    // epilogue: normalize, store fp32 O[row][vdim]
    #pragma unroll
    for (int r = 0; r < 4; ++r) {
        const float inv = 1.0f / l_run[r];
        const int row = rowBase + wr * 16 + quad * 4 + r;
        float* op = O + ((size_t)b * S_LEN + row) * DKV + wc * 32 + l15;
        op[0]  = acc0[r] * inv;
        op[16] = acc1[r] * inv;
    }
}

// ---------------------------------------------------------------------------
// Kernel 3: output projection (16384 x 64) @ (64 x 512) + bias (unchanged).
// ---------------------------------------------------------------------------
__global__ __launch_bounds__(256) void proj_kernel(
    const float* __restrict__ A, const void* __restrict__ Wo,
    const void* __restrict__ bo, void* __restrict__ out,
    const int* __restrict__ flag)
{
    const int row = blockIdx.x;
    const int tid = threadIdx.x;
    const int f32 = *flag;
    __shared__ float as[DKV];
    if (tid < DKV) as[tid] = A[(size_t)row * DKV + tid];
    __syncthreads();

    if (f32) {
        const float* Wf = (const float*)Wo;
        #pragma unroll
        for (int rep = 0; rep < 2; ++rep) {
            const int o = rep * 256 + tid;
            float sum = 0.f;
            #pragma unroll 8
            for (int v = 0; v < DKV; ++v) sum += as[v] * Wf[v * D_MODEL + o];
            sum += ((const float*)bo)[o];
            ((float*)out)[(size_t)row * D_MODEL + o] = sum;
        }
    } else {
        const bf16* Wb = (const bf16*)Wo;
        #pragma unroll
        for (int rep = 0; rep < 2; ++rep) {
            const int o = rep * 256 + tid;
            float sum = 0.f;
            #pragma unroll 8
            for (int v = 0; v < DKV; ++v) sum += as[v] * b2f(Wb[v * D_MODEL + o]);
            sum += b2f(((const bf16*)bo)[o]);
            ((bf16*)out)[(size_t)row * D_MODEL + o] = __float2bfloat16(sum);
        }
    }
}

extern "C" void kernel_launch(void* const* d_in, const int* in_sizes, int n_in,
                              void* d_out, int out_size, void* d_ws, size_t ws_size,
                              hipStream_t stream) {
    const void* x  = d_in[0];
    const void* Wq = d_in[1];
    const void* bq = d_in[2];
    const void* Wk = d_in[3];
    const void* bk = d_in[4];
    const void* Wv = d_in[5];
    const void* bv = d_in[6];
    const void* Wo = d_in[7];
    const void* bo = d_in[8];

    const int rows = B_N * S_LEN;                 // 16384
    int*  flag = (int*)d_ws;
    bf16* Qb = (bf16*)((char*)d_ws + 256);        // 2 MB each
    bf16* Kb = Qb + (size_t)rows * DKV;
    bf16* Vt = Kb + (size_t)rows * DKV;
    float* Oa = (float*)(Vt + (size_t)rows * DKV); // 4 MB fp32
    bf16* Wth = (bf16*)((char*)Oa + (size_t)rows * DKV * sizeof(float)); // 192 KB
    bf16* Wtl = Wth + 192 * D_MODEL;                                     // 192 KB
    float* ball = (float*)(Wtl + 192 * D_MODEL);                         // 768 B

    detect_kernel<<<1, 64, 0, stream>>>(x, flag);
    wprep_kernel<<<192, 512, 0, stream>>>(Wq, bq, Wk, bk, Wv, bv, Wth, Wtl, ball, flag);
    qkv_mfma<<<256, 256, 0, stream>>>(x, Wth, Wtl, ball, Qb, Kb, Vt, flag);
    attn_mfma<<<512, 256, 0, stream>>>(Qb, Kb, Vt, Oa);
    proj_kernel<<<rows, 256, 0, stream>>>(Oa, Wo, bo, d_out, flag);
}

// Round 2
// 250.301 us; speedup vs baseline: 2.0618x; 1.5132x over previous
//
#include <hip/hip_runtime.h>
#include <hip/hip_bf16.h>

#define S_LEN 4096
#define D_MODEL 512
#define DKV 64
#define B_N 4
#define STR 72   // LDS row stride (elems): 144 B = 16B-aligned, breaks 16-way bank conflicts

typedef __hip_bfloat16 bf16;
typedef __attribute__((ext_vector_type(8))) short short8;   // 8 bf16 (4 VGPRs)
typedef __attribute__((ext_vector_type(4))) float floatx4;  // MFMA C/D

#define MFMA(a, b, c) __builtin_amdgcn_mfma_f32_16x16x32_bf16(a, b, c, 0, 0, 0)

__device__ __forceinline__ float b2f(bf16 v) { return __bfloat162float(v); }

__device__ __forceinline__ unsigned short f2bits(float v) {
    union { bf16 h; unsigned short u; } cv;
    cv.h = __float2bfloat16(v);
    return cv.u;
}
__device__ __forceinline__ float bits2f(unsigned short u) {
    union { bf16 h; unsigned short u; } cv;
    cv.u = u;
    return b2f(cv.h);
}

// ---------------------------------------------------------------------------
// Kernel 0: dtype detect.
// ---------------------------------------------------------------------------
__global__ __launch_bounds__(64) void detect_kernel(const void* x, int* flag) {
    const int lane = threadIdx.x;
    const bf16* xb = (const bf16*)x;
    int bad = 0;
    for (int k = lane; k < 4096; k += 64) {
        float v = fabsf(b2f(xb[2 * k]));
        if (!(v < 64.f)) bad++;
    }
    #pragma unroll
    for (int off = 32; off >= 1; off >>= 1) bad += __shfl_xor(bad, off);
    if (lane == 0) *flag = (bad > 100) ? 1 : 0;
}

// ---------------------------------------------------------------------------
// Kernel 1a: W prep. Blocks 0..191: transpose Wq/Wk/Wv col c into Wt[c][k]
// (bf16 hi/lo) + bias gather. ALL blocks 0..511: transpose Wo col c into
// WoT[c][k] (bf16 hi/lo) + bo gather (threads 0..63 only).
// ---------------------------------------------------------------------------
__global__ __launch_bounds__(512) void wprep_kernel(
    const void* __restrict__ Wq, const void* __restrict__ bq,
    const void* __restrict__ Wk, const void* __restrict__ bk,
    const void* __restrict__ Wv, const void* __restrict__ bv,
    const void* __restrict__ Wo, const void* __restrict__ bo,
    bf16* __restrict__ Wth, bf16* __restrict__ Wtl, float* __restrict__ ball,
    bf16* __restrict__ WoTh, bf16* __restrict__ WoTl, float* __restrict__ ball2,
    const int* __restrict__ flag)
{
    const int c = blockIdx.x;
    const int tid = threadIdx.x;
    const int f32 = *flag;

    if (c < 192) {
        const int g = c >> 6;              // 0=Q 1=K 2=V
        const int cc = c & 63;
        const void* W    = (g == 0) ? Wq : (g == 1) ? Wk : Wv;
        const void* bias = (g == 0) ? bq : (g == 1) ? bk : bv;
        const int d = tid;
        const float v = f32 ? ((const float*)W)[d * DKV + cc]
                            : b2f(((const bf16*)W)[d * DKV + cc]);
        const unsigned short hb = f2bits(v);
        Wth[c * D_MODEL + d] = *(const bf16*)&hb;
        const unsigned short lb = f2bits(v - bits2f(hb));
        Wtl[c * D_MODEL + d] = *(const bf16*)&lb;
        if (d == 0)
            ball[c] = f32 ? ((const float*)bias)[cc] : b2f(((const bf16*)bias)[cc]);
    }
    if (tid < DKV) {                       // Wo is (DKV=64, D=512): Wo[k][c]
        const int k = tid;
        const float v = f32 ? ((const float*)Wo)[k * D_MODEL + c]
                            : b2f(((const bf16*)Wo)[k * D_MODEL + c]);
        const unsigned short hb = f2bits(v);
        WoTh[c * DKV + k] = *(const bf16*)&hb;
        const unsigned short lb = f2bits(v - bits2f(hb));
        WoTl[c * DKV + k] = *(const bf16*)&lb;
        if (k == 0)
            ball2[c] = f32 ? ((const float*)bo)[c] : b2f(((const bf16*)bo)[c]);
    }
}

// ---------------------------------------------------------------------------
// Kernel 1b: fused QKV projection as MFMA GEMM with bf16 hi/lo split.
// Q is pre-scaled by 0.125*log2(e) so attention skips the score scaling.
// ---------------------------------------------------------------------------
__global__ __launch_bounds__(256) void qkv_mfma(
    const void* __restrict__ x,
    const bf16* __restrict__ Wth, const bf16* __restrict__ Wtl,
    const float* __restrict__ ball,
    bf16* __restrict__ Qb, bf16* __restrict__ Kb, bf16* __restrict__ Vt,
    const int* __restrict__ flag)
{
    __shared__ unsigned short hiA[64 * D_MODEL];   // 64 KB
    __shared__ unsigned short loA[64 * D_MODEL];   // 64 KB
    const int tid = threadIdx.x;
    const int rowBase = blockIdx.x * 64;
    const int f32 = *flag;

    union Pack8 { uint4 u; unsigned short s[8]; };

    if (f32) {
        const float* xr = (const float*)x + (size_t)rowBase * D_MODEL;
        #pragma unroll
        for (int i = 0; i < 16; ++i) {
            const int idx = tid + 256 * i;
            const int r = idx >> 6;
            const int c0 = (idx & 63) << 3;
            const float4 v0 = *(const float4*)&xr[r * D_MODEL + c0];
            const float4 v1 = *(const float4*)&xr[r * D_MODEL + c0 + 4];
            const float vv[8] = {v0.x, v0.y, v0.z, v0.w, v1.x, v1.y, v1.z, v1.w};
            Pack8 ph, pl;
            #pragma unroll
            for (int j = 0; j < 8; ++j) {
                const unsigned short hb = f2bits(vv[j]);
                ph.s[j] = hb;
                pl.s[j] = f2bits(vv[j] - bits2f(hb));
            }
            const int boff = (c0 * 2) ^ ((r & 7) << 4);
            *(uint4*)((char*)hiA + r * 1024 + boff) = ph.u;
            *(uint4*)((char*)loA + r * 1024 + boff) = pl.u;
        }
    } else {
        const unsigned short* xr = (const unsigned short*)x + (size_t)rowBase * D_MODEL;
        const uint4 z = {0u, 0u, 0u, 0u};
        #pragma unroll
        for (int i = 0; i < 16; ++i) {
            const int idx = tid + 256 * i;
            const int r = idx >> 6;
            const int c0 = (idx & 63) << 3;
            const uint4 hv = *(const uint4*)&xr[r * D_MODEL + c0];
            const int boff = (c0 * 2) ^ ((r & 7) << 4);
            *(uint4*)((char*)hiA + r * 1024 + boff) = hv;
            *(uint4*)((char*)loA + r * 1024 + boff) = z;
        }
    }
    __syncthreads();

    const int lane = tid & 63;
    const int w    = tid >> 6;
    const int quad = lane >> 4;
    const int l15  = lane & 15;
    const int arow = w * 16 + l15;
    const char* hib = (const char*)hiA + arow * 1024;
    const char* lob = (const char*)loA + arow * 1024;
    const int swz = (arow & 7) << 4;

    floatx4 acc[12];
    #pragma unroll
    for (int ct = 0; ct < 12; ++ct) acc[ct] = (floatx4){0.f, 0.f, 0.f, 0.f};

    const int wofs = l15 * D_MODEL + quad * 8;

    for (int kt = 0; kt < 16; ++kt) {
        const int boff = (kt * 64 + quad * 16) ^ swz;
        const short8 ah = *(const short8*)(hib + boff);
        const short8 al = *(const short8*)(lob + boff);
        const bf16* wh = Wth + wofs + kt * 32;
        const bf16* wl = Wtl + wofs + kt * 32;
        #pragma unroll
        for (int ct = 0; ct < 12; ++ct) {
            const short8 bh = *(const short8*)(wh + ct * 16 * D_MODEL);
            const short8 bl = *(const short8*)(wl + ct * 16 * D_MODEL);
            acc[ct] = MFMA(ah, bh, acc[ct]);
            acc[ct] = MFMA(ah, bl, acc[ct]);
            acc[ct] = MFMA(al, bh, acc[ct]);
        }
    }

    #pragma unroll
    for (int ct = 0; ct < 12; ++ct) {
        const int gc = ct * 16 + l15;
        const float bias = ball[gc];
        const float scale = (ct < 4) ? 0.18033688f : 1.0f;  // 0.125*log2e on Q
        #pragma unroll
        for (int r = 0; r < 4; ++r) {
            const int gr = rowBase + w * 16 + quad * 4 + r;
            const bf16 o = __float2bfloat16((acc[ct][r] + bias) * scale);
            if (gc < 64)       Qb[(size_t)gr * DKV + gc] = o;
            else if (gc < 128) Kb[(size_t)gr * DKV + (gc - 64)] = o;
            else {
                const int bb = gr >> 12, s = gr & (S_LEN - 1);
                Vt[((size_t)bb * DKV + (gc - 128)) * S_LEN + s] = o;
            }
        }
    }
}

// ---------------------------------------------------------------------------
// Kernel 2: MFMA flash attention, split-K by parity. Grid 1024:
// xcd = bid&7 -> batch b = xcd>>1, parity kh = xcd&1 (XCD-local K/V/Q);
// j = bid>>3 -> t = 127-j (longest-first). Block processes key tiles
// kt in {kh, kh+2, ...} <= ktMax, emits unnormalized O + (m, l).
// Next-tile K/V prefetched into registers (T14) to hide L2 latency.
// ---------------------------------------------------------------------------
__global__ __launch_bounds__(256) void attn_mfma(
    const bf16* __restrict__ Qg, const bf16* __restrict__ Kg,
    const bf16* __restrict__ Vtg, float* __restrict__ Op,
    float* __restrict__ Mp, float* __restrict__ Lp)
{
    const int bid = blockIdx.x;
    const int xcd = bid & 7;
    const int b  = xcd >> 1;
    const int kh = xcd & 1;
    const int t  = 127 - (bid >> 3);
    const int rowBase = t * 32;
    const int tid = threadIdx.x;
    const int lane = tid & 63;
    const int w  = tid >> 6;
    const int wr = w & 1;
    const int wc = w >> 1;
    const int quad = lane >> 4;
    const int l15  = lane & 15;

    __shared__ bf16 Kl[64 * STR];        // [key][dim]
    __shared__ bf16 Vl[64 * STR];        // [vdim][key]
    __shared__ bf16 Pl[32 * STR];        // [row][key]; doubles as Q staging
    __shared__ float redm[2][32];
    __shared__ float reds[2][32];

    const bf16* Qb = Qg + ((size_t)b * S_LEN + rowBase) * DKV;
    const bf16* Kb = Kg + (size_t)b * S_LEN * DKV;
    const bf16* Vb = Vtg + (size_t)b * DKV * S_LEN;

    // stage Q tile (32x64) into Pl, load A-fragments once
    {
        const int r = tid >> 3, d0q = (tid & 7) * 8;
        *(uint4*)&Pl[r * STR + d0q] = *(const uint4*)&Qb[r * DKV + d0q];
    }
    __syncthreads();
    short8 qf0, qf1;
    {
        const int qoff = (wr * 16 + l15) * STR + quad * 8;
        qf0 = *(const short8*)&Pl[qoff];
        qf1 = *(const short8*)&Pl[qoff + 32];
    }

    floatx4 acc0 = {0.f, 0.f, 0.f, 0.f}, acc1 = {0.f, 0.f, 0.f, 0.f};
    float m_run[4], l_run[4];
    #pragma unroll
    for (int r = 0; r < 4; ++r) { m_run[r] = -1e30f; l_run[r] = 0.f; }

    const int ktMax = (rowBase + 31) >> 6;
    const int kk = tid >> 2, d0 = (tid & 3) * 16;   // staging slot

    // prefetch first tile into registers
    uint4 kr0, kr1, vr0, vr1;
    int kt = kh;
    if (kt <= ktMax) {
        const uint4* ks = (const uint4*)&Kb[((size_t)(kt * 64 + kk)) * DKV + d0];
        kr0 = ks[0]; kr1 = ks[1];
        const uint4* vs = (const uint4*)&Vb[(size_t)kk * S_LEN + kt * 64 + d0];
        vr0 = vs[0]; vr1 = vs[1];
    }

    for (; kt <= ktMax; kt += 2) {
        __syncthreads();                 // prior-iter LDS reads (and Q-frag reads) done
        {   // write staged regs -> LDS
            uint4* kd = (uint4*)&Kl[kk * STR + d0];
            kd[0] = kr0; kd[1] = kr1;
            uint4* vd = (uint4*)&Vl[kk * STR + d0];
            vd[0] = vr0; vd[1] = vr1;
        }
        __syncthreads();
        if (kt + 2 <= ktMax) {           // prefetch next tile (hidden under compute)
            const uint4* ks = (const uint4*)&Kb[((size_t)((kt + 2) * 64 + kk)) * DKV + d0];
            kr0 = ks[0]; kr1 = ks[1];
            const uint4* vs = (const uint4*)&Vb[(size_t)kk * S_LEN + (kt + 2) * 64 + d0];
            vr0 = vs[0]; vr1 = vs[1];
        }

        // S = Q K^T (Q pre-scaled): two 16x16 tiles per wave
        floatx4 s0 = {0.f, 0.f, 0.f, 0.f}, s1 = {0.f, 0.f, 0.f, 0.f};
        {
            const int qk = quad * 8;
            const int key0 = (wc * 32 + l15) * STR;
            const int key1 = key0 + 16 * STR;
            short8 b00 = *(const short8*)&Kl[key0 + qk];
            short8 b01 = *(const short8*)&Kl[key0 + qk + 32];
            short8 b10 = *(const short8*)&Kl[key1 + qk];
            short8 b11 = *(const short8*)&Kl[key1 + qk + 32];
            s0 = MFMA(qf0, b00, s0);
            s0 = MFMA(qf1, b01, s0);
            s1 = MFMA(qf0, b10, s1);
            s1 = MFMA(qf1, b11, s1);
        }
        if (kt == ktMax) {               // causal mask, uniform branch
            const int rowg = rowBase + wr * 16 + quad * 4;
            const int k0g = kt * 64 + wc * 32 + l15;
            #pragma unroll
            for (int r = 0; r < 4; ++r) {
                if (k0g > rowg + r)      s0[r] = -1e30f;
                if (k0g + 16 > rowg + r) s1[r] = -1e30f;
            }
        }
        // per-row max over this wave's 32 cols (16-lane butterfly)
        float m4[4];
        #pragma unroll
        for (int r = 0; r < 4; ++r) m4[r] = fmaxf(s0[r], s1[r]);
        #pragma unroll
        for (int off = 1; off < 16; off <<= 1) {
            #pragma unroll
            for (int r = 0; r < 4; ++r) m4[r] = fmaxf(m4[r], __shfl_xor(m4[r], off));
        }
        if (l15 == 0) {
            #pragma unroll
            for (int r = 0; r < 4; ++r) redm[wc][wr * 16 + quad * 4 + r] = m4[r];
        }
        __syncthreads();
        float alpha[4], mnew[4];
        #pragma unroll
        for (int r = 0; r < 4; ++r) {
            const int row = wr * 16 + quad * 4 + r;
            const float mm = fmaxf(redm[0][row], redm[1][row]);
            mnew[r] = fmaxf(m_run[r], mm);
            alpha[r] = exp2f(m_run[r] - mnew[r]);   // -1e30 first iter -> 0
            m_run[r] = mnew[r];
        }
        float ps[4];
        #pragma unroll
        for (int r = 0; r < 4; ++r) {
            const float p0 = exp2f(s0[r] - mnew[r]);
            const float p1 = exp2f(s1[r] - mnew[r]);
            s0[r] = p0; s1[r] = p1;
            ps[r] = p0 + p1;
        }
        #pragma unroll
        for (int off = 1; off < 16; off <<= 1) {
            #pragma unroll
            for (int r = 0; r < 4; ++r) ps[r] += __shfl_xor(ps[r], off);
        }
        if (l15 == 0) {
            #pragma unroll
            for (int r = 0; r < 4; ++r) reds[wc][wr * 16 + quad * 4 + r] = ps[r];
        }
        // rescale O-acc, write P (bf16) to LDS
        #pragma unroll
        for (int r = 0; r < 4; ++r) {
            acc0[r] *= alpha[r]; acc1[r] *= alpha[r];
            const int poff = (wr * 16 + quad * 4 + r) * STR + wc * 32 + l15;
            Pl[poff]      = __float2bfloat16(s0[r]);
            Pl[poff + 16] = __float2bfloat16(s1[r]);
        }
        __syncthreads();
        #pragma unroll
        for (int r = 0; r < 4; ++r) {
            const int row = wr * 16 + quad * 4 + r;
            l_run[r] = l_run[r] * alpha[r] + reds[0][row] + reds[1][row];
        }
        // O += P V
        {
            const int pk = quad * 8;
            const int prow = (wr * 16 + l15) * STR;
            const int v0 = (wc * 32 + l15) * STR;
            const int v1 = v0 + 16 * STR;
            short8 pa0 = *(const short8*)&Pl[prow + pk];
            short8 pa1 = *(const short8*)&Pl[prow + pk + 32];
            short8 vb00 = *(const short8*)&Vl[v0 + pk];
            short8 vb01 = *(const short8*)&Vl[v0 + pk + 32];
            short8 vb10 = *(const short8*)&Vl[v1 + pk];
            short8 vb11 = *(const short8*)&Vl[v1 + pk + 32];
            acc0 = MFMA(pa0, vb00, acc0);
            acc0 = MFMA(pa1, vb01, acc0);
            acc1 = MFMA(pa0, vb10, acc1);
            acc1 = MFMA(pa1, vb11, acc1);
        }
    }
    // epilogue: store unnormalized O + per-row (m, l)
    #pragma unroll
    for (int r = 0; r < 4; ++r) {
        const int row = rowBase + wr * 16 + quad * 4 + r;
        float* op = Op + (((size_t)kh * B_N + b) * S_LEN + row) * DKV + wc * 32 + l15;
        op[0]  = acc0[r];
        op[16] = acc1[r];
    }
    if (wc == 0 && l15 == 0) {
        #pragma unroll
        for (int r = 0; r < 4; ++r) {
            const int row = rowBase + wr * 16 + quad * 4 + r;
            const size_t mi = (size_t)kh * B_N * S_LEN + (size_t)b * S_LEN + row;
            Mp[mi] = m_run[r];
            Lp[mi] = l_run[r];
        }
    }
}

// ---------------------------------------------------------------------------
// Kernel 2b: merge the two split-K halves, normalize, emit O as bf16 hi/lo.
// ---------------------------------------------------------------------------
__global__ __launch_bounds__(256) void merge_kernel(
    const float* __restrict__ Op, const float* __restrict__ Mp,
    const float* __restrict__ Lp, bf16* __restrict__ Oh, bf16* __restrict__ Ol)
{
    const int row = blockIdx.x * 32 + (threadIdx.x >> 3);
    const int d0 = (threadIdx.x & 7) * 8;
    const size_t half = (size_t)B_N * S_LEN;

    const float m0 = Mp[row], m1 = Mp[half + row];
    const float l0 = Lp[row], l1 = Lp[half + row];
    const float m = fmaxf(m0, m1);
    const float w0 = exp2f(m0 - m), w1 = exp2f(m1 - m);
    const float inv = 1.0f / (l0 * w0 + l1 * w1);

    const float* p0 = Op + (size_t)row * DKV + d0;
    const float* p1 = Op + half * DKV + (size_t)row * DKV + d0;
    union Pack8 { uint4 u; unsigned short s[8]; };
    Pack8 ph, pl;
    #pragma unroll
    for (int j = 0; j < 8; ++j) {
        const float o = (p0[j] * w0 + p1[j] * w1) * inv;
        const unsigned short hb = f2bits(o);
        ph.s[j] = hb;
        pl.s[j] = f2bits(o - bits2f(hb));
    }
    *(uint4*)&Oh[(size_t)row * DKV + d0] = ph.u;
    *(uint4*)&Ol[(size_t)row * DKV + d0] = pl.u;
}

// ---------------------------------------------------------------------------
// Kernel 3: output projection as MFMA GEMM (16384 x 64) @ (64 x 512) + bias,
// bf16 hi/lo split on both operands (3-term). Block = 32 rows x 512 cols,
// 4 waves: wr=w&1 row-half, wcq=w>>1 col-half (256 cols, 16 tiles).
// ---------------------------------------------------------------------------
#define PSTR 72
__global__ __launch_bounds__(256) void proj_mfma(
    const bf16* __restrict__ Oh, const bf16* __restrict__ Ol,
    const bf16* __restrict__ WoTh, const bf16* __restrict__ WoTl,
    const float* __restrict__ ball2, void* __restrict__ out,
    const int* __restrict__ flag)
{
    __shared__ unsigned short Ah[32 * PSTR], Al[32 * PSTR];
    const int tid = threadIdx.x;
    const int rowBase = blockIdx.x * 32;
    const int f32 = *flag;

    {   // stage 32x64 A tile (hi/lo), one uint4 each per thread
        const int r = tid >> 3, c0 = (tid & 7) * 8;
        *(uint4*)&Ah[r * PSTR + c0] = *(const uint4*)&Oh[(size_t)(rowBase + r) * DKV + c0];
        *(uint4*)&Al[r * PSTR + c0] = *(const uint4*)&Ol[(size_t)(rowBase + r) * DKV + c0];
    }
    __syncthreads();

    const int lane = tid & 63;
    const int w    = tid >> 6;
    const int quad = lane >> 4;
    const int l15  = lane & 15;
    const int wr   = w & 1;
    const int wcq  = w >> 1;

    const int aoff = (wr * 16 + l15) * PSTR + quad * 8;
    const short8 ah0 = *(const short8*)&Ah[aoff];
    const short8 ah1 = *(const short8*)&Ah[aoff + 32];
    const short8 al0 = *(const short8*)&Al[aoff];
    const short8 al1 = *(const short8*)&Al[aoff + 32];

    floatx4 acc[16];
    #pragma unroll
    for (int ct = 0; ct < 16; ++ct) acc[ct] = (floatx4){0.f, 0.f, 0.f, 0.f};

    #pragma unroll
    for (int ct = 0; ct < 16; ++ct) {
        const size_t cb = (size_t)(wcq * 256 + ct * 16 + l15) * DKV + quad * 8;
        const short8 bh0 = *(const short8*)&WoTh[cb];
        const short8 bh1 = *(const short8*)&WoTh[cb + 32];
        const short8 bl0 = *(const short8*)&WoTl[cb];
        const short8 bl1 = *(const short8*)&WoTl[cb + 32];
        acc[ct] = MFMA(ah0, bh0, acc[ct]);
        acc[ct] = MFMA(ah1, bh1, acc[ct]);
        acc[ct] = MFMA(ah0, bl0, acc[ct]);
        acc[ct] = MFMA(ah1, bl1, acc[ct]);
        acc[ct] = MFMA(al0, bh0, acc[ct]);
        acc[ct] = MFMA(al1, bh1, acc[ct]);
    }

    if (f32) {
        float* outf = (float*)out;
        #pragma unroll
        for (int ct = 0; ct < 16; ++ct) {
            const int col = wcq * 256 + ct * 16 + l15;
            const float bias = ball2[col];
            #pragma unroll
            for (int r = 0; r < 4; ++r) {
                const int row = rowBase + wr * 16 + quad * 4 + r;
                outf[(size_t)row * D_MODEL + col] = acc[ct][r] + bias;
            }
        }
    } else {
        bf16* outb = (bf16*)out;
        #pragma unroll
        for (int ct = 0; ct < 16; ++ct) {
            const int col = wcq * 256 + ct * 16 + l15;
            const float bias = ball2[col];
            #pragma unroll
            for (int r = 0; r < 4; ++r) {
                const int row = rowBase + wr * 16 + quad * 4 + r;
                outb[(size_t)row * D_MODEL + col] = __float2bfloat16(acc[ct][r] + bias);
            }
        }
    }
}

extern "C" void kernel_launch(void* const* d_in, const int* in_sizes, int n_in,
                              void* d_out, int out_size, void* d_ws, size_t ws_size,
                              hipStream_t stream) {
    const void* x  = d_in[0];
    const void* Wq = d_in[1];
    const void* bq = d_in[2];
    const void* Wk = d_in[3];
    const void* bk = d_in[4];
    const void* Wv = d_in[5];
    const void* bv = d_in[6];
    const void* Wo = d_in[7];
    const void* bo = d_in[8];

    const int rows = B_N * S_LEN;                 // 16384
    char* p = (char*)d_ws;
    int*  flag = (int*)p;                          p += 256;
    bf16* Qb = (bf16*)p;                           p += (size_t)rows * DKV * 2;   // 2 MB
    bf16* Kb = (bf16*)p;                           p += (size_t)rows * DKV * 2;
    bf16* Vt = (bf16*)p;                           p += (size_t)rows * DKV * 2;
    bf16* Wth = (bf16*)p;                          p += 192 * D_MODEL * 2;
    bf16* Wtl = (bf16*)p;                          p += 192 * D_MODEL * 2;
    float* ball = (float*)p;                       p += 1024;
    bf16* WoTh = (bf16*)p;                         p += D_MODEL * DKV * 2;
    bf16* WoTl = (bf16*)p;                         p += D_MODEL * DKV * 2;
    float* ball2 = (float*)p;                      p += D_MODEL * 4;
    float* Op = (float*)p;                         p += (size_t)2 * rows * DKV * 4; // 8 MB
    float* Mp = (float*)p;                         p += (size_t)2 * rows * 4;
    float* Lp = (float*)p;                         p += (size_t)2 * rows * 4;
    bf16* Ohb = (bf16*)p;                          p += (size_t)rows * DKV * 2;
    bf16* Olb = (bf16*)p;                          p += (size_t)rows * DKV * 2;

    detect_kernel<<<1, 64, 0, stream>>>(x, flag);
    wprep_kernel<<<512, 512, 0, stream>>>(Wq, bq, Wk, bk, Wv, bv, Wo, bo,
                                          Wth, Wtl, ball, WoTh, WoTl, ball2, flag);
    qkv_mfma<<<256, 256, 0, stream>>>(x, Wth, Wtl, ball, Qb, Kb, Vt, flag);
    attn_mfma<<<1024, 256, 0, stream>>>(Qb, Kb, Vt, Op, Mp, Lp);
    merge_kernel<<<512, 256, 0, stream>>>(Op, Mp, Lp, Ohb, Olb);
    proj_mfma<<<512, 256, 0, stream>>>(Ohb, Olb, WoTh, WoTl, ball2, d_out, flag);
}

// Round 3
// 237.183 us; speedup vs baseline: 2.1758x; 1.0553x over previous
//
#include <hip/hip_runtime.h>
#include <hip/hip_bf16.h>

#define S_LEN 4096
#define D_MODEL 512
#define DKV 64
#define B_N 4
#define STR 72    // K-tile LDS row stride (elems)
#define VSTR 136  // V/P LDS row stride (elems), 128 keys + pad

typedef __hip_bfloat16 bf16;
typedef __attribute__((ext_vector_type(8))) short short8;   // 8 bf16 (4 VGPRs)
typedef __attribute__((ext_vector_type(4))) float floatx4;  // MFMA C/D

#define MFMA(a, b, c) __builtin_amdgcn_mfma_f32_16x16x32_bf16(a, b, c, 0, 0, 0)

__device__ __forceinline__ float b2f(bf16 v) { return __bfloat162float(v); }

__device__ __forceinline__ unsigned short f2bits(float v) {
    union { bf16 h; unsigned short u; } cv;
    cv.h = __float2bfloat16(v);
    return cv.u;
}
__device__ __forceinline__ float bits2f(unsigned short u) {
    union { bf16 h; unsigned short u; } cv;
    cv.u = u;
    return b2f(cv.h);
}

// ---------------------------------------------------------------------------
// Kernel 0: dtype detect (value-based; proven). flag=1 -> fp32 inputs.
// ---------------------------------------------------------------------------
__global__ __launch_bounds__(64) void detect_kernel(const void* x, int* flag) {
    const int lane = threadIdx.x;
    const bf16* xb = (const bf16*)x;
    int bad = 0;
    for (int k = lane; k < 4096; k += 64) {
        float v = fabsf(b2f(xb[2 * k]));
        if (!(v < 64.f)) bad++;
    }
    #pragma unroll
    for (int off = 32; off >= 1; off >>= 1) bad += __shfl_xor(bad, off);
    if (lane == 0) *flag = (bad > 100) ? 1 : 0;
}

// ---------------------------------------------------------------------------
// Kernel 1a: W prep. Blocks 0..191: transpose Wq/Wk/Wv col c into Wt[c][k]
// (bf16 hi/lo) + bias gather. ALL blocks: transpose Wo col c into WoT[c][k].
// In bf16 mode the lo parts are exact zeros (unused by bf16-path kernels).
// ---------------------------------------------------------------------------
__global__ __launch_bounds__(512) void wprep_kernel(
    const void* __restrict__ Wq, const void* __restrict__ bq,
    const void* __restrict__ Wk, const void* __restrict__ bk,
    const void* __restrict__ Wv, const void* __restrict__ bv,
    const void* __restrict__ Wo, const void* __restrict__ bo,
    bf16* __restrict__ Wth, bf16* __restrict__ Wtl, float* __restrict__ ball,
    bf16* __restrict__ WoTh, bf16* __restrict__ WoTl, float* __restrict__ ball2,
    const int* __restrict__ flag)
{
    const int c = blockIdx.x;
    const int tid = threadIdx.x;
    const int f32 = *flag;

    if (c < 192) {
        const int g = c >> 6;              // 0=Q 1=K 2=V
        const int cc = c & 63;
        const void* W    = (g == 0) ? Wq : (g == 1) ? Wk : Wv;
        const void* bias = (g == 0) ? bq : (g == 1) ? bk : bv;
        const int d = tid;
        const float v = f32 ? ((const float*)W)[d * DKV + cc]
                            : b2f(((const bf16*)W)[d * DKV + cc]);
        const unsigned short hb = f2bits(v);
        Wth[c * D_MODEL + d] = *(const bf16*)&hb;
        const unsigned short lb = f2bits(v - bits2f(hb));
        Wtl[c * D_MODEL + d] = *(const bf16*)&lb;
        if (d == 0)
            ball[c] = f32 ? ((const float*)bias)[cc] : b2f(((const bf16*)bias)[cc]);
    }
    if (tid < DKV) {                       // Wo is (DKV=64, D=512): Wo[k][c]
        const int k = tid;
        const float v = f32 ? ((const float*)Wo)[k * D_MODEL + c]
                            : b2f(((const bf16*)Wo)[k * D_MODEL + c]);
        const unsigned short hb = f2bits(v);
        WoTh[c * DKV + k] = *(const bf16*)&hb;
        const unsigned short lb = f2bits(v - bits2f(hb));
        WoTl[c * DKV + k] = *(const bf16*)&lb;
        if (k == 0)
            ball2[c] = f32 ? ((const float*)bo)[c] : b2f(((const bf16*)bo)[c]);
    }
}

// ---------------------------------------------------------------------------
// Kernel 1b (bf16 path): QKV projection, single-term MFMA (x and W exact in
// bf16). 512 blocks x 32 rows; 32 KB LDS -> 2 blocks/CU. 4 waves =
// 2 row-halves x 2 col-halves (96 cols = 6 tiles each).
// Q pre-scaled by 0.125*log2(e).
// ---------------------------------------------------------------------------
__global__ __launch_bounds__(256) void qkv_mfma_bf16(
    const void* __restrict__ x,
    const bf16* __restrict__ Wth, const float* __restrict__ ball,
    bf16* __restrict__ Qb, bf16* __restrict__ Kb, bf16* __restrict__ Vt,
    const int* __restrict__ flag)
{
    if (*flag) return;
    __shared__ unsigned short hiA[32 * D_MODEL];   // 32 KB
    const int tid = threadIdx.x;
    const int rowBase = blockIdx.x * 32;

    const unsigned short* xr = (const unsigned short*)x + (size_t)rowBase * D_MODEL;
    #pragma unroll
    for (int i = 0; i < 8; ++i) {
        const int idx = tid + 256 * i;
        const int r = idx >> 6;
        const int c0 = (idx & 63) << 3;
        const uint4 hv = *(const uint4*)&xr[r * D_MODEL + c0];
        const int boff = (c0 * 2) ^ ((r & 7) << 4);
        *(uint4*)((char*)hiA + r * 1024 + boff) = hv;
    }
    __syncthreads();

    const int lane = tid & 63;
    const int w    = tid >> 6;
    const int quad = lane >> 4;
    const int l15  = lane & 15;
    const int wr   = w & 1;
    const int wcol = w >> 1;
    const int arow = wr * 16 + l15;
    const char* hib = (const char*)hiA + arow * 1024;
    const int swz = (arow & 7) << 4;

    floatx4 acc[6];
    #pragma unroll
    for (int ct = 0; ct < 6; ++ct) acc[ct] = (floatx4){0.f, 0.f, 0.f, 0.f};

    const bf16* wbase = Wth + (size_t)(wcol * 96 + l15) * D_MODEL + quad * 8;

    for (int kt = 0; kt < 16; ++kt) {
        const int boff = (kt * 64 + quad * 16) ^ swz;
        const short8 ah = *(const short8*)(hib + boff);
        const bf16* wk = wbase + kt * 32;
        #pragma unroll
        for (int ct = 0; ct < 6; ++ct) {
            const short8 bh = *(const short8*)(wk + (size_t)ct * 16 * D_MODEL);
            acc[ct] = MFMA(ah, bh, acc[ct]);
        }
    }

    #pragma unroll
    for (int ct = 0; ct < 6; ++ct) {
        const int gc = wcol * 96 + ct * 16 + l15;
        const float bias = ball[gc];
        const float scale = (gc < 64) ? 0.18033688f : 1.0f;
        #pragma unroll
        for (int r = 0; r < 4; ++r) {
            const int gr = rowBase + wr * 16 + quad * 4 + r;
            const bf16 o = __float2bfloat16((acc[ct][r] + bias) * scale);
            if (gc < 64)       Qb[(size_t)gr * DKV + gc] = o;
            else if (gc < 128) Kb[(size_t)gr * DKV + (gc - 64)] = o;
            else {
                const int bb = gr >> 12, sidx = gr & (S_LEN - 1);
                Vt[((size_t)bb * DKV + (gc - 128)) * S_LEN + sidx] = o;
            }
        }
    }
}

// ---------------------------------------------------------------------------
// Kernel 1b (fp32 fallback): 3-term hi/lo split, 64-row tiles, 128 KB LDS.
// ---------------------------------------------------------------------------
__global__ __launch_bounds__(256) void qkv_mfma_f32(
    const void* __restrict__ x,
    const bf16* __restrict__ Wth, const bf16* __restrict__ Wtl,
    const float* __restrict__ ball,
    bf16* __restrict__ Qb, bf16* __restrict__ Kb, bf16* __restrict__ Vt,
    const int* __restrict__ flag)
{
    if (!*flag) return;
    __shared__ unsigned short hiA[64 * D_MODEL];   // 64 KB
    __shared__ unsigned short loA[64 * D_MODEL];   // 64 KB
    const int tid = threadIdx.x;
    const int rowBase = blockIdx.x * 64;

    union Pack8 { uint4 u; unsigned short s[8]; };
    {
        const float* xr = (const float*)x + (size_t)rowBase * D_MODEL;
        #pragma unroll
        for (int i = 0; i < 16; ++i) {
            const int idx = tid + 256 * i;
            const int r = idx >> 6;
            const int c0 = (idx & 63) << 3;
            const float4 v0 = *(const float4*)&xr[r * D_MODEL + c0];
            const float4 v1 = *(const float4*)&xr[r * D_MODEL + c0 + 4];
            const float vv[8] = {v0.x, v0.y, v0.z, v0.w, v1.x, v1.y, v1.z, v1.w};
            Pack8 ph, pl;
            #pragma unroll
            for (int j = 0; j < 8; ++j) {
                const unsigned short hb = f2bits(vv[j]);
                ph.s[j] = hb;
                pl.s[j] = f2bits(vv[j] - bits2f(hb));
            }
            const int boff = (c0 * 2) ^ ((r & 7) << 4);
            *(uint4*)((char*)hiA + r * 1024 + boff) = ph.u;
            *(uint4*)((char*)loA + r * 1024 + boff) = pl.u;
        }
    }
    __syncthreads();

    const int lane = tid & 63;
    const int w    = tid >> 6;
    const int quad = lane >> 4;
    const int l15  = lane & 15;
    const int arow = w * 16 + l15;
    const char* hib = (const char*)hiA + arow * 1024;
    const char* lob = (const char*)loA + arow * 1024;
    const int swz = (arow & 7) << 4;

    floatx4 acc[12];
    #pragma unroll
    for (int ct = 0; ct < 12; ++ct) acc[ct] = (floatx4){0.f, 0.f, 0.f, 0.f};

    const int wofs = l15 * D_MODEL + quad * 8;

    for (int kt = 0; kt < 16; ++kt) {
        const int boff = (kt * 64 + quad * 16) ^ swz;
        const short8 ah = *(const short8*)(hib + boff);
        const short8 al = *(const short8*)(lob + boff);
        const bf16* wh = Wth + wofs + kt * 32;
        const bf16* wl = Wtl + wofs + kt * 32;
        #pragma unroll
        for (int ct = 0; ct < 12; ++ct) {
            const short8 bh = *(const short8*)(wh + ct * 16 * D_MODEL);
            const short8 bl = *(const short8*)(wl + ct * 16 * D_MODEL);
            acc[ct] = MFMA(ah, bh, acc[ct]);
            acc[ct] = MFMA(ah, bl, acc[ct]);
            acc[ct] = MFMA(al, bh, acc[ct]);
        }
    }

    #pragma unroll
    for (int ct = 0; ct < 12; ++ct) {
        const int gc = ct * 16 + l15;
        const float bias = ball[gc];
        const float scale = (gc < 64) ? 0.18033688f : 1.0f;
        #pragma unroll
        for (int r = 0; r < 4; ++r) {
            const int gr = rowBase + w * 16 + quad * 4 + r;
            const bf16 o = __float2bfloat16((acc[ct][r] + bias) * scale);
            if (gc < 64)       Qb[(size_t)gr * DKV + gc] = o;
            else if (gc < 128) Kb[(size_t)gr * DKV + (gc - 64)] = o;
            else {
                const int bb = gr >> 12, sidx = gr & (S_LEN - 1);
                Vt[((size_t)bb * DKV + (gc - 128)) * S_LEN + sidx] = o;
            }
        }
    }
}

// ---------------------------------------------------------------------------
// Kernel 2: MFMA flash attention, KVBLK=128, split-K by 128-tile parity.
// Grid 1024: xcd=bid&7 -> b=xcd>>1, kh=xcd&1; t=127-(bid>>3) longest-first.
// Per iter: 16 MFMAs/wave, 4 syncs, 2 butterfly reductions (vs 8/4 at KVB=64).
// Register prefetch of next K/V tile hides L2 latency.
// ---------------------------------------------------------------------------
__global__ __launch_bounds__(256, 3) void attn_mfma(
    const bf16* __restrict__ Qg, const bf16* __restrict__ Kg,
    const bf16* __restrict__ Vtg, float* __restrict__ Op,
    float* __restrict__ Mp, float* __restrict__ Lp)
{
    const int bid = blockIdx.x;
    const int xcd = bid & 7;
    const int b  = xcd >> 1;
    const int kh = xcd & 1;
    const int t  = 127 - (bid >> 3);
    const int rowBase = t * 32;
    const int tid = threadIdx.x;
    const int lane = tid & 63;
    const int w  = tid >> 6;
    const int wr = w & 1;
    const int wc = w >> 1;
    const int quad = lane >> 4;
    const int l15  = lane & 15;

    __shared__ bf16 Kl[128 * STR];       // [key][dim]     18.0 KB
    __shared__ bf16 Vl[64 * VSTR];       // [vdim][key]    17.0 KB
    __shared__ bf16 Pl[32 * VSTR];       // [row][key]      8.5 KB; Q staging
    __shared__ float redm[2][32];
    __shared__ float reds[2][32];

    const bf16* Qb = Qg + ((size_t)b * S_LEN + rowBase) * DKV;
    const bf16* Kb = Kg + (size_t)b * S_LEN * DKV;
    const bf16* Vb = Vtg + (size_t)b * DKV * S_LEN;

    // stage Q tile (32x64) into Pl, load A-fragments once
    {
        const int r = tid >> 3, d0q = (tid & 7) * 8;
        *(uint4*)&Pl[r * VSTR + d0q] = *(const uint4*)&Qb[r * DKV + d0q];
    }
    __syncthreads();
    short8 qf0, qf1;
    {
        const int qoff = (wr * 16 + l15) * VSTR + quad * 8;
        qf0 = *(const short8*)&Pl[qoff];
        qf1 = *(const short8*)&Pl[qoff + 32];
    }

    floatx4 acc0 = {0.f, 0.f, 0.f, 0.f}, acc1 = {0.f, 0.f, 0.f, 0.f};
    float m_run[4], l_run[4];
    #pragma unroll
    for (int r = 0; r < 4; ++r) { m_run[r] = -1e30f; l_run[r] = 0.f; }

    const int kbMax = (rowBase + 31) >> 7;
    const int kk = tid >> 1, dk = (tid & 1) * 32;   // K staging: 2 thr/row
    const int vd = tid >> 2, vk = (tid & 3) * 32;   // V staging: 4 thr/row

    uint4 kr0, kr1, kr2, kr3, vr0, vr1, vr2, vr3;
    int kb = kh;
    if (kb <= kbMax) {
        const uint4* ks = (const uint4*)&Kb[((size_t)(kb * 128 + kk)) * DKV + dk];
        kr0 = ks[0]; kr1 = ks[1]; kr2 = ks[2]; kr3 = ks[3];
        const uint4* vs = (const uint4*)&Vb[(size_t)vd * S_LEN + kb * 128 + vk];
        vr0 = vs[0]; vr1 = vs[1]; vr2 = vs[2]; vr3 = vs[3];
    }

    for (; kb <= kbMax; kb += 2) {
        __syncthreads();                 // prior-iter LDS reads done
        {
            uint4* kd = (uint4*)&Kl[kk * STR + dk];
            kd[0] = kr0; kd[1] = kr1; kd[2] = kr2; kd[3] = kr3;
            uint4* vdst = (uint4*)&Vl[vd * VSTR + vk];
            vdst[0] = vr0; vdst[1] = vr1; vdst[2] = vr2; vdst[3] = vr3;
        }
        __syncthreads();
        if (kb + 2 <= kbMax) {           // prefetch next tile under compute
            const uint4* ks = (const uint4*)&Kb[((size_t)((kb + 2) * 128 + kk)) * DKV + dk];
            kr0 = ks[0]; kr1 = ks[1]; kr2 = ks[2]; kr3 = ks[3];
            const uint4* vs = (const uint4*)&Vb[(size_t)vd * S_LEN + (kb + 2) * 128 + vk];
            vr0 = vs[0]; vr1 = vs[1]; vr2 = vs[2]; vr3 = vs[3];
        }

        // S = Q K^T (Q pre-scaled): four 16x16 key-tiles per wave
        floatx4 s[4];
        #pragma unroll
        for (int j = 0; j < 4; ++j) s[j] = (floatx4){0.f, 0.f, 0.f, 0.f};
        {
            const int qk = quad * 8;
            #pragma unroll
            for (int j = 0; j < 4; ++j) {
                const int kc = (wc * 64 + j * 16 + l15) * STR + qk;
                const short8 ba = *(const short8*)&Kl[kc];
                const short8 bb = *(const short8*)&Kl[kc + 32];
                s[j] = MFMA(qf0, ba, s[j]);
                s[j] = MFMA(qf1, bb, s[j]);
            }
        }
        if (kb == kbMax) {               // causal mask, uniform branch
            const int rowg = rowBase + wr * 16 + quad * 4;
            #pragma unroll
            for (int j = 0; j < 4; ++j) {
                const int kg = kb * 128 + wc * 64 + j * 16 + l15;
                #pragma unroll
                for (int r = 0; r < 4; ++r)
                    if (kg > rowg + r) s[j][r] = -1e30f;
            }
        }
        // per-row max over this wave's 64 cols (16-lane butterfly)
        float m4[4];
        #pragma unroll
        for (int r = 0; r < 4; ++r)
            m4[r] = fmaxf(fmaxf(s[0][r], s[1][r]), fmaxf(s[2][r], s[3][r]));
        #pragma unroll
        for (int off = 1; off < 16; off <<= 1) {
            #pragma unroll
            for (int r = 0; r < 4; ++r) m4[r] = fmaxf(m4[r], __shfl_xor(m4[r], off));
        }
        if (l15 == 0) {
            #pragma unroll
            for (int r = 0; r < 4; ++r) redm[wc][wr * 16 + quad * 4 + r] = m4[r];
        }
        __syncthreads();
        float alpha[4], mnew[4];
        #pragma unroll
        for (int r = 0; r < 4; ++r) {
            const int row = wr * 16 + quad * 4 + r;
            const float mm = fmaxf(redm[0][row], redm[1][row]);
            mnew[r] = fmaxf(m_run[r], mm);
            alpha[r] = exp2f(m_run[r] - mnew[r]);   // -1e30 first iter -> 0
            m_run[r] = mnew[r];
        }
        float ps[4];
        #pragma unroll
        for (int r = 0; r < 4; ++r) {
            float acc_ps = 0.f;
            #pragma unroll
            for (int j = 0; j < 4; ++j) {
                const float p = exp2f(s[j][r] - mnew[r]);
                s[j][r] = p;
                acc_ps += p;
            }
            ps[r] = acc_ps;
        }
        #pragma unroll
        for (int off = 1; off < 16; off <<= 1) {
            #pragma unroll
            for (int r = 0; r < 4; ++r) ps[r] += __shfl_xor(ps[r], off);
        }
        if (l15 == 0) {
            #pragma unroll
            for (int r = 0; r < 4; ++r) reds[wc][wr * 16 + quad * 4 + r] = ps[r];
        }
        // rescale O-acc, write P (bf16) to LDS
        #pragma unroll
        for (int r = 0; r < 4; ++r) {
            acc0[r] *= alpha[r]; acc1[r] *= alpha[r];
            const int poff = (wr * 16 + quad * 4 + r) * VSTR + wc * 64 + l15;
            Pl[poff]      = __float2bfloat16(s[0][r]);
            Pl[poff + 16] = __float2bfloat16(s[1][r]);
            Pl[poff + 32] = __float2bfloat16(s[2][r]);
            Pl[poff + 48] = __float2bfloat16(s[3][r]);
        }
        __syncthreads();
        #pragma unroll
        for (int r = 0; r < 4; ++r) {
            const int row = wr * 16 + quad * 4 + r;
            l_run[r] = l_run[r] * alpha[r] + reds[0][row] + reds[1][row];
        }
        // O += P V : K=128 keys over 4 chunks, two vdim-tiles per wave
        {
            const int pk = quad * 8;
            const int prow = (wr * 16 + l15) * VSTR;
            const int vrow0 = (wc * 32 + l15) * VSTR;
            const int vrow1 = vrow0 + 16 * VSTR;
            #pragma unroll
            for (int j = 0; j < 4; ++j) {
                const short8 pa  = *(const short8*)&Pl[prow + pk + j * 32];
                const short8 vb0 = *(const short8*)&Vl[vrow0 + pk + j * 32];
                const short8 vb1 = *(const short8*)&Vl[vrow1 + pk + j * 32];
                acc0 = MFMA(pa, vb0, acc0);
                acc1 = MFMA(pa, vb1, acc1);
            }
        }
    }
    // epilogue: store unnormalized O + per-row (m, l)
    #pragma unroll
    for (int r = 0; r < 4; ++r) {
        const int row = rowBase + wr * 16 + quad * 4 + r;
        float* op = Op + (((size_t)kh * B_N + b) * S_LEN + row) * DKV + wc * 32 + l15;
        op[0]  = acc0[r];
        op[16] = acc1[r];
    }
    if (wc == 0 && l15 == 0) {
        #pragma unroll
        for (int r = 0; r < 4; ++r) {
            const int row = rowBase + wr * 16 + quad * 4 + r;
            const size_t mi = (size_t)kh * B_N * S_LEN + (size_t)b * S_LEN + row;
            Mp[mi] = m_run[r];
            Lp[mi] = l_run[r];
        }
    }
}

// ---------------------------------------------------------------------------
// Kernel 2b: merge the two split-K halves, normalize, emit O as bf16 hi/lo.
// ---------------------------------------------------------------------------
__global__ __launch_bounds__(256) void merge_kernel(
    const float* __restrict__ Op, const float* __restrict__ Mp,
    const float* __restrict__ Lp, bf16* __restrict__ Oh, bf16* __restrict__ Ol)
{
    const int row = blockIdx.x * 32 + (threadIdx.x >> 3);
    const int d0 = (threadIdx.x & 7) * 8;
    const size_t half = (size_t)B_N * S_LEN;

    const float m0 = Mp[row], m1 = Mp[half + row];
    const float l0 = Lp[row], l1 = Lp[half + row];
    const float m = fmaxf(m0, m1);
    const float w0 = exp2f(m0 - m), w1 = exp2f(m1 - m);
    const float inv = 1.0f / (l0 * w0 + l1 * w1);

    const float* p0 = Op + (size_t)row * DKV + d0;
    const float* p1 = Op + half * DKV + (size_t)row * DKV + d0;
    union Pack8 { uint4 u; unsigned short s[8]; };
    Pack8 ph, pl;
    #pragma unroll
    for (int j = 0; j < 8; ++j) {
        const float o = (p0[j] * w0 + p1[j] * w1) * inv;
        const unsigned short hb = f2bits(o);
        ph.s[j] = hb;
        pl.s[j] = f2bits(o - bits2f(hb));
    }
    *(uint4*)&Oh[(size_t)row * DKV + d0] = ph.u;
    *(uint4*)&Ol[(size_t)row * DKV + d0] = pl.u;
}

// ---------------------------------------------------------------------------
// Kernel 3 (bf16 path): output projection, A hi/lo x W hi (W exact in bf16).
// 4 MFMAs/tile. bf16 output.
// ---------------------------------------------------------------------------
#define PSTR 72
__global__ __launch_bounds__(256) void proj_mfma_bf16(
    const bf16* __restrict__ Oh, const bf16* __restrict__ Ol,
    const bf16* __restrict__ WoTh, const float* __restrict__ ball2,
    bf16* __restrict__ out, const int* __restrict__ flag)
{
    if (*flag) return;
    __shared__ unsigned short Ah[32 * PSTR], Al[32 * PSTR];
    const int tid = threadIdx.x;
    const int rowBase = blockIdx.x * 32;

    {
        const int r = tid >> 3, c0 = (tid & 7) * 8;
        *(uint4*)&Ah[r * PSTR + c0] = *(const uint4*)&Oh[(size_t)(rowBase + r) * DKV + c0];
        *(uint4*)&Al[r * PSTR + c0] = *(const uint4*)&Ol[(size_t)(rowBase + r) * DKV + c0];
    }
    __syncthreads();

    const int lane = tid & 63;
    const int w    = tid >> 6;
    const int quad = lane >> 4;
    const int l15  = lane & 15;
    const int wr   = w & 1;
    const int wcq  = w >> 1;

    const int aoff = (wr * 16 + l15) * PSTR + quad * 8;
    const short8 ah0 = *(const short8*)&Ah[aoff];
    const short8 ah1 = *(const short8*)&Ah[aoff + 32];
    const short8 al0 = *(const short8*)&Al[aoff];
    const short8 al1 = *(const short8*)&Al[aoff + 32];

    floatx4 acc[16];
    #pragma unroll
    for (int ct = 0; ct < 16; ++ct) acc[ct] = (floatx4){0.f, 0.f, 0.f, 0.f};

    #pragma unroll
    for (int ct = 0; ct < 16; ++ct) {
        const size_t cb = (size_t)(wcq * 256 + ct * 16 + l15) * DKV + quad * 8;
        const short8 bh0 = *(const short8*)&WoTh[cb];
        const short8 bh1 = *(const short8*)&WoTh[cb + 32];
        acc[ct] = MFMA(ah0, bh0, acc[ct]);
        acc[ct] = MFMA(ah1, bh1, acc[ct]);
        acc[ct] = MFMA(al0, bh0, acc[ct]);
        acc[ct] = MFMA(al1, bh1, acc[ct]);
    }

    #pragma unroll
    for (int ct = 0; ct < 16; ++ct) {
        const int col = wcq * 256 + ct * 16 + l15;
        const float bias = ball2[col];
        #pragma unroll
        for (int r = 0; r < 4; ++r) {
            const int row = rowBase + wr * 16 + quad * 4 + r;
            out[(size_t)row * D_MODEL + col] = __float2bfloat16(acc[ct][r] + bias);
        }
    }
}

// ---------------------------------------------------------------------------
// Kernel 3 (fp32 fallback): 6-term hi/lo on both operands, fp32 output.
// ---------------------------------------------------------------------------
__global__ __launch_bounds__(256) void proj_mfma_f32(
    const bf16* __restrict__ Oh, const bf16* __restrict__ Ol,
    const bf16* __restrict__ WoTh, const bf16* __restrict__ WoTl,
    const float* __restrict__ ball2, float* __restrict__ out,
    const int* __restrict__ flag)
{
    if (!*flag) return;
    __shared__ unsigned short Ah[32 * PSTR], Al[32 * PSTR];
    const int tid = threadIdx.x;
    const int rowBase = blockIdx.x * 32;

    {
        const int r = tid >> 3, c0 = (tid & 7) * 8;
        *(uint4*)&Ah[r * PSTR + c0] = *(const uint4*)&Oh[(size_t)(rowBase + r) * DKV + c0];
        *(uint4*)&Al[r * PSTR + c0] = *(const uint4*)&Ol[(size_t)(rowBase + r) * DKV + c0];
    }
    __syncthreads();

    const int lane = tid & 63;
    const int w    = tid >> 6;
    const int quad = lane >> 4;
    const int l15  = lane & 15;
    const int wr   = w & 1;
    const int wcq  = w >> 1;

    const int aoff = (wr * 16 + l15) * PSTR + quad * 8;
    const short8 ah0 = *(const short8*)&Ah[aoff];
    const short8 ah1 = *(const short8*)&Ah[aoff + 32];
    const short8 al0 = *(const short8*)&Al[aoff];
    const short8 al1 = *(const short8*)&Al[aoff + 32];

    floatx4 acc[16];
    #pragma unroll
    for (int ct = 0; ct < 16; ++ct) acc[ct] = (floatx4){0.f, 0.f, 0.f, 0.f};

    #pragma unroll
    for (int ct = 0; ct < 16; ++ct) {
        const size_t cb = (size_t)(wcq * 256 + ct * 16 + l15) * DKV + quad * 8;
        const short8 bh0 = *(const short8*)&WoTh[cb];
        const short8 bh1 = *(const short8*)&WoTh[cb + 32];
        const short8 bl0 = *(const short8*)&WoTl[cb];
        const short8 bl1 = *(const short8*)&WoTl[cb + 32];
        acc[ct] = MFMA(ah0, bh0, acc[ct]);
        acc[ct] = MFMA(ah1, bh1, acc[ct]);
        acc[ct] = MFMA(ah0, bl0, acc[ct]);
        acc[ct] = MFMA(ah1, bl1, acc[ct]);
        acc[ct] = MFMA(al0, bh0, acc[ct]);
        acc[ct] = MFMA(al1, bh1, acc[ct]);
    }

    #pragma unroll
    for (int ct = 0; ct < 16; ++ct) {
        const int col = wcq * 256 + ct * 16 + l15;
        const float bias = ball2[col];
        #pragma unroll
        for (int r = 0; r < 4; ++r) {
            const int row = rowBase + wr * 16 + quad * 4 + r;
            out[(size_t)row * D_MODEL + col] = acc[ct][r] + bias;
        }
    }
}

extern "C" void kernel_launch(void* const* d_in, const int* in_sizes, int n_in,
                              void* d_out, int out_size, void* d_ws, size_t ws_size,
                              hipStream_t stream) {
    const void* x  = d_in[0];
    const void* Wq = d_in[1];
    const void* bq = d_in[2];
    const void* Wk = d_in[3];
    const void* bk = d_in[4];
    const void* Wv = d_in[5];
    const void* bv = d_in[6];
    const void* Wo = d_in[7];
    const void* bo = d_in[8];

    const int rows = B_N * S_LEN;                 // 16384
    char* p = (char*)d_ws;
    int*  flag = (int*)p;                          p += 256;
    bf16* Qb = (bf16*)p;                           p += (size_t)rows * DKV * 2;   // 2 MB
    bf16* Kb = (bf16*)p;                           p += (size_t)rows * DKV * 2;
    bf16* Vt = (bf16*)p;                           p += (size_t)rows * DKV * 2;
    bf16* Wth = (bf16*)p;                          p += 192 * D_MODEL * 2;
    bf16* Wtl = (bf16*)p;                          p += 192 * D_MODEL * 2;
    float* ball = (float*)p;                       p += 1024;
    bf16* WoTh = (bf16*)p;                         p += D_MODEL * DKV * 2;
    bf16* WoTl = (bf16*)p;                         p += D_MODEL * DKV * 2;
    float* ball2 = (float*)p;                      p += D_MODEL * 4;
    float* Op = (float*)p;                         p += (size_t)2 * rows * DKV * 4; // 8 MB
    float* Mp = (float*)p;                         p += (size_t)2 * rows * 4;
    float* Lp = (float*)p;                         p += (size_t)2 * rows * 4;
    bf16* Ohb = (bf16*)p;                          p += (size_t)rows * DKV * 2;
    bf16* Olb = (bf16*)p;                          p += (size_t)rows * DKV * 2;

    detect_kernel<<<1, 64, 0, stream>>>(x, flag);
    wprep_kernel<<<512, 512, 0, stream>>>(Wq, bq, Wk, bk, Wv, bv, Wo, bo,
                                          Wth, Wtl, ball, WoTh, WoTl, ball2, flag);
    qkv_mfma_bf16<<<512, 256, 0, stream>>>(x, Wth, ball, Qb, Kb, Vt, flag);
    qkv_mfma_f32<<<256, 256, 0, stream>>>(x, Wth, Wtl, ball, Qb, Kb, Vt, flag);
    attn_mfma<<<1024, 256, 0, stream>>>(Qb, Kb, Vt, Op, Mp, Lp);
    merge_kernel<<<512, 256, 0, stream>>>(Op, Mp, Lp, Ohb, Olb);
    proj_mfma_bf16<<<512, 256, 0, stream>>>(Ohb, Olb, WoTh, ball2, (bf16*)d_out, flag);
    proj_mfma_f32<<<512, 256, 0, stream>>>(Ohb, Olb, WoTh, WoTl, ball2, (float*)d_out, flag);
}

// Round 4
// 222.261 us; speedup vs baseline: 2.3219x; 1.0671x over previous
//
#include <hip/hip_runtime.h>
#include <hip/hip_bf16.h>

#define S_LEN 4096
#define D_MODEL 512
#define DKV 64
#define B_N 4
#define STR 72    // K-tile LDS row stride (elems)
#define VSTR 136  // V/P LDS row stride (elems), 128 keys + pad

typedef __hip_bfloat16 bf16;
typedef __attribute__((ext_vector_type(8))) short short8;   // 8 bf16 (4 VGPRs)
typedef __attribute__((ext_vector_type(4))) float floatx4;  // MFMA C/D

#define MFMA(a, b, c) __builtin_amdgcn_mfma_f32_16x16x32_bf16(a, b, c, 0, 0, 0)

__device__ __forceinline__ float b2f(bf16 v) { return __bfloat162float(v); }

__device__ __forceinline__ unsigned short f2bits(float v) {
    union { bf16 h; unsigned short u; } cv;
    cv.h = __float2bfloat16(v);
    return cv.u;
}
__device__ __forceinline__ float bits2f(unsigned short u) {
    union { bf16 h; unsigned short u; } cv;
    cv.u = u;
    return b2f(cv.h);
}

// ---------------------------------------------------------------------------
// Kernel 0: dtype detect (value-based; proven). flag=1 -> fp32 inputs.
// ---------------------------------------------------------------------------
__global__ __launch_bounds__(64) void detect_kernel(const void* x, int* flag) {
    const int lane = threadIdx.x;
    const bf16* xb = (const bf16*)x;
    int bad = 0;
    for (int k = lane; k < 4096; k += 64) {
        float v = fabsf(b2f(xb[2 * k]));
        if (!(v < 64.f)) bad++;
    }
    #pragma unroll
    for (int off = 32; off >= 1; off >>= 1) bad += __shfl_xor(bad, off);
    if (lane == 0) *flag = (bad > 100) ? 1 : 0;
}

// ---------------------------------------------------------------------------
// Kernel 1a: W prep. Blocks 0..191: transpose Wq/Wk/Wv col c into Wt[c][k]
// (bf16 hi/lo) + bias gather. ALL blocks: transpose Wo col c into WoT[c][k].
// ---------------------------------------------------------------------------
__global__ __launch_bounds__(512) void wprep_kernel(
    const void* __restrict__ Wq, const void* __restrict__ bq,
    const void* __restrict__ Wk, const void* __restrict__ bk,
    const void* __restrict__ Wv, const void* __restrict__ bv,
    const void* __restrict__ Wo, const void* __restrict__ bo,
    bf16* __restrict__ Wth, bf16* __restrict__ Wtl, float* __restrict__ ball,
    bf16* __restrict__ WoTh, bf16* __restrict__ WoTl, float* __restrict__ ball2,
    const int* __restrict__ flag)
{
    const int c = blockIdx.x;
    const int tid = threadIdx.x;
    const int f32 = *flag;

    if (c < 192) {
        const int g = c >> 6;              // 0=Q 1=K 2=V
        const int cc = c & 63;
        const void* W    = (g == 0) ? Wq : (g == 1) ? Wk : Wv;
        const void* bias = (g == 0) ? bq : (g == 1) ? bk : bv;
        const int d = tid;
        const float v = f32 ? ((const float*)W)[d * DKV + cc]
                            : b2f(((const bf16*)W)[d * DKV + cc]);
        const unsigned short hb = f2bits(v);
        Wth[c * D_MODEL + d] = *(const bf16*)&hb;
        const unsigned short lb = f2bits(v - bits2f(hb));
        Wtl[c * D_MODEL + d] = *(const bf16*)&lb;
        if (d == 0)
            ball[c] = f32 ? ((const float*)bias)[cc] : b2f(((const bf16*)bias)[cc]);
    }
    if (tid < DKV) {                       // Wo is (DKV=64, D=512): Wo[k][c]
        const int k = tid;
        const float v = f32 ? ((const float*)Wo)[k * D_MODEL + c]
                            : b2f(((const bf16*)Wo)[k * D_MODEL + c]);
        const unsigned short hb = f2bits(v);
        WoTh[c * DKV + k] = *(const bf16*)&hb;
        const unsigned short lb = f2bits(v - bits2f(hb));
        WoTl[c * DKV + k] = *(const bf16*)&lb;
        if (k == 0)
            ball2[c] = f32 ? ((const float*)bo)[c] : b2f(((const bf16*)bo)[c]);
    }
}

// ---------------------------------------------------------------------------
// Kernel 1b (bf16 path): QKV projection, single-term MFMA. Dead when fp32.
// ---------------------------------------------------------------------------
__global__ __launch_bounds__(256) void qkv_mfma_bf16(
    const void* __restrict__ x,
    const bf16* __restrict__ Wth, const float* __restrict__ ball,
    bf16* __restrict__ Qb, bf16* __restrict__ Kb, bf16* __restrict__ Vt,
    const int* __restrict__ flag)
{
    if (*flag) return;
    __shared__ unsigned short hiA[32 * D_MODEL];   // 32 KB
    const int tid = threadIdx.x;
    const int rowBase = blockIdx.x * 32;

    const unsigned short* xr = (const unsigned short*)x + (size_t)rowBase * D_MODEL;
    #pragma unroll
    for (int i = 0; i < 8; ++i) {
        const int idx = tid + 256 * i;
        const int r = idx >> 6;
        const int c0 = (idx & 63) << 3;
        const uint4 hv = *(const uint4*)&xr[r * D_MODEL + c0];
        const int boff = (c0 * 2) ^ ((r & 7) << 4);
        *(uint4*)((char*)hiA + r * 1024 + boff) = hv;
    }
    __syncthreads();

    const int lane = tid & 63;
    const int w    = tid >> 6;
    const int quad = lane >> 4;
    const int l15  = lane & 15;
    const int wr   = w & 1;
    const int wcol = w >> 1;
    const int arow = wr * 16 + l15;
    const char* hib = (const char*)hiA + arow * 1024;
    const int swz = (arow & 7) << 4;

    floatx4 acc[6];
    #pragma unroll
    for (int ct = 0; ct < 6; ++ct) acc[ct] = (floatx4){0.f, 0.f, 0.f, 0.f};

    const bf16* wbase = Wth + (size_t)(wcol * 96 + l15) * D_MODEL + quad * 8;

    for (int kt = 0; kt < 16; ++kt) {
        const int boff = (kt * 64 + quad * 16) ^ swz;
        const short8 ah = *(const short8*)(hib + boff);
        const bf16* wk = wbase + kt * 32;
        #pragma unroll
        for (int ct = 0; ct < 6; ++ct) {
            const short8 bh = *(const short8*)(wk + (size_t)ct * 16 * D_MODEL);
            acc[ct] = MFMA(ah, bh, acc[ct]);
        }
    }

    #pragma unroll
    for (int ct = 0; ct < 6; ++ct) {
        const int gc = wcol * 96 + ct * 16 + l15;
        const float bias = ball[gc];
        const float scale = (gc < 64) ? 0.18033688f : 1.0f;
        #pragma unroll
        for (int r = 0; r < 4; ++r) {
            const int gr = rowBase + wr * 16 + quad * 4 + r;
            const bf16 o = __float2bfloat16((acc[ct][r] + bias) * scale);
            if (gc < 64)       Qb[(size_t)gr * DKV + gc] = o;
            else if (gc < 128) Kb[(size_t)gr * DKV + (gc - 64)] = o;
            else {
                const int bb = gr >> 12, sidx = gr & (S_LEN - 1);
                Vt[((size_t)bb * DKV + (gc - 128)) * S_LEN + sidx] = o;
            }
        }
    }
}

// ---------------------------------------------------------------------------
// Kernel 1b (fp32 LIVE path): 3-term hi/lo split MFMA GEMM.
// Restructured for occupancy: 32-row tiles (64 KB LDS -> 2 blocks/CU),
// 512 threads = 8 waves (2 row-halves x 4 col-quarters, 3 C-tiles each).
// 4 waves/SIMD vs previous 1 -> latency actually hidden.
// ---------------------------------------------------------------------------
__global__ __launch_bounds__(512) void qkv_mfma_f32(
    const void* __restrict__ x,
    const bf16* __restrict__ Wth, const bf16* __restrict__ Wtl,
    const float* __restrict__ ball,
    bf16* __restrict__ Qb, bf16* __restrict__ Kb, bf16* __restrict__ Vt,
    const int* __restrict__ flag)
{
    if (!*flag) return;
    __shared__ unsigned short hiA[32 * D_MODEL];   // 32 KB
    __shared__ unsigned short loA[32 * D_MODEL];   // 32 KB
    const int tid = threadIdx.x;
    const int rowBase = blockIdx.x * 32;

    union Pack8 { uint4 u; unsigned short s[8]; };
    {
        const float* xr = (const float*)x + (size_t)rowBase * D_MODEL;
        #pragma unroll
        for (int i = 0; i < 4; ++i) {
            const int idx = tid + 512 * i;       // 2048 8-elem chunks
            const int r = idx >> 6;
            const int c0 = (idx & 63) << 3;
            const float4 v0 = *(const float4*)&xr[r * D_MODEL + c0];
            const float4 v1 = *(const float4*)&xr[r * D_MODEL + c0 + 4];
            const float vv[8] = {v0.x, v0.y, v0.z, v0.w, v1.x, v1.y, v1.z, v1.w};
            Pack8 ph, pl;
            #pragma unroll
            for (int j = 0; j < 8; ++j) {
                const unsigned short hb = f2bits(vv[j]);
                ph.s[j] = hb;
                pl.s[j] = f2bits(vv[j] - bits2f(hb));
            }
            const int boff = (c0 * 2) ^ ((r & 7) << 4);
            *(uint4*)((char*)hiA + r * 1024 + boff) = ph.u;
            *(uint4*)((char*)loA + r * 1024 + boff) = pl.u;
        }
    }
    __syncthreads();

    const int lane = tid & 63;
    const int w    = tid >> 6;           // 0..7
    const int quad = lane >> 4;
    const int l15  = lane & 15;
    const int wr   = w & 1;              // row half (16 rows)
    const int wq   = w >> 1;             // col quarter (48 cols = 3 tiles)
    const int arow = wr * 16 + l15;
    const char* hib = (const char*)hiA + arow * 1024;
    const char* lob = (const char*)loA + arow * 1024;
    const int swz = (arow & 7) << 4;

    floatx4 acc[3];
    #pragma unroll
    for (int ct = 0; ct < 3; ++ct) acc[ct] = (floatx4){0.f, 0.f, 0.f, 0.f};

    const int colBase = wq * 48;
    const bf16* wh_base = Wth + (size_t)(colBase + l15) * D_MODEL + quad * 8;
    const bf16* wl_base = Wtl + (size_t)(colBase + l15) * D_MODEL + quad * 8;

    for (int kt = 0; kt < 16; ++kt) {
        const int boff = (kt * 64 + quad * 16) ^ swz;
        const short8 ah = *(const short8*)(hib + boff);
        const short8 al = *(const short8*)(lob + boff);
        #pragma unroll
        for (int ct = 0; ct < 3; ++ct) {
            const short8 bh = *(const short8*)(wh_base + (size_t)ct * 16 * D_MODEL + kt * 32);
            const short8 bl = *(const short8*)(wl_base + (size_t)ct * 16 * D_MODEL + kt * 32);
            acc[ct] = MFMA(ah, bh, acc[ct]);
            acc[ct] = MFMA(ah, bl, acc[ct]);
            acc[ct] = MFMA(al, bh, acc[ct]);
        }
    }

    #pragma unroll
    for (int ct = 0; ct < 3; ++ct) {
        const int gc = colBase + ct * 16 + l15;
        const float bias = ball[gc];
        const float scale = (gc < 64) ? 0.18033688f : 1.0f;
        #pragma unroll
        for (int r = 0; r < 4; ++r) {
            const int gr = rowBase + wr * 16 + quad * 4 + r;
            const bf16 o = __float2bfloat16((acc[ct][r] + bias) * scale);
            if (gc < 64)       Qb[(size_t)gr * DKV + gc] = o;
            else if (gc < 128) Kb[(size_t)gr * DKV + (gc - 64)] = o;
            else {
                const int bb = gr >> 12, sidx = gr & (S_LEN - 1);
                Vt[((size_t)bb * DKV + (gc - 128)) * S_LEN + sidx] = o;
            }
        }
    }
}

// ---------------------------------------------------------------------------
// Kernel 2: MFMA flash attention, KVBLK=128, split-K by 128-tile parity.
// Grid 1024: xcd=bid&7 -> b=xcd>>1, kh=xcd&1; t=127-(bid>>3) longest-first.
// ---------------------------------------------------------------------------
__global__ __launch_bounds__(256, 3) void attn_mfma(
    const bf16* __restrict__ Qg, const bf16* __restrict__ Kg,
    const bf16* __restrict__ Vtg, float* __restrict__ Op,
    float* __restrict__ Mp, float* __restrict__ Lp)
{
    const int bid = blockIdx.x;
    const int xcd = bid & 7;
    const int b  = xcd >> 1;
    const int kh = xcd & 1;
    const int t  = 127 - (bid >> 3);
    const int rowBase = t * 32;
    const int tid = threadIdx.x;
    const int lane = tid & 63;
    const int w  = tid >> 6;
    const int wr = w & 1;
    const int wc = w >> 1;
    const int quad = lane >> 4;
    const int l15  = lane & 15;

    __shared__ bf16 Kl[128 * STR];       // [key][dim]     18.0 KB
    __shared__ bf16 Vl[64 * VSTR];       // [vdim][key]    17.0 KB
    __shared__ bf16 Pl[32 * VSTR];       // [row][key]      8.5 KB; Q staging
    __shared__ float redm[2][32];
    __shared__ float reds[2][32];

    const bf16* Qb = Qg + ((size_t)b * S_LEN + rowBase) * DKV;
    const bf16* Kb = Kg + (size_t)b * S_LEN * DKV;
    const bf16* Vb = Vtg + (size_t)b * DKV * S_LEN;

    // stage Q tile (32x64) into Pl, load A-fragments once
    {
        const int r = tid >> 3, d0q = (tid & 7) * 8;
        *(uint4*)&Pl[r * VSTR + d0q] = *(const uint4*)&Qb[r * DKV + d0q];
    }
    __syncthreads();
    short8 qf0, qf1;
    {
        const int qoff = (wr * 16 + l15) * VSTR + quad * 8;
        qf0 = *(const short8*)&Pl[qoff];
        qf1 = *(const short8*)&Pl[qoff + 32];
    }

    floatx4 acc0 = {0.f, 0.f, 0.f, 0.f}, acc1 = {0.f, 0.f, 0.f, 0.f};
    float m_run[4], l_run[4];
    #pragma unroll
    for (int r = 0; r < 4; ++r) { m_run[r] = -1e30f; l_run[r] = 0.f; }

    const int kbMax = (rowBase + 31) >> 7;
    const int kk = tid >> 1, dk = (tid & 1) * 32;   // K staging: 2 thr/row
    const int vd = tid >> 2, vk = (tid & 3) * 32;   // V staging: 4 thr/row

    uint4 kr0, kr1, kr2, kr3, vr0, vr1, vr2, vr3;
    int kb = kh;
    if (kb <= kbMax) {
        const uint4* ks = (const uint4*)&Kb[((size_t)(kb * 128 + kk)) * DKV + dk];
        kr0 = ks[0]; kr1 = ks[1]; kr2 = ks[2]; kr3 = ks[3];
        const uint4* vs = (const uint4*)&Vb[(size_t)vd * S_LEN + kb * 128 + vk];
        vr0 = vs[0]; vr1 = vs[1]; vr2 = vs[2]; vr3 = vs[3];
    }

    for (; kb <= kbMax; kb += 2) {
        __syncthreads();                 // prior-iter LDS reads done
        {
            uint4* kd = (uint4*)&Kl[kk * STR + dk];
            kd[0] = kr0; kd[1] = kr1; kd[2] = kr2; kd[3] = kr3;
            uint4* vdst = (uint4*)&Vl[vd * VSTR + vk];
            vdst[0] = vr0; vdst[1] = vr1; vdst[2] = vr2; vdst[3] = vr3;
        }
        __syncthreads();
        if (kb + 2 <= kbMax) {           // prefetch next tile under compute
            const uint4* ks = (const uint4*)&Kb[((size_t)((kb + 2) * 128 + kk)) * DKV + dk];
            kr0 = ks[0]; kr1 = ks[1]; kr2 = ks[2]; kr3 = ks[3];
            const uint4* vs = (const uint4*)&Vb[(size_t)vd * S_LEN + (kb + 2) * 128 + vk];
            vr0 = vs[0]; vr1 = vs[1]; vr2 = vs[2]; vr3 = vs[3];
        }

        // S = Q K^T (Q pre-scaled): four 16x16 key-tiles per wave
        floatx4 s[4];
        #pragma unroll
        for (int j = 0; j < 4; ++j) s[j] = (floatx4){0.f, 0.f, 0.f, 0.f};
        {
            const int qk = quad * 8;
            #pragma unroll
            for (int j = 0; j < 4; ++j) {
                const int kc = (wc * 64 + j * 16 + l15) * STR + qk;
                const short8 ba = *(const short8*)&Kl[kc];
                const short8 bb = *(const short8*)&Kl[kc + 32];
                s[j] = MFMA(qf0, ba, s[j]);
                s[j] = MFMA(qf1, bb, s[j]);
            }
        }
        if (kb == kbMax) {               // causal mask, uniform branch
            const int rowg = rowBase + wr * 16 + quad * 4;
            #pragma unroll
            for (int j = 0; j < 4; ++j) {
                const int kg = kb * 128 + wc * 64 + j * 16 + l15;
                #pragma unroll
                for (int r = 0; r < 4; ++r)
                    if (kg > rowg + r) s[j][r] = -1e30f;
            }
        }
        // per-row max over this wave's 64 cols (16-lane butterfly)
        float m4[4];
        #pragma unroll
        for (int r = 0; r < 4; ++r)
            m4[r] = fmaxf(fmaxf(s[0][r], s[1][r]), fmaxf(s[2][r], s[3][r]));
        #pragma unroll
        for (int off = 1; off < 16; off <<= 1) {
            #pragma unroll
            for (int r = 0; r < 4; ++r) m4[r] = fmaxf(m4[r], __shfl_xor(m4[r], off));
        }
        if (l15 == 0) {
            #pragma unroll
            for (int r = 0; r < 4; ++r) redm[wc][wr * 16 + quad * 4 + r] = m4[r];
        }
        __syncthreads();
        float alpha[4], mnew[4];
        #pragma unroll
        for (int r = 0; r < 4; ++r) {
            const int row = wr * 16 + quad * 4 + r;
            const float mm = fmaxf(redm[0][row], redm[1][row]);
            mnew[r] = fmaxf(m_run[r], mm);
            alpha[r] = exp2f(m_run[r] - mnew[r]);   // -1e30 first iter -> 0
            m_run[r] = mnew[r];
        }
        float ps[4];
        #pragma unroll
        for (int r = 0; r < 4; ++r) {
            float acc_ps = 0.f;
            #pragma unroll
            for (int j = 0; j < 4; ++j) {
                const float p = exp2f(s[j][r] - mnew[r]);
                s[j][r] = p;
                acc_ps += p;
            }
            ps[r] = acc_ps;
        }
        #pragma unroll
        for (int off = 1; off < 16; off <<= 1) {
            #pragma unroll
            for (int r = 0; r < 4; ++r) ps[r] += __shfl_xor(ps[r], off);
        }
        if (l15 == 0) {
            #pragma unroll
            for (int r = 0; r < 4; ++r) reds[wc][wr * 16 + quad * 4 + r] = ps[r];
        }
        // rescale O-acc, write P (bf16) to LDS
        #pragma unroll
        for (int r = 0; r < 4; ++r) {
            acc0[r] *= alpha[r]; acc1[r] *= alpha[r];
            const int poff = (wr * 16 + quad * 4 + r) * VSTR + wc * 64 + l15;
            Pl[poff]      = __float2bfloat16(s[0][r]);
            Pl[poff + 16] = __float2bfloat16(s[1][r]);
            Pl[poff + 32] = __float2bfloat16(s[2][r]);
            Pl[poff + 48] = __float2bfloat16(s[3][r]);
        }
        __syncthreads();
        #pragma unroll
        for (int r = 0; r < 4; ++r) {
            const int row = wr * 16 + quad * 4 + r;
            l_run[r] = l_run[r] * alpha[r] + reds[0][row] + reds[1][row];
        }
        // O += P V : K=128 keys over 4 chunks, two vdim-tiles per wave
        {
            const int pk = quad * 8;
            const int prow = (wr * 16 + l15) * VSTR;
            const int vrow0 = (wc * 32 + l15) * VSTR;
            const int vrow1 = vrow0 + 16 * VSTR;
            #pragma unroll
            for (int j = 0; j < 4; ++j) {
                const short8 pa  = *(const short8*)&Pl[prow + pk + j * 32];
                const short8 vb0 = *(const short8*)&Vl[vrow0 + pk + j * 32];
                const short8 vb1 = *(const short8*)&Vl[vrow1 + pk + j * 32];
                acc0 = MFMA(pa, vb0, acc0);
                acc1 = MFMA(pa, vb1, acc1);
            }
        }
    }
    // epilogue: store unnormalized O + per-row (m, l)
    #pragma unroll
    for (int r = 0; r < 4; ++r) {
        const int row = rowBase + wr * 16 + quad * 4 + r;
        float* op = Op + (((size_t)kh * B_N + b) * S_LEN + row) * DKV + wc * 32 + l15;
        op[0]  = acc0[r];
        op[16] = acc1[r];
    }
    if (wc == 0 && l15 == 0) {
        #pragma unroll
        for (int r = 0; r < 4; ++r) {
            const int row = rowBase + wr * 16 + quad * 4 + r;
            const size_t mi = (size_t)kh * B_N * S_LEN + (size_t)b * S_LEN + row;
            Mp[mi] = m_run[r];
            Lp[mi] = l_run[r];
        }
    }
}

// ---------------------------------------------------------------------------
// Kernel 2b: merge the two split-K halves, normalize, emit O as bf16 hi/lo.
// ---------------------------------------------------------------------------
__global__ __launch_bounds__(256) void merge_kernel(
    const float* __restrict__ Op, const float* __restrict__ Mp,
    const float* __restrict__ Lp, bf16* __restrict__ Oh, bf16* __restrict__ Ol)
{
    const int row = blockIdx.x * 32 + (threadIdx.x >> 3);
    const int d0 = (threadIdx.x & 7) * 8;
    const size_t half = (size_t)B_N * S_LEN;

    const float m0 = Mp[row], m1 = Mp[half + row];
    const float l0 = Lp[row], l1 = Lp[half + row];
    const float m = fmaxf(m0, m1);
    const float w0 = exp2f(m0 - m), w1 = exp2f(m1 - m);
    const float inv = 1.0f / (l0 * w0 + l1 * w1);

    const float* p0 = Op + (size_t)row * DKV + d0;
    const float* p1 = Op + half * DKV + (size_t)row * DKV + d0;
    union Pack8 { uint4 u; unsigned short s[8]; };
    Pack8 ph, pl;
    #pragma unroll
    for (int j = 0; j < 8; ++j) {
        const float o = (p0[j] * w0 + p1[j] * w1) * inv;
        const unsigned short hb = f2bits(o);
        ph.s[j] = hb;
        pl.s[j] = f2bits(o - bits2f(hb));
    }
    *(uint4*)&Oh[(size_t)row * DKV + d0] = ph.u;
    *(uint4*)&Ol[(size_t)row * DKV + d0] = pl.u;
}

// ---------------------------------------------------------------------------
// Kernel 3 (bf16 path): output projection, A hi/lo x W hi. Dead when fp32.
// ---------------------------------------------------------------------------
#define PSTR 72
__global__ __launch_bounds__(256) void proj_mfma_bf16(
    const bf16* __restrict__ Oh, const bf16* __restrict__ Ol,
    const bf16* __restrict__ WoTh, const float* __restrict__ ball2,
    bf16* __restrict__ out, const int* __restrict__ flag)
{
    if (*flag) return;
    __shared__ unsigned short Ah[32 * PSTR], Al[32 * PSTR];
    const int tid = threadIdx.x;
    const int rowBase = blockIdx.x * 32;

    {
        const int r = tid >> 3, c0 = (tid & 7) * 8;
        *(uint4*)&Ah[r * PSTR + c0] = *(const uint4*)&Oh[(size_t)(rowBase + r) * DKV + c0];
        *(uint4*)&Al[r * PSTR + c0] = *(const uint4*)&Ol[(size_t)(rowBase + r) * DKV + c0];
    }
    __syncthreads();

    const int lane = tid & 63;
    const int w    = tid >> 6;
    const int quad = lane >> 4;
    const int l15  = lane & 15;
    const int wr   = w & 1;
    const int wcq  = w >> 1;

    const int aoff = (wr * 16 + l15) * PSTR + quad * 8;
    const short8 ah0 = *(const short8*)&Ah[aoff];
    const short8 ah1 = *(const short8*)&Ah[aoff + 32];
    const short8 al0 = *(const short8*)&Al[aoff];
    const short8 al1 = *(const short8*)&Al[aoff + 32];

    floatx4 acc[16];
    #pragma unroll
    for (int ct = 0; ct < 16; ++ct) acc[ct] = (floatx4){0.f, 0.f, 0.f, 0.f};

    #pragma unroll
    for (int ct = 0; ct < 16; ++ct) {
        const size_t cb = (size_t)(wcq * 256 + ct * 16 + l15) * DKV + quad * 8;
        const short8 bh0 = *(const short8*)&WoTh[cb];
        const short8 bh1 = *(const short8*)&WoTh[cb + 32];
        acc[ct] = MFMA(ah0, bh0, acc[ct]);
        acc[ct] = MFMA(ah1, bh1, acc[ct]);
        acc[ct] = MFMA(al0, bh0, acc[ct]);
        acc[ct] = MFMA(al1, bh1, acc[ct]);
    }

    #pragma unroll
    for (int ct = 0; ct < 16; ++ct) {
        const int col = wcq * 256 + ct * 16 + l15;
        const float bias = ball2[col];
        #pragma unroll
        for (int r = 0; r < 4; ++r) {
            const int row = rowBase + wr * 16 + quad * 4 + r;
            out[(size_t)row * D_MODEL + col] = __float2bfloat16(acc[ct][r] + bias);
        }
    }
}

// ---------------------------------------------------------------------------
// Kernel 3 (fp32 LIVE path): 6-term hi/lo on both operands, fp32 output.
// 512 threads = 8 waves (2 row-halves x 4 col-quarters, 8 C-tiles each)
// -> 4096 waves total, 4/SIMD.
// ---------------------------------------------------------------------------
__global__ __launch_bounds__(512) void proj_mfma_f32(
    const bf16* __restrict__ Oh, const bf16* __restrict__ Ol,
    const bf16* __restrict__ WoTh, const bf16* __restrict__ WoTl,
    const float* __restrict__ ball2, float* __restrict__ out,
    const int* __restrict__ flag)
{
    if (!*flag) return;
    __shared__ unsigned short Ah[32 * PSTR], Al[32 * PSTR];
    const int tid = threadIdx.x;
    const int rowBase = blockIdx.x * 32;

    {   // 512 chunks: threads 0..255 -> Ah, 256..511 -> Al
        const int r = (tid & 255) >> 3, c0 = (tid & 7) * 8;
        if (tid < 256)
            *(uint4*)&Ah[r * PSTR + c0] = *(const uint4*)&Oh[(size_t)(rowBase + r) * DKV + c0];
        else
            *(uint4*)&Al[r * PSTR + c0] = *(const uint4*)&Ol[(size_t)(rowBase + r) * DKV + c0];
    }
    __syncthreads();

    const int lane = tid & 63;
    const int w    = tid >> 6;           // 0..7
    const int quad = lane >> 4;
    const int l15  = lane & 15;
    const int wr   = w & 1;
    const int wcq  = w >> 1;             // 0..3 col quarter (128 cols)

    const int aoff = (wr * 16 + l15) * PSTR + quad * 8;
    const short8 ah0 = *(const short8*)&Ah[aoff];
    const short8 ah1 = *(const short8*)&Ah[aoff + 32];
    const short8 al0 = *(const short8*)&Al[aoff];
    const short8 al1 = *(const short8*)&Al[aoff + 32];

    floatx4 acc[8];
    #pragma unroll
    for (int ct = 0; ct < 8; ++ct) acc[ct] = (floatx4){0.f, 0.f, 0.f, 0.f};

    #pragma unroll
    for (int ct = 0; ct < 8; ++ct) {
        const size_t cb = (size_t)(wcq * 128 + ct * 16 + l15) * DKV + quad * 8;
        const short8 bh0 = *(const short8*)&WoTh[cb];
        const short8 bh1 = *(const short8*)&WoTh[cb + 32];
        const short8 bl0 = *(const short8*)&WoTl[cb];
        const short8 bl1 = *(const short8*)&WoTl[cb + 32];
        acc[ct] = MFMA(ah0, bh0, acc[ct]);
        acc[ct] = MFMA(ah1, bh1, acc[ct]);
        acc[ct] = MFMA(ah0, bl0, acc[ct]);
        acc[ct] = MFMA(ah1, bl1, acc[ct]);
        acc[ct] = MFMA(al0, bh0, acc[ct]);
        acc[ct] = MFMA(al1, bh1, acc[ct]);
    }

    #pragma unroll
    for (int ct = 0; ct < 8; ++ct) {
        const int col = wcq * 128 + ct * 16 + l15;
        const float bias = ball2[col];
        #pragma unroll
        for (int r = 0; r < 4; ++r) {
            const int row = rowBase + wr * 16 + quad * 4 + r;
            out[(size_t)row * D_MODEL + col] = acc[ct][r] + bias;
        }
    }
}

extern "C" void kernel_launch(void* const* d_in, const int* in_sizes, int n_in,
                              void* d_out, int out_size, void* d_ws, size_t ws_size,
                              hipStream_t stream) {
    const void* x  = d_in[0];
    const void* Wq = d_in[1];
    const void* bq = d_in[2];
    const void* Wk = d_in[3];
    const void* bk = d_in[4];
    const void* Wv = d_in[5];
    const void* bv = d_in[6];
    const void* Wo = d_in[7];
    const void* bo = d_in[8];

    const int rows = B_N * S_LEN;                 // 16384
    char* p = (char*)d_ws;
    int*  flag = (int*)p;                          p += 256;
    bf16* Qb = (bf16*)p;                           p += (size_t)rows * DKV * 2;   // 2 MB
    bf16* Kb = (bf16*)p;                           p += (size_t)rows * DKV * 2;
    bf16* Vt = (bf16*)p;                           p += (size_t)rows * DKV * 2;
    bf16* Wth = (bf16*)p;                          p += 192 * D_MODEL * 2;
    bf16* Wtl = (bf16*)p;                          p += 192 * D_MODEL * 2;
    float* ball = (float*)p;                       p += 1024;
    bf16* WoTh = (bf16*)p;                         p += D_MODEL * DKV * 2;
    bf16* WoTl = (bf16*)p;                         p += D_MODEL * DKV * 2;
    float* ball2 = (float*)p;                      p += D_MODEL * 4;
    float* Op = (float*)p;                         p += (size_t)2 * rows * DKV * 4; // 8 MB
    float* Mp = (float*)p;                         p += (size_t)2 * rows * 4;
    float* Lp = (float*)p;                         p += (size_t)2 * rows * 4;
    bf16* Ohb = (bf16*)p;                          p += (size_t)rows * DKV * 2;
    bf16* Olb = (bf16*)p;                          p += (size_t)rows * DKV * 2;

    detect_kernel<<<1, 64, 0, stream>>>(x, flag);
    wprep_kernel<<<512, 512, 0, stream>>>(Wq, bq, Wk, bk, Wv, bv, Wo, bo,
                                          Wth, Wtl, ball, WoTh, WoTl, ball2, flag);
    qkv_mfma_bf16<<<512, 256, 0, stream>>>(x, Wth, ball, Qb, Kb, Vt, flag);
    qkv_mfma_f32<<<512, 512, 0, stream>>>(x, Wth, Wtl, ball, Qb, Kb, Vt, flag);
    attn_mfma<<<1024, 256, 0, stream>>>(Qb, Kb, Vt, Op, Mp, Lp);
    merge_kernel<<<512, 256, 0, stream>>>(Op, Mp, Lp, Ohb, Olb);
    proj_mfma_bf16<<<512, 256, 0, stream>>>(Ohb, Olb, WoTh, ball2, (bf16*)d_out, flag);
    proj_mfma_f32<<<512, 512, 0, stream>>>(Ohb, Olb, WoTh, WoTl, ball2, (float*)d_out, flag);
}

// Round 6
// 189.868 us; speedup vs baseline: 2.7180x; 1.1706x over previous
//
#include <hip/hip_runtime.h>
#include <hip/hip_bf16.h>

#define S_LEN 4096
#define D_MODEL 512
#define DKV 64
#define B_N 4
#define STR 72    // K-tile LDS row stride (elems)
#define VSTR 136  // V/P LDS row stride (elems), 128 keys + pad

typedef __hip_bfloat16 bf16;
typedef __attribute__((ext_vector_type(8))) short short8;   // 8 bf16 (4 VGPRs)
typedef __attribute__((ext_vector_type(4))) float floatx4;  // MFMA C/D

#define MFMA(a, b, c) __builtin_amdgcn_mfma_f32_16x16x32_bf16(a, b, c, 0, 0, 0)

__device__ __forceinline__ float b2f(bf16 v) { return __bfloat162float(v); }

__device__ __forceinline__ unsigned short f2bits(float v) {
    union { bf16 h; unsigned short u; } cv;
    cv.h = __float2bfloat16(v);
    return cv.u;
}
__device__ __forceinline__ float bits2f(unsigned short u) {
    union { bf16 h; unsigned short u; } cv;
    cv.u = u;
    return b2f(cv.h);
}

// ---------------------------------------------------------------------------
// Kernel 0: dtype detect (value-based; proven). flag=1 -> fp32 inputs.
// ---------------------------------------------------------------------------
__global__ __launch_bounds__(64) void detect_kernel(const void* x, int* flag) {
    const int lane = threadIdx.x;
    const bf16* xb = (const bf16*)x;
    int bad = 0;
    for (int k = lane; k < 4096; k += 64) {
        float v = fabsf(b2f(xb[2 * k]));
        if (!(v < 64.f)) bad++;
    }
    #pragma unroll
    for (int off = 32; off >= 1; off >>= 1) bad += __shfl_xor(bad, off);
    if (lane == 0) *flag = (bad > 100) ? 1 : 0;
}

// ---------------------------------------------------------------------------
// Kernel 1a: QKV W prep -> FRAGMENT-PACKED layout.
// Wf[tile][kt][lane][8]: tile in [0,12) (16 cols), kt in [0,16) (K=32 step).
// Fragment elem j of lane (quad=lane>>4, l15=lane&15):
//   W[k = kt*32+quad*8+j][col = tile*16+l15]   (hi/lo bf16 split)
// A wave's B-fragment load is 64 lanes x 16B CONTIGUOUS (1 KB) -> coalesced.
// ---------------------------------------------------------------------------
__global__ __launch_bounds__(512) void wprep_qkv_frag(
    const void* __restrict__ Wq, const void* __restrict__ bq,
    const void* __restrict__ Wk, const void* __restrict__ bk,
    const void* __restrict__ Wv, const void* __restrict__ bv,
    bf16* __restrict__ Wfh, bf16* __restrict__ Wfl, float* __restrict__ ball,
    const int* __restrict__ flag)
{
    __shared__ float xs[16][513];        // [col][k], padded
    const int ct = blockIdx.x;           // 0..11
    const int c0 = ct * 16;
    const int g = c0 >> 6;               // 0=Q 1=K 2=V
    const int cc0 = c0 & 63;
    const void* W    = (g == 0) ? Wq : (g == 1) ? Wk : Wv;
    const void* bias = (g == 0) ? bq : (g == 1) ? bk : bv;
    const int tid = threadIdx.x;
    const int f32 = *flag;

    // stage 512x16 source slice into LDS (transposed), coalesced-ish reads
    #pragma unroll
    for (int i = 0; i < 16; ++i) {
        const int idx = tid + 512 * i;   // 0..8191
        const int d = idx >> 4, j = idx & 15;
        const float v = f32 ? ((const float*)W)[(size_t)d * DKV + cc0 + j]
                            : b2f(((const bf16*)W)[(size_t)d * DKV + cc0 + j]);
        xs[j][d] = v;
    }
    __syncthreads();

    union Pack8 { uint4 u; unsigned short s[8]; };
    #pragma unroll
    for (int rep = 0; rep < 2; ++rep) {
        const int f = tid + rep * 512;   // fragment id: kt*64 + lane
        const int kt = f >> 6, lane = f & 63;
        const int quad = lane >> 4, l15 = lane & 15;
        Pack8 ph, pl;
        #pragma unroll
        for (int j = 0; j < 8; ++j) {
            const float v = xs[l15][kt * 32 + quad * 8 + j];
            const unsigned short hb = f2bits(v);
            ph.s[j] = hb;
            pl.s[j] = f2bits(v - bits2f(hb));
        }
        const size_t o = (((size_t)ct * 16 + kt) * 64 + lane) * 8;
        *(uint4*)&Wfh[o] = ph.u;
        *(uint4*)&Wfl[o] = pl.u;
    }
    if (tid < 16)
        ball[c0 + tid] = f32 ? ((const float*)bias)[cc0 + tid]
                             : b2f(((const bf16*)bias)[cc0 + tid]);
}

// ---------------------------------------------------------------------------
// Kernel 1a': Wo prep -> fragment-packed WoF[ctile][kc][lane][8], ctile in
// [0,32), kc in {0,1}: elem j = Wo[kc*32+quad*8+j][ctile*16+l15].
// ---------------------------------------------------------------------------
__global__ __launch_bounds__(512) void wprep_o_frag(
    const void* __restrict__ Wo, const void* __restrict__ bo,
    bf16* __restrict__ WoFh, bf16* __restrict__ WoFl,
    float* __restrict__ ball2, const int* __restrict__ flag)
{
    __shared__ float ys[16][65];         // [col][k]
    const int ctile = blockIdx.x;        // 0..31
    const int c0 = ctile * 16;
    const int tid = threadIdx.x;
    const int f32 = *flag;

    #pragma unroll
    for (int rep = 0; rep < 2; ++rep) {
        const int idx = tid + rep * 512; // 0..1023
        const int d = idx >> 4, j = idx & 15;
        const float v = f32 ? ((const float*)Wo)[(size_t)d * D_MODEL + c0 + j]
                            : b2f(((const bf16*)Wo)[(size_t)d * D_MODEL + c0 + j]);
        ys[j][d] = v;
    }
    __syncthreads();

    union Pack8 { uint4 u; unsigned short s[8]; };
    if (tid < 128) {
        const int kc = tid >> 6, lane = tid & 63;
        const int quad = lane >> 4, l15 = lane & 15;
        Pack8 ph, pl;
        #pragma unroll
        for (int j = 0; j < 8; ++j) {
            const float v = ys[l15][kc * 32 + quad * 8 + j];
            const unsigned short hb = f2bits(v);
            ph.s[j] = hb;
            pl.s[j] = f2bits(v - bits2f(hb));
        }
        const size_t o = (((size_t)ctile * 2 + kc) * 64 + lane) * 8;
        *(uint4*)&WoFh[o] = ph.u;
        *(uint4*)&WoFl[o] = pl.u;
    }
    if (tid < 16)
        ball2[c0 + tid] = f32 ? ((const float*)bo)[c0 + tid]
                              : b2f(((const bf16*)bo)[c0 + tid]);
}

// ---------------------------------------------------------------------------
// Kernel 1b (bf16 path): QKV projection, single-term MFMA. Dead when fp32.
// ---------------------------------------------------------------------------
__global__ __launch_bounds__(256) void qkv_mfma_bf16(
    const void* __restrict__ x,
    const bf16* __restrict__ Wfh, const float* __restrict__ ball,
    bf16* __restrict__ Qb, bf16* __restrict__ Kb, bf16* __restrict__ Vt,
    const int* __restrict__ flag)
{
    if (*flag) return;
    __shared__ unsigned short hiA[32 * D_MODEL];   // 32 KB
    const int tid = threadIdx.x;
    const int rowBase = blockIdx.x * 32;

    const unsigned short* xr = (const unsigned short*)x + (size_t)rowBase * D_MODEL;
    #pragma unroll
    for (int i = 0; i < 8; ++i) {
        const int idx = tid + 256 * i;
        const int r = idx >> 6;
        const int c0 = (idx & 63) << 3;
        const uint4 hv = *(const uint4*)&xr[r * D_MODEL + c0];
        const int boff = (c0 * 2) ^ ((r & 7) << 4);
        *(uint4*)((char*)hiA + r * 1024 + boff) = hv;
    }
    __syncthreads();

    const int lane = tid & 63;
    const int w    = tid >> 6;
    const int quad = lane >> 4;
    const int l15  = lane & 15;
    const int wr   = w & 1;
    const int wcol = w >> 1;
    const int arow = wr * 16 + l15;
    const char* hib = (const char*)hiA + arow * 1024;
    const int swz = (arow & 7) << 4;

    floatx4 acc[6];
    #pragma unroll
    for (int ct = 0; ct < 6; ++ct) acc[ct] = (floatx4){0.f, 0.f, 0.f, 0.f};

    for (int kt = 0; kt < 16; ++kt) {
        const int boff = (kt * 64 + quad * 16) ^ swz;
        const short8 ah = *(const short8*)(hib + boff);
        #pragma unroll
        for (int ct = 0; ct < 6; ++ct) {
            const size_t fo = (((size_t)(wcol * 6 + ct) * 16 + kt) * 64 + lane) * 8;
            const short8 bh = *(const short8*)&Wfh[fo];
            acc[ct] = MFMA(ah, bh, acc[ct]);
        }
    }

    #pragma unroll
    for (int ct = 0; ct < 6; ++ct) {
        const int gc = wcol * 96 + ct * 16 + l15;
        const float bias = ball[gc];
        const float scale = (gc < 64) ? 0.18033688f : 1.0f;
        #pragma unroll
        for (int r = 0; r < 4; ++r) {
            const int gr = rowBase + wr * 16 + quad * 4 + r;
            const bf16 o = __float2bfloat16((acc[ct][r] + bias) * scale);
            if (gc < 64)       Qb[(size_t)gr * DKV + gc] = o;
            else if (gc < 128) Kb[(size_t)gr * DKV + (gc - 64)] = o;
            else {
                const int bb = gr >> 12, sidx = gr & (S_LEN - 1);
                Vt[((size_t)bb * DKV + (gc - 128)) * S_LEN + sidx] = o;
            }
        }
    }
}

// ---------------------------------------------------------------------------
// Kernel 1b (fp32 LIVE path): 3-term hi/lo split MFMA GEMM.
// 32-row tiles, 512 threads = 8 waves (2 row-halves x 4 col-quarters).
// B-fragments loaded from fragment-packed Wf: 1 KB contiguous per wave load.
// ---------------------------------------------------------------------------
__global__ __launch_bounds__(512) void qkv_mfma_f32(
    const void* __restrict__ x,
    const bf16* __restrict__ Wfh, const bf16* __restrict__ Wfl,
    const float* __restrict__ ball,
    bf16* __restrict__ Qb, bf16* __restrict__ Kb, bf16* __restrict__ Vt,
    const int* __restrict__ flag)
{
    if (!*flag) return;
    __shared__ unsigned short hiA[32 * D_MODEL];   // 32 KB
    __shared__ unsigned short loA[32 * D_MODEL];   // 32 KB
    const int tid = threadIdx.x;
    const int rowBase = blockIdx.x * 32;

    union Pack8 { uint4 u; unsigned short s[8]; };
    {
        const float* xr = (const float*)x + (size_t)rowBase * D_MODEL;
        #pragma unroll
        for (int i = 0; i < 4; ++i) {
            const int idx = tid + 512 * i;       // 2048 8-elem chunks
            const int r = idx >> 6;
            const int c0 = (idx & 63) << 3;
            const float4 v0 = *(const float4*)&xr[r * D_MODEL + c0];
            const float4 v1 = *(const float4*)&xr[r * D_MODEL + c0 + 4];
            const float vv[8] = {v0.x, v0.y, v0.z, v0.w, v1.x, v1.y, v1.z, v1.w};
            Pack8 ph, pl;
            #pragma unroll
            for (int j = 0; j < 8; ++j) {
                const unsigned short hb = f2bits(vv[j]);
                ph.s[j] = hb;
                pl.s[j] = f2bits(vv[j] - bits2f(hb));
            }
            const int boff = (c0 * 2) ^ ((r & 7) << 4);
            *(uint4*)((char*)hiA + r * 1024 + boff) = ph.u;
            *(uint4*)((char*)loA + r * 1024 + boff) = pl.u;
        }
    }
    __syncthreads();

    const int lane = tid & 63;
    const int w    = tid >> 6;           // 0..7
    const int quad = lane >> 4;
    const int l15  = lane & 15;
    const int wr   = w & 1;              // row half (16 rows)
    const int wq   = w >> 1;             // col quarter (48 cols = 3 tiles)
    const int arow = wr * 16 + l15;
    const char* hib = (const char*)hiA + arow * 1024;
    const char* lob = (const char*)loA + arow * 1024;
    const int swz = (arow & 7) << 4;

    floatx4 acc[3];
    #pragma unroll
    for (int ct = 0; ct < 3; ++ct) acc[ct] = (floatx4){0.f, 0.f, 0.f, 0.f};

    for (int kt = 0; kt < 16; ++kt) {
        const int boff = (kt * 64 + quad * 16) ^ swz;
        const short8 ah = *(const short8*)(hib + boff);
        const short8 al = *(const short8*)(lob + boff);
        #pragma unroll
        for (int ct = 0; ct < 3; ++ct) {
            const size_t fo = (((size_t)(wq * 3 + ct) * 16 + kt) * 64 + lane) * 8;
            const short8 bh = *(const short8*)&Wfh[fo];
            const short8 bl = *(const short8*)&Wfl[fo];
            acc[ct] = MFMA(ah, bh, acc[ct]);
            acc[ct] = MFMA(ah, bl, acc[ct]);
            acc[ct] = MFMA(al, bh, acc[ct]);
        }
    }

    #pragma unroll
    for (int ct = 0; ct < 3; ++ct) {
        const int gc = wq * 48 + ct * 16 + l15;
        const float bias = ball[gc];
        const float scale = (gc < 64) ? 0.18033688f : 1.0f;
        #pragma unroll
        for (int r = 0; r < 4; ++r) {
            const int gr = rowBase + wr * 16 + quad * 4 + r;
            const bf16 o = __float2bfloat16((acc[ct][r] + bias) * scale);
            if (gc < 64)       Qb[(size_t)gr * DKV + gc] = o;
            else if (gc < 128) Kb[(size_t)gr * DKV + (gc - 64)] = o;
            else {
                const int bb = gr >> 12, sidx = gr & (S_LEN - 1);
                Vt[((size_t)bb * DKV + (gc - 128)) * S_LEN + sidx] = o;
            }
        }
    }
}

// ---------------------------------------------------------------------------
// Kernel 2: MFMA flash attention, KVBLK=128, split-K by 128-tile parity.
// Grid 1024: xcd=bid&7 -> b=xcd>>1, kh=xcd&1; t=127-(bid>>3) longest-first.
// ---------------------------------------------------------------------------
__global__ __launch_bounds__(256, 3) void attn_mfma(
    const bf16* __restrict__ Qg, const bf16* __restrict__ Kg,
    const bf16* __restrict__ Vtg, float* __restrict__ Op,
    float* __restrict__ Mp, float* __restrict__ Lp)
{
    const int bid = blockIdx.x;
    const int xcd = bid & 7;
    const int b  = xcd >> 1;
    const int kh = xcd & 1;
    const int t  = 127 - (bid >> 3);
    const int rowBase = t * 32;
    const int tid = threadIdx.x;
    const int lane = tid & 63;
    const int w  = tid >> 6;
    const int wr = w & 1;
    const int wc = w >> 1;
    const int quad = lane >> 4;
    const int l15  = lane & 15;

    __shared__ bf16 Kl[128 * STR];       // [key][dim]     18.0 KB
    __shared__ bf16 Vl[64 * VSTR];       // [vdim][key]    17.0 KB
    __shared__ bf16 Pl[32 * VSTR];       // [row][key]      8.5 KB; Q staging
    __shared__ float redm[2][32];
    __shared__ float reds[2][32];

    const bf16* Qb = Qg + ((size_t)b * S_LEN + rowBase) * DKV;
    const bf16* Kb = Kg + (size_t)b * S_LEN * DKV;
    const bf16* Vb = Vtg + (size_t)b * DKV * S_LEN;

    // stage Q tile (32x64) into Pl, load A-fragments once
    {
        const int r = tid >> 3, d0q = (tid & 7) * 8;
        *(uint4*)&Pl[r * VSTR + d0q] = *(const uint4*)&Qb[r * DKV + d0q];
    }
    __syncthreads();
    short8 qf0, qf1;
    {
        const int qoff = (wr * 16 + l15) * VSTR + quad * 8;
        qf0 = *(const short8*)&Pl[qoff];
        qf1 = *(const short8*)&Pl[qoff + 32];
    }

    floatx4 acc0 = {0.f, 0.f, 0.f, 0.f}, acc1 = {0.f, 0.f, 0.f, 0.f};
    float m_run[4], l_run[4];
    #pragma unroll
    for (int r = 0; r < 4; ++r) { m_run[r] = -1e30f; l_run[r] = 0.f; }

    const int kbMax = (rowBase + 31) >> 7;
    const int kk = tid >> 1, dk = (tid & 1) * 32;   // K staging: 2 thr/row
    const int vd = tid >> 2, vk = (tid & 3) * 32;   // V staging: 4 thr/row

    uint4 kr0, kr1, kr2, kr3, vr0, vr1, vr2, vr3;
    int kb = kh;
    if (kb <= kbMax) {
        const uint4* ks = (const uint4*)&Kb[((size_t)(kb * 128 + kk)) * DKV + dk];
        kr0 = ks[0]; kr1 = ks[1]; kr2 = ks[2]; kr3 = ks[3];
        const uint4* vs = (const uint4*)&Vb[(size_t)vd * S_LEN + kb * 128 + vk];
        vr0 = vs[0]; vr1 = vs[1]; vr2 = vs[2]; vr3 = vs[3];
    }

    for (; kb <= kbMax; kb += 2) {
        __syncthreads();                 // prior-iter LDS reads done
        {
            uint4* kd = (uint4*)&Kl[kk * STR + dk];
            kd[0] = kr0; kd[1] = kr1; kd[2] = kr2; kd[3] = kr3;
            uint4* vdst = (uint4*)&Vl[vd * VSTR + vk];
            vdst[0] = vr0; vdst[1] = vr1; vdst[2] = vr2; vdst[3] = vr3;
        }
        __syncthreads();
        if (kb + 2 <= kbMax) {           // prefetch next tile under compute
            const uint4* ks = (const uint4*)&Kb[((size_t)((kb + 2) * 128 + kk)) * DKV + dk];
            kr0 = ks[0]; kr1 = ks[1]; kr2 = ks[2]; kr3 = ks[3];
            const uint4* vs = (const uint4*)&Vb[(size_t)vd * S_LEN + (kb + 2) * 128 + vk];
            vr0 = vs[0]; vr1 = vs[1]; vr2 = vs[2]; vr3 = vs[3];
        }

        // S = Q K^T (Q pre-scaled): four 16x16 key-tiles per wave
        floatx4 s[4];
        #pragma unroll
        for (int j = 0; j < 4; ++j) s[j] = (floatx4){0.f, 0.f, 0.f, 0.f};
        {
            const int qk = quad * 8;
            #pragma unroll
            for (int j = 0; j < 4; ++j) {
                const int kc = (wc * 64 + j * 16 + l15) * STR + qk;
                const short8 ba = *(const short8*)&Kl[kc];
                const short8 bb = *(const short8*)&Kl[kc + 32];
                s[j] = MFMA(qf0, ba, s[j]);
                s[j] = MFMA(qf1, bb, s[j]);
            }
        }
        if (kb == kbMax) {               // causal mask, uniform branch
            const int rowg = rowBase + wr * 16 + quad * 4;
            #pragma unroll
            for (int j = 0; j < 4; ++j) {
                const int kg = kb * 128 + wc * 64 + j * 16 + l15;
                #pragma unroll
                for (int r = 0; r < 4; ++r)
                    if (kg > rowg + r) s[j][r] = -1e30f;
            }
        }
        // per-row max over this wave's 64 cols (16-lane butterfly)
        float m4[4];
        #pragma unroll
        for (int r = 0; r < 4; ++r)
            m4[r] = fmaxf(fmaxf(s[0][r], s[1][r]), fmaxf(s[2][r], s[3][r]));
        #pragma unroll
        for (int off = 1; off < 16; off <<= 1) {
            #pragma unroll
            for (int r = 0; r < 4; ++r) m4[r] = fmaxf(m4[r], __shfl_xor(m4[r], off));
        }
        if (l15 == 0) {
            #pragma unroll
            for (int r = 0; r < 4; ++r) redm[wc][wr * 16 + quad * 4 + r] = m4[r];
        }
        __syncthreads();
        float alpha[4], mnew[4];
        #pragma unroll
        for (int r = 0; r < 4; ++r) {
            const int row = wr * 16 + quad * 4 + r;
            const float mm = fmaxf(redm[0][row], redm[1][row]);
            mnew[r] = fmaxf(m_run[r], mm);
            alpha[r] = exp2f(m_run[r] - mnew[r]);   // -1e30 first iter -> 0
            m_run[r] = mnew[r];
        }
        float ps[4];
        #pragma unroll
        for (int r = 0; r < 4; ++r) {
            float acc_ps = 0.f;
            #pragma unroll
            for (int j = 0; j < 4; ++j) {
                const float p = exp2f(s[j][r] - mnew[r]);
                s[j][r] = p;
                acc_ps += p;
            }
            ps[r] = acc_ps;
        }
        #pragma unroll
        for (int off = 1; off < 16; off <<= 1) {
            #pragma unroll
            for (int r = 0; r < 4; ++r) ps[r] += __shfl_xor(ps[r], off);
        }
        if (l15 == 0) {
            #pragma unroll
            for (int r = 0; r < 4; ++r) reds[wc][wr * 16 + quad * 4 + r] = ps[r];
        }
        // rescale O-acc, write P (bf16) to LDS
        #pragma unroll
        for (int r = 0; r < 4; ++r) {
            acc0[r] *= alpha[r]; acc1[r] *= alpha[r];
            const int poff = (wr * 16 + quad * 4 + r) * VSTR + wc * 64 + l15;
            Pl[poff]      = __float2bfloat16(s[0][r]);
            Pl[poff + 16] = __float2bfloat16(s[1][r]);
            Pl[poff + 32] = __float2bfloat16(s[2][r]);
            Pl[poff + 48] = __float2bfloat16(s[3][r]);
        }
        __syncthreads();
        #pragma unroll
        for (int r = 0; r < 4; ++r) {
            const int row = wr * 16 + quad * 4 + r;
            l_run[r] = l_run[r] * alpha[r] + reds[0][row] + reds[1][row];
        }
        // O += P V : K=128 keys over 4 chunks, two vdim-tiles per wave
        {
            const int pk = quad * 8;
            const int prow = (wr * 16 + l15) * VSTR;
            const int vrow0 = (wc * 32 + l15) * VSTR;
            const int vrow1 = vrow0 + 16 * VSTR;
            #pragma unroll
            for (int j = 0; j < 4; ++j) {
                const short8 pa  = *(const short8*)&Pl[prow + pk + j * 32];
                const short8 vb0 = *(const short8*)&Vl[vrow0 + pk + j * 32];
                const short8 vb1 = *(const short8*)&Vl[vrow1 + pk + j * 32];
                acc0 = MFMA(pa, vb0, acc0);
                acc1 = MFMA(pa, vb1, acc1);
            }
        }
    }
    // epilogue: store unnormalized O + per-row (m, l)
    #pragma unroll
    for (int r = 0; r < 4; ++r) {
        const int row = rowBase + wr * 16 + quad * 4 + r;
        float* op = Op + (((size_t)kh * B_N + b) * S_LEN + row) * DKV + wc * 32 + l15;
        op[0]  = acc0[r];
        op[16] = acc1[r];
    }
    if (wc == 0 && l15 == 0) {
        #pragma unroll
        for (int r = 0; r < 4; ++r) {
            const int row = rowBase + wr * 16 + quad * 4 + r;
            const size_t mi = (size_t)kh * B_N * S_LEN + (size_t)b * S_LEN + row;
            Mp[mi] = m_run[r];
            Lp[mi] = l_run[r];
        }
    }
}

// ---------------------------------------------------------------------------
// Kernel 2b: merge the two split-K halves, normalize, emit O as bf16 hi/lo.
// ---------------------------------------------------------------------------
__global__ __launch_bounds__(256) void merge_kernel(
    const float* __restrict__ Op, const float* __restrict__ Mp,
    const float* __restrict__ Lp, bf16* __restrict__ Oh, bf16* __restrict__ Ol)
{
    const int row = blockIdx.x * 32 + (threadIdx.x >> 3);
    const int d0 = (threadIdx.x & 7) * 8;
    const size_t half = (size_t)B_N * S_LEN;

    const float m0 = Mp[row], m1 = Mp[half + row];
    const float l0 = Lp[row], l1 = Lp[half + row];
    const float m = fmaxf(m0, m1);
    const float w0 = exp2f(m0 - m), w1 = exp2f(m1 - m);
    const float inv = 1.0f / (l0 * w0 + l1 * w1);

    const float* p0 = Op + (size_t)row * DKV + d0;
    const float* p1 = Op + half * DKV + (size_t)row * DKV + d0;
    union Pack8 { uint4 u; unsigned short s[8]; };
    Pack8 ph, pl;
    #pragma unroll
    for (int j = 0; j < 8; ++j) {
        const float o = (p0[j] * w0 + p1[j] * w1) * inv;
        const unsigned short hb = f2bits(o);
        ph.s[j] = hb;
        pl.s[j] = f2bits(o - bits2f(hb));
    }
    *(uint4*)&Oh[(size_t)row * DKV + d0] = ph.u;
    *(uint4*)&Ol[(size_t)row * DKV + d0] = pl.u;
}

// ---------------------------------------------------------------------------
// Kernel 3 (bf16 path): output projection, A hi/lo x W hi. Dead when fp32.
// ---------------------------------------------------------------------------
#define PSTR 72
__global__ __launch_bounds__(256) void proj_mfma_bf16(
    const bf16* __restrict__ Oh, const bf16* __restrict__ Ol,
    const bf16* __restrict__ WoFh, const float* __restrict__ ball2,
    bf16* __restrict__ out, const int* __restrict__ flag)
{
    if (*flag) return;
    __shared__ unsigned short Ah[32 * PSTR], Al[32 * PSTR];
    const int tid = threadIdx.x;
    const int rowBase = blockIdx.x * 32;

    {
        const int r = tid >> 3, c0 = (tid & 7) * 8;
        *(uint4*)&Ah[r * PSTR + c0] = *(const uint4*)&Oh[(size_t)(rowBase + r) * DKV + c0];
        *(uint4*)&Al[r * PSTR + c0] = *(const uint4*)&Ol[(size_t)(rowBase + r) * DKV + c0];
    }
    __syncthreads();

    const int lane = tid & 63;
    const int w    = tid >> 6;
    const int quad = lane >> 4;
    const int l15  = lane & 15;
    const int wr   = w & 1;
    const int wcq  = w >> 1;

    const int aoff = (wr * 16 + l15) * PSTR + quad * 8;
    const short8 ah0 = *(const short8*)&Ah[aoff];
    const short8 ah1 = *(const short8*)&Ah[aoff + 32];
    const short8 al0 = *(const short8*)&Al[aoff];
    const short8 al1 = *(const short8*)&Al[aoff + 32];

    floatx4 acc[16];
    #pragma unroll
    for (int ct = 0; ct < 16; ++ct) acc[ct] = (floatx4){0.f, 0.f, 0.f, 0.f};

    #pragma unroll
    for (int ct = 0; ct < 16; ++ct) {
        const int ctile = wcq * 16 + ct;
        const size_t o0 = (((size_t)ctile * 2 + 0) * 64 + lane) * 8;
        const size_t o1 = (((size_t)ctile * 2 + 1) * 64 + lane) * 8;
        const short8 bh0 = *(const short8*)&WoFh[o0];
        const short8 bh1 = *(const short8*)&WoFh[o1];
        acc[ct] = MFMA(ah0, bh0, acc[ct]);
        acc[ct] = MFMA(ah1, bh1, acc[ct]);
        acc[ct] = MFMA(al0, bh0, acc[ct]);
        acc[ct] = MFMA(al1, bh1, acc[ct]);
    }

    #pragma unroll
    for (int ct = 0; ct < 16; ++ct) {
        const int col = wcq * 256 + ct * 16 + l15;
        const float bias = ball2[col];
        #pragma unroll
        for (int r = 0; r < 4; ++r) {
            const int row = rowBase + wr * 16 + quad * 4 + r;
            out[(size_t)row * D_MODEL + col] = __float2bfloat16(acc[ct][r] + bias);
        }
    }
}

// ---------------------------------------------------------------------------
// Kernel 3 (fp32 LIVE path): 6-term hi/lo on both operands, fp32 output.
// 512 threads = 8 waves; W from fragment-packed WoF (coalesced 1 KB loads).
// ---------------------------------------------------------------------------
__global__ __launch_bounds__(512) void proj_mfma_f32(
    const bf16* __restrict__ Oh, const bf16* __restrict__ Ol,
    const bf16* __restrict__ WoFh, const bf16* __restrict__ WoFl,
    const float* __restrict__ ball2, float* __restrict__ out,
    const int* __restrict__ flag)
{
    if (!*flag) return;
    __shared__ unsigned short Ah[32 * PSTR], Al[32 * PSTR];
    const int tid = threadIdx.x;
    const int rowBase = blockIdx.x * 32;

    {   // 512 chunks: threads 0..255 -> Ah, 256..511 -> Al
        const int r = (tid & 255) >> 3, c0 = (tid & 7) * 8;
        if (tid < 256)
            *(uint4*)&Ah[r * PSTR + c0] = *(const uint4*)&Oh[(size_t)(rowBase + r) * DKV + c0];
        else
            *(uint4*)&Al[r * PSTR + c0] = *(const uint4*)&Ol[(size_t)(rowBase + r) * DKV + c0];
    }
    __syncthreads();

    const int lane = tid & 63;
    const int w    = tid >> 6;           // 0..7
    const int quad = lane >> 4;
    const int l15  = lane & 15;
    const int wr   = w & 1;
    const int wcq  = w >> 1;             // 0..3 col quarter (128 cols)

    const int aoff = (wr * 16 + l15) * PSTR + quad * 8;
    const short8 ah0 = *(const short8*)&Ah[aoff];
    const short8 ah1 = *(const short8*)&Ah[aoff + 32];
    const short8 al0 = *(const short8*)&Al[aoff];
    const short8 al1 = *(const short8*)&Al[aoff + 32];

    floatx4 acc[8];
    #pragma unroll
    for (int ct = 0; ct < 8; ++ct) acc[ct] = (floatx4){0.f, 0.f, 0.f, 0.f};

    #pragma unroll
    for (int ct = 0; ct < 8; ++ct) {
        const int ctile = wcq * 8 + ct;
        const size_t o0 = (((size_t)ctile * 2 + 0) * 64 + lane) * 8;
        const size_t o1 = (((size_t)ctile * 2 + 1) * 64 + lane) * 8;
        const short8 bh0 = *(const short8*)&WoFh[o0];
        const short8 bh1 = *(const short8*)&WoFh[o1];
        const short8 bl0 = *(const short8*)&WoFl[o0];
        const short8 bl1 = *(const short8*)&WoFl[o1];
        acc[ct] = MFMA(ah0, bh0, acc[ct]);
        acc[ct] = MFMA(ah1, bh1, acc[ct]);
        acc[ct] = MFMA(ah0, bl0, acc[ct]);
        acc[ct] = MFMA(ah1, bl1, acc[ct]);
        acc[ct] = MFMA(al0, bh0, acc[ct]);
        acc[ct] = MFMA(al1, bh1, acc[ct]);
    }

    #pragma unroll
    for (int ct = 0; ct < 8; ++ct) {
        const int col = wcq * 128 + ct * 16 + l15;
        const float bias = ball2[col];
        #pragma unroll
        for (int r = 0; r < 4; ++r) {
            const int row = rowBase + wr * 16 + quad * 4 + r;
            out[(size_t)row * D_MODEL + col] = acc[ct][r] + bias;
        }
    }
}

extern "C" void kernel_launch(void* const* d_in, const int* in_sizes, int n_in,
                              void* d_out, int out_size, void* d_ws, size_t ws_size,
                              hipStream_t stream) {
    const void* x  = d_in[0];
    const void* Wq = d_in[1];
    const void* bq = d_in[2];
    const void* Wk = d_in[3];
    const void* bk = d_in[4];
    const void* Wv = d_in[5];
    const void* bv = d_in[6];
    const void* Wo = d_in[7];
    const void* bo = d_in[8];

    const int rows = B_N * S_LEN;                 // 16384
    char* p = (char*)d_ws;
    int*  flag = (int*)p;                          p += 256;
    bf16* Qb = (bf16*)p;                           p += (size_t)rows * DKV * 2;   // 2 MB
    bf16* Kb = (bf16*)p;                           p += (size_t)rows * DKV * 2;
    bf16* Vt = (bf16*)p;                           p += (size_t)rows * DKV * 2;
    bf16* Wfh = (bf16*)p;                          p += (size_t)12 * 16 * 64 * 8 * 2;  // 196.6 KB
    bf16* Wfl = (bf16*)p;                          p += (size_t)12 * 16 * 64 * 8 * 2;
    float* ball = (float*)p;                       p += 1024;
    bf16* WoFh = (bf16*)p;                         p += (size_t)32 * 2 * 64 * 8 * 2;   // 64 KB
    bf16* WoFl = (bf16*)p;                         p += (size_t)32 * 2 * 64 * 8 * 2;
    float* ball2 = (float*)p;                      p += D_MODEL * 4;
    float* Op = (float*)p;                         p += (size_t)2 * rows * DKV * 4; // 8 MB
    float* Mp = (float*)p;                         p += (size_t)2 * rows * 4;
    float* Lp = (float*)p;                         p += (size_t)2 * rows * 4;
    bf16* Ohb = (bf16*)p;                          p += (size_t)rows * DKV * 2;
    bf16* Olb = (bf16*)p;                          p += (size_t)rows * DKV * 2;

    detect_kernel<<<1, 64, 0, stream>>>(x, flag);
    wprep_qkv_frag<<<12, 512, 0, stream>>>(Wq, bq, Wk, bk, Wv, bv, Wfh, Wfl, ball, flag);
    wprep_o_frag<<<32, 512, 0, stream>>>(Wo, bo, WoFh, WoFl, ball2, flag);
    qkv_mfma_bf16<<<512, 256, 0, stream>>>(x, Wfh, ball, Qb, Kb, Vt, flag);
    qkv_mfma_f32<<<512, 512, 0, stream>>>(x, Wfh, Wfl, ball, Qb, Kb, Vt, flag);
    attn_mfma<<<1024, 256, 0, stream>>>(Qb, Kb, Vt, Op, Mp, Lp);
    merge_kernel<<<512, 256, 0, stream>>>(Op, Mp, Lp, Ohb, Olb);
    proj_mfma_bf16<<<512, 256, 0, stream>>>(Ohb, Olb, WoFh, ball2, (bf16*)d_out, flag);
    proj_mfma_f32<<<512, 512, 0, stream>>>(Ohb, Olb, WoFh, WoFl, ball2, (float*)d_out, flag);
}

// Round 7
// 181.914 us; speedup vs baseline: 2.8369x; 1.0437x over previous
//
#include <hip/hip_runtime.h>
#include <hip/hip_bf16.h>

#define S_LEN 4096
#define D_MODEL 512
#define DKV 64
#define B_N 4
#define STR 72    // K-tile LDS row stride (elems)
#define VSTR 136  // V/P LDS row stride (elems), 128 keys + pad

typedef __hip_bfloat16 bf16;
typedef __attribute__((ext_vector_type(8))) short short8;   // 8 bf16 (4 VGPRs)
typedef __attribute__((ext_vector_type(4))) float floatx4;  // MFMA C/D

#define MFMA(a, b, c) __builtin_amdgcn_mfma_f32_16x16x32_bf16(a, b, c, 0, 0, 0)

__device__ __forceinline__ float b2f(bf16 v) { return __bfloat162float(v); }

__device__ __forceinline__ unsigned short f2bits(float v) {
    union { bf16 h; unsigned short u; } cv;
    cv.h = __float2bfloat16(v);
    return cv.u;
}
__device__ __forceinline__ float bits2f(unsigned short u) {
    union { bf16 h; unsigned short u; } cv;
    cv.u = u;
    return b2f(cv.h);
}

// ---------------------------------------------------------------------------
// Kernel 0: dtype detect (value-based; proven). flag=1 -> fp32 inputs.
// ---------------------------------------------------------------------------
__global__ __launch_bounds__(64) void detect_kernel(const void* x, int* flag) {
    const int lane = threadIdx.x;
    const bf16* xb = (const bf16*)x;
    int bad = 0;
    for (int k = lane; k < 4096; k += 64) {
        float v = fabsf(b2f(xb[2 * k]));
        if (!(v < 64.f)) bad++;
    }
    #pragma unroll
    for (int off = 32; off >= 1; off >>= 1) bad += __shfl_xor(bad, off);
    if (lane == 0) *flag = (bad > 100) ? 1 : 0;
}

// ---------------------------------------------------------------------------
// Kernel 1a: QKV W prep -> FRAGMENT-PACKED layout (proven R6).
// ---------------------------------------------------------------------------
__global__ __launch_bounds__(512) void wprep_qkv_frag(
    const void* __restrict__ Wq, const void* __restrict__ bq,
    const void* __restrict__ Wk, const void* __restrict__ bk,
    const void* __restrict__ Wv, const void* __restrict__ bv,
    bf16* __restrict__ Wfh, bf16* __restrict__ Wfl, float* __restrict__ ball,
    const int* __restrict__ flag)
{
    __shared__ float xs[16][513];        // [col][k], padded
    const int ct = blockIdx.x;           // 0..11
    const int c0 = ct * 16;
    const int g = c0 >> 6;               // 0=Q 1=K 2=V
    const int cc0 = c0 & 63;
    const void* W    = (g == 0) ? Wq : (g == 1) ? Wk : Wv;
    const void* bias = (g == 0) ? bq : (g == 1) ? bk : bv;
    const int tid = threadIdx.x;
    const int f32 = *flag;

    #pragma unroll
    for (int i = 0; i < 16; ++i) {
        const int idx = tid + 512 * i;   // 0..8191
        const int d = idx >> 4, j = idx & 15;
        const float v = f32 ? ((const float*)W)[(size_t)d * DKV + cc0 + j]
                            : b2f(((const bf16*)W)[(size_t)d * DKV + cc0 + j]);
        xs[j][d] = v;
    }
    __syncthreads();

    union Pack8 { uint4 u; unsigned short s[8]; };
    #pragma unroll
    for (int rep = 0; rep < 2; ++rep) {
        const int f = tid + rep * 512;   // fragment id: kt*64 + lane
        const int kt = f >> 6, lane = f & 63;
        const int quad = lane >> 4, l15 = lane & 15;
        Pack8 ph, pl;
        #pragma unroll
        for (int j = 0; j < 8; ++j) {
            const float v = xs[l15][kt * 32 + quad * 8 + j];
            const unsigned short hb = f2bits(v);
            ph.s[j] = hb;
            pl.s[j] = f2bits(v - bits2f(hb));
        }
        const size_t o = (((size_t)ct * 16 + kt) * 64 + lane) * 8;
        *(uint4*)&Wfh[o] = ph.u;
        *(uint4*)&Wfl[o] = pl.u;
    }
    if (tid < 16)
        ball[c0 + tid] = f32 ? ((const float*)bias)[cc0 + tid]
                             : b2f(((const bf16*)bias)[cc0 + tid]);
}

// ---------------------------------------------------------------------------
// Kernel 1a': Wo prep -> fragment-packed (proven R6).
// ---------------------------------------------------------------------------
__global__ __launch_bounds__(512) void wprep_o_frag(
    const void* __restrict__ Wo, const void* __restrict__ bo,
    bf16* __restrict__ WoFh, bf16* __restrict__ WoFl,
    float* __restrict__ ball2, const int* __restrict__ flag)
{
    __shared__ float ys[16][65];         // [col][k]
    const int ctile = blockIdx.x;        // 0..31
    const int c0 = ctile * 16;
    const int tid = threadIdx.x;
    const int f32 = *flag;

    #pragma unroll
    for (int rep = 0; rep < 2; ++rep) {
        const int idx = tid + rep * 512; // 0..1023
        const int d = idx >> 4, j = idx & 15;
        const float v = f32 ? ((const float*)Wo)[(size_t)d * D_MODEL + c0 + j]
                            : b2f(((const bf16*)Wo)[(size_t)d * D_MODEL + c0 + j]);
        ys[j][d] = v;
    }
    __syncthreads();

    union Pack8 { uint4 u; unsigned short s[8]; };
    if (tid < 128) {
        const int kc = tid >> 6, lane = tid & 63;
        const int quad = lane >> 4, l15 = lane & 15;
        Pack8 ph, pl;
        #pragma unroll
        for (int j = 0; j < 8; ++j) {
            const float v = ys[l15][kc * 32 + quad * 8 + j];
            const unsigned short hb = f2bits(v);
            ph.s[j] = hb;
            pl.s[j] = f2bits(v - bits2f(hb));
        }
        const size_t o = (((size_t)ctile * 2 + kc) * 64 + lane) * 8;
        *(uint4*)&WoFh[o] = ph.u;
        *(uint4*)&WoFl[o] = pl.u;
    }
    if (tid < 16)
        ball2[c0 + tid] = f32 ? ((const float*)bo)[c0 + tid]
                              : b2f(((const bf16*)bo)[c0 + tid]);
}

// ---------------------------------------------------------------------------
// Kernel 1b (bf16 path): QKV projection, single-term MFMA. Dead when fp32.
// ---------------------------------------------------------------------------
__global__ __launch_bounds__(256) void qkv_mfma_bf16(
    const void* __restrict__ x,
    const bf16* __restrict__ Wfh, const float* __restrict__ ball,
    bf16* __restrict__ Qb, bf16* __restrict__ Kb, bf16* __restrict__ Vt,
    const int* __restrict__ flag)
{
    if (*flag) return;
    __shared__ unsigned short hiA[32 * D_MODEL];   // 32 KB
    const int tid = threadIdx.x;
    const int rowBase = blockIdx.x * 32;

    const unsigned short* xr = (const unsigned short*)x + (size_t)rowBase * D_MODEL;
    #pragma unroll
    for (int i = 0; i < 8; ++i) {
        const int idx = tid + 256 * i;
        const int r = idx >> 6;
        const int c0 = (idx & 63) << 3;
        const uint4 hv = *(const uint4*)&xr[r * D_MODEL + c0];
        const int boff = (c0 * 2) ^ ((r & 7) << 4);
        *(uint4*)((char*)hiA + r * 1024 + boff) = hv;
    }
    __syncthreads();

    const int lane = tid & 63;
    const int w    = tid >> 6;
    const int quad = lane >> 4;
    const int l15  = lane & 15;
    const int wr   = w & 1;
    const int wcol = w >> 1;
    const int arow = wr * 16 + l15;
    const char* hib = (const char*)hiA + arow * 1024;
    const int swz = (arow & 7) << 4;

    floatx4 acc[6];
    #pragma unroll
    for (int ct = 0; ct < 6; ++ct) acc[ct] = (floatx4){0.f, 0.f, 0.f, 0.f};

    for (int kt = 0; kt < 16; ++kt) {
        const int boff = (kt * 64 + quad * 16) ^ swz;
        const short8 ah = *(const short8*)(hib + boff);
        #pragma unroll
        for (int ct = 0; ct < 6; ++ct) {
            const size_t fo = (((size_t)(wcol * 6 + ct) * 16 + kt) * 64 + lane) * 8;
            const short8 bh = *(const short8*)&Wfh[fo];
            acc[ct] = MFMA(ah, bh, acc[ct]);
        }
    }

    #pragma unroll
    for (int ct = 0; ct < 6; ++ct) {
        const int gc = wcol * 96 + ct * 16 + l15;
        const float bias = ball[gc];
        const float scale = (gc < 64) ? 0.18033688f : 1.0f;
        #pragma unroll
        for (int r = 0; r < 4; ++r) {
            const int gr = rowBase + wr * 16 + quad * 4 + r;
            const bf16 o = __float2bfloat16((acc[ct][r] + bias) * scale);
            if (gc < 64)       Qb[(size_t)gr * DKV + gc] = o;
            else if (gc < 128) Kb[(size_t)gr * DKV + (gc - 64)] = o;
            else {
                const int bb = gr >> 12, sidx = gr & (S_LEN - 1);
                Vt[((size_t)bb * DKV + (gc - 128)) * S_LEN + sidx] = o;
            }
        }
    }
}

// ---------------------------------------------------------------------------
// Kernel 1b (fp32 LIVE path): 3-term hi/lo split MFMA GEMM (proven R6).
// ---------------------------------------------------------------------------
__global__ __launch_bounds__(512) void qkv_mfma_f32(
    const void* __restrict__ x,
    const bf16* __restrict__ Wfh, const bf16* __restrict__ Wfl,
    const float* __restrict__ ball,
    bf16* __restrict__ Qb, bf16* __restrict__ Kb, bf16* __restrict__ Vt,
    const int* __restrict__ flag)
{
    if (!*flag) return;
    __shared__ unsigned short hiA[32 * D_MODEL];   // 32 KB
    __shared__ unsigned short loA[32 * D_MODEL];   // 32 KB
    const int tid = threadIdx.x;
    const int rowBase = blockIdx.x * 32;

    union Pack8 { uint4 u; unsigned short s[8]; };
    {
        const float* xr = (const float*)x + (size_t)rowBase * D_MODEL;
        #pragma unroll
        for (int i = 0; i < 4; ++i) {
            const int idx = tid + 512 * i;       // 2048 8-elem chunks
            const int r = idx >> 6;
            const int c0 = (idx & 63) << 3;
            const float4 v0 = *(const float4*)&xr[r * D_MODEL + c0];
            const float4 v1 = *(const float4*)&xr[r * D_MODEL + c0 + 4];
            const float vv[8] = {v0.x, v0.y, v0.z, v0.w, v1.x, v1.y, v1.z, v1.w};
            Pack8 ph, pl;
            #pragma unroll
            for (int j = 0; j < 8; ++j) {
                const unsigned short hb = f2bits(vv[j]);
                ph.s[j] = hb;
                pl.s[j] = f2bits(vv[j] - bits2f(hb));
            }
            const int boff = (c0 * 2) ^ ((r & 7) << 4);
            *(uint4*)((char*)hiA + r * 1024 + boff) = ph.u;
            *(uint4*)((char*)loA + r * 1024 + boff) = pl.u;
        }
    }
    __syncthreads();

    const int lane = tid & 63;
    const int w    = tid >> 6;           // 0..7
    const int quad = lane >> 4;
    const int l15  = lane & 15;
    const int wr   = w & 1;              // row half (16 rows)
    const int wq   = w >> 1;             // col quarter (48 cols = 3 tiles)
    const int arow = wr * 16 + l15;
    const char* hib = (const char*)hiA + arow * 1024;
    const char* lob = (const char*)loA + arow * 1024;
    const int swz = (arow & 7) << 4;

    floatx4 acc[3];
    #pragma unroll
    for (int ct = 0; ct < 3; ++ct) acc[ct] = (floatx4){0.f, 0.f, 0.f, 0.f};

    for (int kt = 0; kt < 16; ++kt) {
        const int boff = (kt * 64 + quad * 16) ^ swz;
        const short8 ah = *(const short8*)(hib + boff);
        const short8 al = *(const short8*)(lob + boff);
        #pragma unroll
        for (int ct = 0; ct < 3; ++ct) {
            const size_t fo = (((size_t)(wq * 3 + ct) * 16 + kt) * 64 + lane) * 8;
            const short8 bh = *(const short8*)&Wfh[fo];
            const short8 bl = *(const short8*)&Wfl[fo];
            acc[ct] = MFMA(ah, bh, acc[ct]);
            acc[ct] = MFMA(ah, bl, acc[ct]);
            acc[ct] = MFMA(al, bh, acc[ct]);
        }
    }

    #pragma unroll
    for (int ct = 0; ct < 3; ++ct) {
        const int gc = wq * 48 + ct * 16 + l15;
        const float bias = ball[gc];
        const float scale = (gc < 64) ? 0.18033688f : 1.0f;
        #pragma unroll
        for (int r = 0; r < 4; ++r) {
            const int gr = rowBase + wr * 16 + quad * 4 + r;
            const bf16 o = __float2bfloat16((acc[ct][r] + bias) * scale);
            if (gc < 64)       Qb[(size_t)gr * DKV + gc] = o;
            else if (gc < 128) Kb[(size_t)gr * DKV + (gc - 64)] = o;
            else {
                const int bb = gr >> 12, sidx = gr & (S_LEN - 1);
                Vt[((size_t)bb * DKV + (gc - 128)) * S_LEN + sidx] = o;
            }
        }
    }
}

// ---------------------------------------------------------------------------
// Kernel 2: MFMA flash attention v3. BM=64 rows/block, 4 waves, each wave
// owns 16 rows x ALL 128 keys -> WAVE-PRIVATE softmax (no cross-wave reduce,
// no redm/reds, 2 barriers/iter). P LDS region is per-wave private: PV reads
// need only lgkmcnt(0), not a barrier. Split-K into NS parts (2 or 4).
// Grid 256*NS: xcd=bid&7 -> b=xcd>>1, khL=xcd&1; rest=bid>>3 -> khH,t64.
// ---------------------------------------------------------------------------
__global__ __launch_bounds__(256, 3) void attn_mfma(
    const bf16* __restrict__ Qg, const bf16* __restrict__ Kg,
    const bf16* __restrict__ Vtg, float* __restrict__ Op,
    float* __restrict__ Mp, float* __restrict__ Lp, const int NS)
{
    const int bid = blockIdx.x;
    const int xcd = bid & 7;
    const int rest = bid >> 3;
    const int b   = xcd >> 1;
    const int khH = (NS == 4) ? (rest & 1) : 0;
    const int t64 = 63 - ((NS == 4) ? (rest >> 1) : rest);
    const int kh  = khH * 2 + (xcd & 1);
    const int rowBase = t64 * 64;
    const int tid = threadIdx.x;
    const int lane = tid & 63;
    const int w  = tid >> 6;             // wave: rows w*16..w*16+16
    const int quad = lane >> 4;
    const int l15  = lane & 15;

    __shared__ bf16 Kl[128 * STR];       // [key][dim]     18.0 KB
    __shared__ bf16 Vl[64 * VSTR];       // [vdim][key]    17.0 KB
    __shared__ bf16 Pl[64 * VSTR];       // [row][key]     17.0 KB; Q staging
    // total 52 KB -> 3 blocks/CU

    const bf16* Qb = Qg + ((size_t)b * S_LEN + rowBase) * DKV;
    const bf16* Kb = Kg + (size_t)b * S_LEN * DKV;
    const bf16* Vb = Vtg + (size_t)b * DKV * S_LEN;

    // stage Q tile (64x64) into Pl rows, load A-fragments once
    {
        const int qr = tid >> 2, qd = (tid & 3) * 16;
        *(uint4*)&Pl[qr * VSTR + qd]     = *(const uint4*)&Qb[qr * DKV + qd];
        *(uint4*)&Pl[qr * VSTR + qd + 8] = *(const uint4*)&Qb[qr * DKV + qd + 8];
    }
    __syncthreads();
    short8 qf0, qf1;
    {
        const int qoff = (w * 16 + l15) * VSTR + quad * 8;
        qf0 = *(const short8*)&Pl[qoff];
        qf1 = *(const short8*)&Pl[qoff + 32];
    }

    floatx4 acc[4];
    #pragma unroll
    for (int v = 0; v < 4; ++v) acc[v] = (floatx4){0.f, 0.f, 0.f, 0.f};
    float m_run[4], l_run[4];
    #pragma unroll
    for (int r = 0; r < 4; ++r) { m_run[r] = -1e30f; l_run[r] = 0.f; }

    const int kbMax = (rowBase + 63) >> 7;
    const int kk = tid >> 1, dk = (tid & 1) * 32;   // K staging: 2 thr/row
    const int vd = tid >> 2, vk = (tid & 3) * 32;   // V staging: 4 thr/row

    uint4 kr0, kr1, kr2, kr3, vr0, vr1, vr2, vr3;
    int kb = kh;
    if (kb <= kbMax) {
        const uint4* ks = (const uint4*)&Kb[((size_t)(kb * 128 + kk)) * DKV + dk];
        kr0 = ks[0]; kr1 = ks[1]; kr2 = ks[2]; kr3 = ks[3];
        const uint4* vs = (const uint4*)&Vb[(size_t)vd * S_LEN + kb * 128 + vk];
        vr0 = vs[0]; vr1 = vs[1]; vr2 = vs[2]; vr3 = vs[3];
    }

    for (; kb <= kbMax; kb += NS) {
        __syncthreads();                 // all waves done reading Kl/Vl
        {
            uint4* kd = (uint4*)&Kl[kk * STR + dk];
            kd[0] = kr0; kd[1] = kr1; kd[2] = kr2; kd[3] = kr3;
            uint4* vdst = (uint4*)&Vl[vd * VSTR + vk];
            vdst[0] = vr0; vdst[1] = vr1; vdst[2] = vr2; vdst[3] = vr3;
        }
        __syncthreads();                 // staging visible
        if (kb + NS <= kbMax) {          // prefetch next tile under compute
            const uint4* ks = (const uint4*)&Kb[((size_t)((kb + NS) * 128 + kk)) * DKV + dk];
            kr0 = ks[0]; kr1 = ks[1]; kr2 = ks[2]; kr3 = ks[3];
            const uint4* vs = (const uint4*)&Vb[(size_t)vd * S_LEN + (kb + NS) * 128 + vk];
            vr0 = vs[0]; vr1 = vs[1]; vr2 = vs[2]; vr3 = vs[3];
        }

        // S = Q K^T (Q pre-scaled): eight 16x16 key-tiles per wave
        floatx4 s[8];
        #pragma unroll
        for (int jt = 0; jt < 8; ++jt) s[jt] = (floatx4){0.f, 0.f, 0.f, 0.f};
        {
            const int qk = quad * 8;
            #pragma unroll
            for (int jt = 0; jt < 8; ++jt) {
                const int kc = (jt * 16 + l15) * STR + qk;
                const short8 ba = *(const short8*)&Kl[kc];
                const short8 bb = *(const short8*)&Kl[kc + 32];
                s[jt] = MFMA(qf0, ba, s[jt]);
                s[jt] = MFMA(qf1, bb, s[jt]);
            }
        }
        if (kb == kbMax) {               // causal mask, uniform branch
            const int rowg = rowBase + w * 16 + quad * 4;
            #pragma unroll
            for (int jt = 0; jt < 8; ++jt) {
                const int kg = kb * 128 + jt * 16 + l15;
                #pragma unroll
                for (int r = 0; r < 4; ++r)
                    if (kg > rowg + r) s[jt][r] = -1e30f;
            }
        }
        // wave-private row max over 128 keys: in-thread tree + 16-lane butterfly
        float m4[4];
        #pragma unroll
        for (int r = 0; r < 4; ++r) {
            float mm = s[0][r];
            #pragma unroll
            for (int jt = 1; jt < 8; ++jt) mm = fmaxf(mm, s[jt][r]);
            m4[r] = mm;
        }
        #pragma unroll
        for (int off = 1; off < 16; off <<= 1) {
            #pragma unroll
            for (int r = 0; r < 4; ++r) m4[r] = fmaxf(m4[r], __shfl_xor(m4[r], off));
        }
        float alpha[4];
        #pragma unroll
        for (int r = 0; r < 4; ++r) {
            const float mnew = fmaxf(m_run[r], m4[r]);
            alpha[r] = exp2f(m_run[r] - mnew);   // -1e30 first iter -> 0
            m_run[r] = mnew;
        }
        float ps[4];
        #pragma unroll
        for (int r = 0; r < 4; ++r) {
            float acc_ps = 0.f;
            #pragma unroll
            for (int jt = 0; jt < 8; ++jt) {
                const float pp = exp2f(s[jt][r] - m_run[r]);
                s[jt][r] = pp;
                acc_ps += pp;
            }
            ps[r] = acc_ps;
        }
        #pragma unroll
        for (int off = 1; off < 16; off <<= 1) {
            #pragma unroll
            for (int r = 0; r < 4; ++r) ps[r] += __shfl_xor(ps[r], off);
        }
        // rescale O-acc, update l, write P (bf16) to this wave's private rows
        #pragma unroll
        for (int r = 0; r < 4; ++r) {
            l_run[r] = l_run[r] * alpha[r] + ps[r];
            #pragma unroll
            for (int v = 0; v < 4; ++v) acc[v][r] *= alpha[r];
            const int poff = (w * 16 + quad * 4 + r) * VSTR + l15;
            #pragma unroll
            for (int jt = 0; jt < 8; ++jt)
                Pl[poff + jt * 16] = __float2bfloat16(s[jt][r]);
        }
        // same-wave LDS RAW: drain writes; "memory" clobber orders the ds_reads
        asm volatile("s_waitcnt lgkmcnt(0)" ::: "memory");

        // O += P V : 128 keys over 4 chunks, four vdim-tiles per wave
        {
            const int pk = quad * 8;
            const int prow = (w * 16 + l15) * VSTR;
            short8 pa[4];
            #pragma unroll
            for (int c = 0; c < 4; ++c)
                pa[c] = *(const short8*)&Pl[prow + pk + c * 32];
            #pragma unroll
            for (int v = 0; v < 4; ++v) {
                const int vrow = (v * 16 + l15) * VSTR;
                #pragma unroll
                for (int c = 0; c < 4; ++c) {
                    const short8 vb = *(const short8*)&Vl[vrow + pk + c * 32];
                    acc[v] = MFMA(pa[c], vb, acc[v]);
                }
            }
        }
    }
    // epilogue: store unnormalized O + per-row (m, l)
    #pragma unroll
    for (int r = 0; r < 4; ++r) {
        const int row = rowBase + w * 16 + quad * 4 + r;
        float* op = Op + (((size_t)kh * B_N + b) * S_LEN + row) * DKV + l15;
        #pragma unroll
        for (int v = 0; v < 4; ++v) op[v * 16] = acc[v][r];
    }
    if (l15 == 0) {
        #pragma unroll
        for (int r = 0; r < 4; ++r) {
            const int row = rowBase + w * 16 + quad * 4 + r;
            const size_t mi = ((size_t)kh * B_N + b) * S_LEN + row;
            Mp[mi] = m_run[r];
            Lp[mi] = l_run[r];
        }
    }
}

// ---------------------------------------------------------------------------
// Kernel 2b: merge NS split-K parts, normalize, emit O as bf16 hi/lo.
// ---------------------------------------------------------------------------
__global__ __launch_bounds__(256) void merge_kernel(
    const float* __restrict__ Op, const float* __restrict__ Mp,
    const float* __restrict__ Lp, bf16* __restrict__ Oh, bf16* __restrict__ Ol,
    const int NS)
{
    const int row = blockIdx.x * 32 + (threadIdx.x >> 3);
    const int d0 = (threadIdx.x & 7) * 8;
    const size_t part = (size_t)B_N * S_LEN;

    float m = -1e30f;
    #pragma unroll 4
    for (int i = 0; i < NS; ++i) m = fmaxf(m, Mp[i * part + row]);

    float oacc[8];
    #pragma unroll
    for (int jj = 0; jj < 8; ++jj) oacc[jj] = 0.f;
    float denom = 0.f;
    #pragma unroll 4
    for (int i = 0; i < NS; ++i) {
        const float wi = exp2f(Mp[i * part + row] - m);
        denom += Lp[i * part + row] * wi;
        const float* pi = Op + (i * part + row) * DKV + d0;
        #pragma unroll
        for (int jj = 0; jj < 8; ++jj) oacc[jj] += pi[jj] * wi;
    }
    const float inv = 1.0f / denom;

    union Pack8 { uint4 u; unsigned short s[8]; };
    Pack8 ph, pl;
    #pragma unroll
    for (int jj = 0; jj < 8; ++jj) {
        const float o = oacc[jj] * inv;
        const unsigned short hb = f2bits(o);
        ph.s[jj] = hb;
        pl.s[jj] = f2bits(o - bits2f(hb));
    }
    *(uint4*)&Oh[(size_t)row * DKV + d0] = ph.u;
    *(uint4*)&Ol[(size_t)row * DKV + d0] = pl.u;
}

// ---------------------------------------------------------------------------
// Kernel 3 (bf16 path): output projection, A hi/lo x W hi. Dead when fp32.
// ---------------------------------------------------------------------------
#define PSTR 72
__global__ __launch_bounds__(256) void proj_mfma_bf16(
    const bf16* __restrict__ Oh, const bf16* __restrict__ Ol,
    const bf16* __restrict__ WoFh, const float* __restrict__ ball2,
    bf16* __restrict__ out, const int* __restrict__ flag)
{
    if (*flag) return;
    __shared__ unsigned short Ah[32 * PSTR], Al[32 * PSTR];
    const int tid = threadIdx.x;
    const int rowBase = blockIdx.x * 32;

    {
        const int r = tid >> 3, c0 = (tid & 7) * 8;
        *(uint4*)&Ah[r * PSTR + c0] = *(const uint4*)&Oh[(size_t)(rowBase + r) * DKV + c0];
        *(uint4*)&Al[r * PSTR + c0] = *(const uint4*)&Ol[(size_t)(rowBase + r) * DKV + c0];
    }
    __syncthreads();

    const int lane = tid & 63;
    const int w    = tid >> 6;
    const int quad = lane >> 4;
    const int l15  = lane & 15;
    const int wr   = w & 1;
    const int wcq  = w >> 1;

    const int aoff = (wr * 16 + l15) * PSTR + quad * 8;
    const short8 ah0 = *(const short8*)&Ah[aoff];
    const short8 ah1 = *(const short8*)&Ah[aoff + 32];
    const short8 al0 = *(const short8*)&Al[aoff];
    const short8 al1 = *(const short8*)&Al[aoff + 32];

    floatx4 acc[16];
    #pragma unroll
    for (int ct = 0; ct < 16; ++ct) acc[ct] = (floatx4){0.f, 0.f, 0.f, 0.f};

    #pragma unroll
    for (int ct = 0; ct < 16; ++ct) {
        const int ctile = wcq * 16 + ct;
        const size_t o0 = (((size_t)ctile * 2 + 0) * 64 + lane) * 8;
        const size_t o1 = (((size_t)ctile * 2 + 1) * 64 + lane) * 8;
        const short8 bh0 = *(const short8*)&WoFh[o0];
        const short8 bh1 = *(const short8*)&WoFh[o1];
        acc[ct] = MFMA(ah0, bh0, acc[ct]);
        acc[ct] = MFMA(ah1, bh1, acc[ct]);
        acc[ct] = MFMA(al0, bh0, acc[ct]);
        acc[ct] = MFMA(al1, bh1, acc[ct]);
    }

    #pragma unroll
    for (int ct = 0; ct < 16; ++ct) {
        const int col = wcq * 256 + ct * 16 + l15;
        const float bias = ball2[col];
        #pragma unroll
        for (int r = 0; r < 4; ++r) {
            const int row = rowBase + wr * 16 + quad * 4 + r;
            out[(size_t)row * D_MODEL + col] = __float2bfloat16(acc[ct][r] + bias);
        }
    }
}

// ---------------------------------------------------------------------------
// Kernel 3 (fp32 LIVE path): 6-term hi/lo on both operands, fp32 output.
// ---------------------------------------------------------------------------
__global__ __launch_bounds__(512) void proj_mfma_f32(
    const bf16* __restrict__ Oh, const bf16* __restrict__ Ol,
    const bf16* __restrict__ WoFh, const bf16* __restrict__ WoFl,
    const float* __restrict__ ball2, float* __restrict__ out,
    const int* __restrict__ flag)
{
    if (!*flag) return;
    __shared__ unsigned short Ah[32 * PSTR], Al[32 * PSTR];
    const int tid = threadIdx.x;
    const int rowBase = blockIdx.x * 32;

    {   // 512 chunks: threads 0..255 -> Ah, 256..511 -> Al
        const int r = (tid & 255) >> 3, c0 = (tid & 7) * 8;
        if (tid < 256)
            *(uint4*)&Ah[r * PSTR + c0] = *(const uint4*)&Oh[(size_t)(rowBase + r) * DKV + c0];
        else
            *(uint4*)&Al[r * PSTR + c0] = *(const uint4*)&Ol[(size_t)(rowBase + r) * DKV + c0];
    }
    __syncthreads();

    const int lane = tid & 63;
    const int w    = tid >> 6;           // 0..7
    const int quad = lane >> 4;
    const int l15  = lane & 15;
    const int wr   = w & 1;
    const int wcq  = w >> 1;             // 0..3 col quarter (128 cols)

    const int aoff = (wr * 16 + l15) * PSTR + quad * 8;
    const short8 ah0 = *(const short8*)&Ah[aoff];
    const short8 ah1 = *(const short8*)&Ah[aoff + 32];
    const short8 al0 = *(const short8*)&Al[aoff];
    const short8 al1 = *(const short8*)&Al[aoff + 32];

    floatx4 acc[8];
    #pragma unroll
    for (int ct = 0; ct < 8; ++ct) acc[ct] = (floatx4){0.f, 0.f, 0.f, 0.f};

    #pragma unroll
    for (int ct = 0; ct < 8; ++ct) {
        const int ctile = wcq * 8 + ct;
        const size_t o0 = (((size_t)ctile * 2 + 0) * 64 + lane) * 8;
        const size_t o1 = (((size_t)ctile * 2 + 1) * 64 + lane) * 8;
        const short8 bh0 = *(const short8*)&WoFh[o0];
        const short8 bh1 = *(const short8*)&WoFh[o1];
        const short8 bl0 = *(const short8*)&WoFl[o0];
        const short8 bl1 = *(const short8*)&WoFl[o1];
        acc[ct] = MFMA(ah0, bh0, acc[ct]);
        acc[ct] = MFMA(ah1, bh1, acc[ct]);
        acc[ct] = MFMA(ah0, bl0, acc[ct]);
        acc[ct] = MFMA(ah1, bl1, acc[ct]);
        acc[ct] = MFMA(al0, bh0, acc[ct]);
        acc[ct] = MFMA(al1, bh1, acc[ct]);
    }

    #pragma unroll
    for (int ct = 0; ct < 8; ++ct) {
        const int col = wcq * 128 + ct * 16 + l15;
        const float bias = ball2[col];
        #pragma unroll
        for (int r = 0; r < 4; ++r) {
            const int row = rowBase + wr * 16 + quad * 4 + r;
            out[(size_t)row * D_MODEL + col] = acc[ct][r] + bias;
        }
    }
}

extern "C" void kernel_launch(void* const* d_in, const int* in_sizes, int n_in,
                              void* d_out, int out_size, void* d_ws, size_t ws_size,
                              hipStream_t stream) {
    const void* x  = d_in[0];
    const void* Wq = d_in[1];
    const void* bq = d_in[2];
    const void* Wk = d_in[3];
    const void* bk = d_in[4];
    const void* Wv = d_in[5];
    const void* bv = d_in[6];
    const void* Wo = d_in[7];
    const void* bo = d_in[8];

    const int rows = B_N * S_LEN;                 // 16384
    // split-K factor: 4 needs ~28.5 MB workspace; fall back to 2 if tight
    const int NS = (ws_size >= (size_t)30 * 1024 * 1024) ? 4 : 2;

    char* p = (char*)d_ws;
    int*  flag = (int*)p;                          p += 256;
    bf16* Qb = (bf16*)p;                           p += (size_t)rows * DKV * 2;   // 2 MB
    bf16* Kb = (bf16*)p;                           p += (size_t)rows * DKV * 2;
    bf16* Vt = (bf16*)p;                           p += (size_t)rows * DKV * 2;
    bf16* Wfh = (bf16*)p;                          p += (size_t)12 * 16 * 64 * 8 * 2;  // 196.6 KB
    bf16* Wfl = (bf16*)p;                          p += (size_t)12 * 16 * 64 * 8 * 2;
    float* ball = (float*)p;                       p += 1024;
    bf16* WoFh = (bf16*)p;                         p += (size_t)32 * 2 * 64 * 8 * 2;   // 64 KB
    bf16* WoFl = (bf16*)p;                         p += (size_t)32 * 2 * 64 * 8 * 2;
    float* ball2 = (float*)p;                      p += D_MODEL * 4;
    float* Op = (float*)p;                         p += (size_t)NS * rows * DKV * 4; // 8/16 MB
    float* Mp = (float*)p;                         p += (size_t)NS * rows * 4;
    float* Lp = (float*)p;                         p += (size_t)NS * rows * 4;
    bf16* Ohb = (bf16*)p;                          p += (size_t)rows * DKV * 2;
    bf16* Olb = (bf16*)p;                          p += (size_t)rows * DKV * 2;

    detect_kernel<<<1, 64, 0, stream>>>(x, flag);
    wprep_qkv_frag<<<12, 512, 0, stream>>>(Wq, bq, Wk, bk, Wv, bv, Wfh, Wfl, ball, flag);
    wprep_o_frag<<<32, 512, 0, stream>>>(Wo, bo, WoFh, WoFl, ball2, flag);
    qkv_mfma_bf16<<<512, 256, 0, stream>>>(x, Wfh, ball, Qb, Kb, Vt, flag);
    qkv_mfma_f32<<<512, 512, 0, stream>>>(x, Wfh, Wfl, ball, Qb, Kb, Vt, flag);
    attn_mfma<<<256 * NS, 256, 0, stream>>>(Qb, Kb, Vt, Op, Mp, Lp, NS);
    merge_kernel<<<512, 256, 0, stream>>>(Op, Mp, Lp, Ohb, Olb, NS);
    proj_mfma_bf16<<<512, 256, 0, stream>>>(Ohb, Olb, WoFh, ball2, (bf16*)d_out, flag);
    proj_mfma_f32<<<512, 512, 0, stream>>>(Ohb, Olb, WoFh, WoFl, ball2, (float*)d_out, flag);
}

// Round 8
// 173.011 us; speedup vs baseline: 2.9829x; 1.0515x over previous
//
#include <hip/hip_runtime.h>
#include <hip/hip_bf16.h>

#define S_LEN 4096
#define D_MODEL 512
#define DKV 64
#define B_N 4
#define STR 72    // K-tile LDS row stride (elems)
#define VSTR 136  // V/P LDS row stride (elems), 128 keys + pad

typedef __hip_bfloat16 bf16;
typedef __attribute__((ext_vector_type(8))) short short8;   // 8 bf16 (4 VGPRs)
typedef __attribute__((ext_vector_type(4))) float floatx4;  // MFMA C/D

#define MFMA(a, b, c) __builtin_amdgcn_mfma_f32_16x16x32_bf16(a, b, c, 0, 0, 0)

__device__ __forceinline__ float b2f(bf16 v) { return __bfloat162float(v); }

__device__ __forceinline__ unsigned short f2bits(float v) {
    union { bf16 h; unsigned short u; } cv;
    cv.h = __float2bfloat16(v);
    return cv.u;
}
__device__ __forceinline__ float bits2f(unsigned short u) {
    union { bf16 h; unsigned short u; } cv;
    cv.u = u;
    return b2f(cv.h);
}

// ---------------------------------------------------------------------------
// Kernel 0: dtype detect (value-based; proven). flag=1 -> fp32 inputs.
// ---------------------------------------------------------------------------
__global__ __launch_bounds__(64) void detect_kernel(const void* x, int* flag) {
    const int lane = threadIdx.x;
    const bf16* xb = (const bf16*)x;
    int bad = 0;
    for (int k = lane; k < 4096; k += 64) {
        float v = fabsf(b2f(xb[2 * k]));
        if (!(v < 64.f)) bad++;
    }
    #pragma unroll
    for (int off = 32; off >= 1; off >>= 1) bad += __shfl_xor(bad, off);
    if (lane == 0) *flag = (bad > 100) ? 1 : 0;
}

// ---------------------------------------------------------------------------
// Kernel 1a: QKV W prep -> FRAGMENT-PACKED layout (proven R6).
// ---------------------------------------------------------------------------
__global__ __launch_bounds__(512) void wprep_qkv_frag(
    const void* __restrict__ Wq, const void* __restrict__ bq,
    const void* __restrict__ Wk, const void* __restrict__ bk,
    const void* __restrict__ Wv, const void* __restrict__ bv,
    bf16* __restrict__ Wfh, bf16* __restrict__ Wfl, float* __restrict__ ball,
    const int* __restrict__ flag)
{
    __shared__ float xs[16][513];        // [col][k], padded
    const int ct = blockIdx.x;           // 0..11
    const int c0 = ct * 16;
    const int g = c0 >> 6;               // 0=Q 1=K 2=V
    const int cc0 = c0 & 63;
    const void* W    = (g == 0) ? Wq : (g == 1) ? Wk : Wv;
    const void* bias = (g == 0) ? bq : (g == 1) ? bk : bv;
    const int tid = threadIdx.x;
    const int f32 = *flag;

    #pragma unroll
    for (int i = 0; i < 16; ++i) {
        const int idx = tid + 512 * i;   // 0..8191
        const int d = idx >> 4, j = idx & 15;
        const float v = f32 ? ((const float*)W)[(size_t)d * DKV + cc0 + j]
                            : b2f(((const bf16*)W)[(size_t)d * DKV + cc0 + j]);
        xs[j][d] = v;
    }
    __syncthreads();

    union Pack8 { uint4 u; unsigned short s[8]; };
    #pragma unroll
    for (int rep = 0; rep < 2; ++rep) {
        const int f = tid + rep * 512;   // fragment id: kt*64 + lane
        const int kt = f >> 6, lane = f & 63;
        const int quad = lane >> 4, l15 = lane & 15;
        Pack8 ph, pl;
        #pragma unroll
        for (int j = 0; j < 8; ++j) {
            const float v = xs[l15][kt * 32 + quad * 8 + j];
            const unsigned short hb = f2bits(v);
            ph.s[j] = hb;
            pl.s[j] = f2bits(v - bits2f(hb));
        }
        const size_t o = (((size_t)ct * 16 + kt) * 64 + lane) * 8;
        *(uint4*)&Wfh[o] = ph.u;
        *(uint4*)&Wfl[o] = pl.u;
    }
    if (tid < 16)
        ball[c0 + tid] = f32 ? ((const float*)bias)[cc0 + tid]
                             : b2f(((const bf16*)bias)[cc0 + tid]);
}

// ---------------------------------------------------------------------------
// Kernel 1a': Wo prep -> fragment-packed (proven R6).
// ---------------------------------------------------------------------------
__global__ __launch_bounds__(512) void wprep_o_frag(
    const void* __restrict__ Wo, const void* __restrict__ bo,
    bf16* __restrict__ WoFh, bf16* __restrict__ WoFl,
    float* __restrict__ ball2, const int* __restrict__ flag)
{
    __shared__ float ys[16][65];         // [col][k]
    const int ctile = blockIdx.x;        // 0..31
    const int c0 = ctile * 16;
    const int tid = threadIdx.x;
    const int f32 = *flag;

    #pragma unroll
    for (int rep = 0; rep < 2; ++rep) {
        const int idx = tid + rep * 512; // 0..1023
        const int d = idx >> 4, j = idx & 15;
        const float v = f32 ? ((const float*)Wo)[(size_t)d * D_MODEL + c0 + j]
                            : b2f(((const bf16*)Wo)[(size_t)d * D_MODEL + c0 + j]);
        ys[j][d] = v;
    }
    __syncthreads();

    union Pack8 { uint4 u; unsigned short s[8]; };
    if (tid < 128) {
        const int kc = tid >> 6, lane = tid & 63;
        const int quad = lane >> 4, l15 = lane & 15;
        Pack8 ph, pl;
        #pragma unroll
        for (int j = 0; j < 8; ++j) {
            const float v = ys[l15][kc * 32 + quad * 8 + j];
            const unsigned short hb = f2bits(v);
            ph.s[j] = hb;
            pl.s[j] = f2bits(v - bits2f(hb));
        }
        const size_t o = (((size_t)ctile * 2 + kc) * 64 + lane) * 8;
        *(uint4*)&WoFh[o] = ph.u;
        *(uint4*)&WoFl[o] = pl.u;
    }
    if (tid < 16)
        ball2[c0 + tid] = f32 ? ((const float*)bo)[c0 + tid]
                              : b2f(((const bf16*)bo)[c0 + tid]);
}

// ---------------------------------------------------------------------------
// Kernel 1b (bf16 path): QKV projection, single-term MFMA. Dead when fp32.
// ---------------------------------------------------------------------------
__global__ __launch_bounds__(256) void qkv_mfma_bf16(
    const void* __restrict__ x,
    const bf16* __restrict__ Wfh, const float* __restrict__ ball,
    bf16* __restrict__ Qb, bf16* __restrict__ Kb, bf16* __restrict__ Vt,
    const int* __restrict__ flag)
{
    if (*flag) return;
    __shared__ unsigned short hiA[32 * D_MODEL];   // 32 KB
    const int tid = threadIdx.x;
    const int rowBase = blockIdx.x * 32;

    const unsigned short* xr = (const unsigned short*)x + (size_t)rowBase * D_MODEL;
    #pragma unroll
    for (int i = 0; i < 8; ++i) {
        const int idx = tid + 256 * i;
        const int r = idx >> 6;
        const int c0 = (idx & 63) << 3;
        const uint4 hv = *(const uint4*)&xr[r * D_MODEL + c0];
        const int boff = (c0 * 2) ^ ((r & 7) << 4);
        *(uint4*)((char*)hiA + r * 1024 + boff) = hv;
    }
    __syncthreads();

    const int lane = tid & 63;
    const int w    = tid >> 6;
    const int quad = lane >> 4;
    const int l15  = lane & 15;
    const int wr   = w & 1;
    const int wcol = w >> 1;
    const int arow = wr * 16 + l15;
    const char* hib = (const char*)hiA + arow * 1024;
    const int swz = (arow & 7) << 4;

    floatx4 acc[6];
    #pragma unroll
    for (int ct = 0; ct < 6; ++ct) acc[ct] = (floatx4){0.f, 0.f, 0.f, 0.f};

    for (int kt = 0; kt < 16; ++kt) {
        const int boff = (kt * 64 + quad * 16) ^ swz;
        const short8 ah = *(const short8*)(hib + boff);
        #pragma unroll
        for (int ct = 0; ct < 6; ++ct) {
            const size_t fo = (((size_t)(wcol * 6 + ct) * 16 + kt) * 64 + lane) * 8;
            const short8 bh = *(const short8*)&Wfh[fo];
            acc[ct] = MFMA(ah, bh, acc[ct]);
        }
    }

    #pragma unroll
    for (int ct = 0; ct < 6; ++ct) {
        const int gc = wcol * 96 + ct * 16 + l15;
        const float bias = ball[gc];
        const float scale = (gc < 64) ? 0.18033688f : 1.0f;
        #pragma unroll
        for (int r = 0; r < 4; ++r) {
            const int gr = rowBase + wr * 16 + quad * 4 + r;
            const bf16 o = __float2bfloat16((acc[ct][r] + bias) * scale);
            if (gc < 64)       Qb[(size_t)gr * DKV + gc] = o;
            else if (gc < 128) Kb[(size_t)gr * DKV + (gc - 64)] = o;
            else {
                const int bb = gr >> 12, sidx = gr & (S_LEN - 1);
                Vt[((size_t)bb * DKV + (gc - 128)) * S_LEN + sidx] = o;
            }
        }
    }
}

// ---------------------------------------------------------------------------
// Kernel 1b (fp32 LIVE path): 3-term hi/lo split MFMA GEMM (proven R6).
// ---------------------------------------------------------------------------
__global__ __launch_bounds__(512) void qkv_mfma_f32(
    const void* __restrict__ x,
    const bf16* __restrict__ Wfh, const bf16* __restrict__ Wfl,
    const float* __restrict__ ball,
    bf16* __restrict__ Qb, bf16* __restrict__ Kb, bf16* __restrict__ Vt,
    const int* __restrict__ flag)
{
    if (!*flag) return;
    __shared__ unsigned short hiA[32 * D_MODEL];   // 32 KB
    __shared__ unsigned short loA[32 * D_MODEL];   // 32 KB
    const int tid = threadIdx.x;
    const int rowBase = blockIdx.x * 32;

    union Pack8 { uint4 u; unsigned short s[8]; };
    {
        const float* xr = (const float*)x + (size_t)rowBase * D_MODEL;
        #pragma unroll
        for (int i = 0; i < 4; ++i) {
            const int idx = tid + 512 * i;       // 2048 8-elem chunks
            const int r = idx >> 6;
            const int c0 = (idx & 63) << 3;
            const float4 v0 = *(const float4*)&xr[r * D_MODEL + c0];
            const float4 v1 = *(const float4*)&xr[r * D_MODEL + c0 + 4];
            const float vv[8] = {v0.x, v0.y, v0.z, v0.w, v1.x, v1.y, v1.z, v1.w};
            Pack8 ph, pl;
            #pragma unroll
            for (int j = 0; j < 8; ++j) {
                const unsigned short hb = f2bits(vv[j]);
                ph.s[j] = hb;
                pl.s[j] = f2bits(vv[j] - bits2f(hb));
            }
            const int boff = (c0 * 2) ^ ((r & 7) << 4);
            *(uint4*)((char*)hiA + r * 1024 + boff) = ph.u;
            *(uint4*)((char*)loA + r * 1024 + boff) = pl.u;
        }
    }
    __syncthreads();

    const int lane = tid & 63;
    const int w    = tid >> 6;           // 0..7
    const int quad = lane >> 4;
    const int l15  = lane & 15;
    const int wr   = w & 1;              // row half (16 rows)
    const int wq   = w >> 1;             // col quarter (48 cols = 3 tiles)
    const int arow = wr * 16 + l15;
    const char* hib = (const char*)hiA + arow * 1024;
    const char* lob = (const char*)loA + arow * 1024;
    const int swz = (arow & 7) << 4;

    floatx4 acc[3];
    #pragma unroll
    for (int ct = 0; ct < 3; ++ct) acc[ct] = (floatx4){0.f, 0.f, 0.f, 0.f};

    for (int kt = 0; kt < 16; ++kt) {
        const int boff = (kt * 64 + quad * 16) ^ swz;
        const short8 ah = *(const short8*)(hib + boff);
        const short8 al = *(const short8*)(lob + boff);
        #pragma unroll
        for (int ct = 0; ct < 3; ++ct) {
            const size_t fo = (((size_t)(wq * 3 + ct) * 16 + kt) * 64 + lane) * 8;
            const short8 bh = *(const short8*)&Wfh[fo];
            const short8 bl = *(const short8*)&Wfl[fo];
            acc[ct] = MFMA(ah, bh, acc[ct]);
            acc[ct] = MFMA(ah, bl, acc[ct]);
            acc[ct] = MFMA(al, bh, acc[ct]);
        }
    }

    #pragma unroll
    for (int ct = 0; ct < 3; ++ct) {
        const int gc = wq * 48 + ct * 16 + l15;
        const float bias = ball[gc];
        const float scale = (gc < 64) ? 0.18033688f : 1.0f;
        #pragma unroll
        for (int r = 0; r < 4; ++r) {
            const int gr = rowBase + wr * 16 + quad * 4 + r;
            const bf16 o = __float2bfloat16((acc[ct][r] + bias) * scale);
            if (gc < 64)       Qb[(size_t)gr * DKV + gc] = o;
            else if (gc < 128) Kb[(size_t)gr * DKV + (gc - 64)] = o;
            else {
                const int bb = gr >> 12, sidx = gr & (S_LEN - 1);
                Vt[((size_t)bb * DKV + (gc - 128)) * S_LEN + sidx] = o;
            }
        }
    }
}

// ---------------------------------------------------------------------------
// Kernel 2: MFMA flash attention v4. BM=64, 4 waves, wave-private softmax.
// NEW: softmax denominator l computed by MFMA with a constant all-ones
// B-fragment (l = P . 1) -- accl is rescaled by alpha like the O accumulator,
// every lane ends with the row sum (all 16 ones-columns identical). The
// 16-lane sum butterfly + 32 VALU adds per iter are deleted.
// ---------------------------------------------------------------------------
__global__ __launch_bounds__(256, 3) void attn_mfma(
    const bf16* __restrict__ Qg, const bf16* __restrict__ Kg,
    const bf16* __restrict__ Vtg, float* __restrict__ Op,
    float* __restrict__ Mp, float* __restrict__ Lp, const int NS)
{
    const int bid = blockIdx.x;
    const int xcd = bid & 7;
    const int rest = bid >> 3;
    const int b   = xcd >> 1;
    const int khH = (NS == 4) ? (rest & 1) : 0;
    const int t64 = 63 - ((NS == 4) ? (rest >> 1) : rest);
    const int kh  = khH * 2 + (xcd & 1);
    const int rowBase = t64 * 64;
    const int tid = threadIdx.x;
    const int lane = tid & 63;
    const int w  = tid >> 6;             // wave: rows w*16..w*16+16
    const int quad = lane >> 4;
    const int l15  = lane & 15;

    __shared__ bf16 Kl[128 * STR];       // [key][dim]     18.0 KB
    __shared__ bf16 Vl[64 * VSTR];       // [vdim][key]    17.0 KB
    __shared__ bf16 Pl[64 * VSTR];       // [row][key]     17.0 KB; Q staging
    // total 52 KB -> 3 blocks/CU

    const bf16* Qb = Qg + ((size_t)b * S_LEN + rowBase) * DKV;
    const bf16* Kb = Kg + (size_t)b * S_LEN * DKV;
    const bf16* Vb = Vtg + (size_t)b * DKV * S_LEN;

    // stage Q tile (64x64) into Pl rows, load A-fragments once
    {
        const int qr = tid >> 2, qd = (tid & 3) * 16;
        *(uint4*)&Pl[qr * VSTR + qd]     = *(const uint4*)&Qb[qr * DKV + qd];
        *(uint4*)&Pl[qr * VSTR + qd + 8] = *(const uint4*)&Qb[qr * DKV + qd + 8];
    }
    __syncthreads();
    short8 qf0, qf1;
    {
        const int qoff = (w * 16 + l15) * VSTR + quad * 8;
        qf0 = *(const short8*)&Pl[qoff];
        qf1 = *(const short8*)&Pl[qoff + 32];
    }

    const short s1b = (short)0x3F80;     // bf16 1.0
    const short8 ones = {s1b, s1b, s1b, s1b, s1b, s1b, s1b, s1b};

    floatx4 acc[4];
    #pragma unroll
    for (int v = 0; v < 4; ++v) acc[v] = (floatx4){0.f, 0.f, 0.f, 0.f};
    floatx4 accl = {0.f, 0.f, 0.f, 0.f};
    float m_run[4];
    #pragma unroll
    for (int r = 0; r < 4; ++r) m_run[r] = -1e30f;

    const int kbMax = (rowBase + 63) >> 7;
    const int kk = tid >> 1, dk = (tid & 1) * 32;   // K staging: 2 thr/row
    const int vd = tid >> 2, vk = (tid & 3) * 32;   // V staging: 4 thr/row

    uint4 kr0, kr1, kr2, kr3, vr0, vr1, vr2, vr3;
    int kb = kh;
    if (kb <= kbMax) {
        const uint4* ks = (const uint4*)&Kb[((size_t)(kb * 128 + kk)) * DKV + dk];
        kr0 = ks[0]; kr1 = ks[1]; kr2 = ks[2]; kr3 = ks[3];
        const uint4* vs = (const uint4*)&Vb[(size_t)vd * S_LEN + kb * 128 + vk];
        vr0 = vs[0]; vr1 = vs[1]; vr2 = vs[2]; vr3 = vs[3];
    }

    for (; kb <= kbMax; kb += NS) {
        __syncthreads();                 // all waves done reading Kl/Vl
        {
            uint4* kd = (uint4*)&Kl[kk * STR + dk];
            kd[0] = kr0; kd[1] = kr1; kd[2] = kr2; kd[3] = kr3;
            uint4* vdst = (uint4*)&Vl[vd * VSTR + vk];
            vdst[0] = vr0; vdst[1] = vr1; vdst[2] = vr2; vdst[3] = vr3;
        }
        __syncthreads();                 // staging visible
        if (kb + NS <= kbMax) {          // prefetch next tile under compute
            const uint4* ks = (const uint4*)&Kb[((size_t)((kb + NS) * 128 + kk)) * DKV + dk];
            kr0 = ks[0]; kr1 = ks[1]; kr2 = ks[2]; kr3 = ks[3];
            const uint4* vs = (const uint4*)&Vb[(size_t)vd * S_LEN + (kb + NS) * 128 + vk];
            vr0 = vs[0]; vr1 = vs[1]; vr2 = vs[2]; vr3 = vs[3];
        }

        // S = Q K^T (Q pre-scaled): eight 16x16 key-tiles per wave
        floatx4 s[8];
        #pragma unroll
        for (int jt = 0; jt < 8; ++jt) s[jt] = (floatx4){0.f, 0.f, 0.f, 0.f};
        {
            const int qk = quad * 8;
            #pragma unroll
            for (int jt = 0; jt < 8; ++jt) {
                const int kc = (jt * 16 + l15) * STR + qk;
                const short8 ba = *(const short8*)&Kl[kc];
                const short8 bb = *(const short8*)&Kl[kc + 32];
                s[jt] = MFMA(qf0, ba, s[jt]);
                s[jt] = MFMA(qf1, bb, s[jt]);
            }
        }
        if (kb == kbMax) {               // causal mask, uniform branch
            const int rowg = rowBase + w * 16 + quad * 4;
            #pragma unroll
            for (int jt = 0; jt < 8; ++jt) {
                const int kg = kb * 128 + jt * 16 + l15;
                #pragma unroll
                for (int r = 0; r < 4; ++r)
                    if (kg > rowg + r) s[jt][r] = -1e30f;
            }
        }
        // wave-private row max: in-thread tree + 16-lane butterfly
        float m4[4];
        #pragma unroll
        for (int r = 0; r < 4; ++r) {
            float mm = s[0][r];
            #pragma unroll
            for (int jt = 1; jt < 8; ++jt) mm = fmaxf(mm, s[jt][r]);
            m4[r] = mm;
        }
        #pragma unroll
        for (int off = 1; off < 16; off <<= 1) {
            #pragma unroll
            for (int r = 0; r < 4; ++r) m4[r] = fmaxf(m4[r], __shfl_xor(m4[r], off));
        }
        float alpha[4];
        #pragma unroll
        for (int r = 0; r < 4; ++r) {
            const float mnew = fmaxf(m_run[r], m4[r]);
            alpha[r] = exp2f(m_run[r] - mnew);   // -1e30 first iter -> 0
            m_run[r] = mnew;
        }
        // P = exp2(S - m); rescale accumulators; write P to wave-private rows
        #pragma unroll
        for (int r = 0; r < 4; ++r) {
            accl[r] *= alpha[r];
            #pragma unroll
            for (int v = 0; v < 4; ++v) acc[v][r] *= alpha[r];
            const int poff = (w * 16 + quad * 4 + r) * VSTR + l15;
            #pragma unroll
            for (int jt = 0; jt < 8; ++jt) {
                const float pp = exp2f(s[jt][r] - m_run[r]);
                Pl[poff + jt * 16] = __float2bfloat16(pp);
            }
        }
        // same-wave LDS RAW: drain writes; "memory" clobber orders the ds_reads
        asm volatile("s_waitcnt lgkmcnt(0)" ::: "memory");

        // O += P V (and l += P . 1 via constant ones B-frag, 4 extra MFMAs)
        {
            const int pk = quad * 8;
            const int prow = (w * 16 + l15) * VSTR;
            short8 pa[4];
            #pragma unroll
            for (int c = 0; c < 4; ++c)
                pa[c] = *(const short8*)&Pl[prow + pk + c * 32];
            #pragma unroll
            for (int c = 0; c < 4; ++c) accl = MFMA(pa[c], ones, accl);
            #pragma unroll
            for (int v = 0; v < 4; ++v) {
                const int vrow = (v * 16 + l15) * VSTR;
                #pragma unroll
                for (int c = 0; c < 4; ++c) {
                    const short8 vb = *(const short8*)&Vl[vrow + pk + c * 32];
                    acc[v] = MFMA(pa[c], vb, acc[v]);
                }
            }
        }
    }
    // epilogue: store unnormalized O + per-row (m, l)
    #pragma unroll
    for (int r = 0; r < 4; ++r) {
        const int row = rowBase + w * 16 + quad * 4 + r;
        float* op = Op + (((size_t)kh * B_N + b) * S_LEN + row) * DKV + l15;
        #pragma unroll
        for (int v = 0; v < 4; ++v) op[v * 16] = acc[v][r];
    }
    if (l15 == 0) {
        #pragma unroll
        for (int r = 0; r < 4; ++r) {
            const int row = rowBase + w * 16 + quad * 4 + r;
            const size_t mi = ((size_t)kh * B_N + b) * S_LEN + row;
            Mp[mi] = m_run[r];
            Lp[mi] = accl[r];
        }
    }
}

// ---------------------------------------------------------------------------
// Kernel 3 (bf16 path): merge fused + output projection, A hi/lo x W hi.
// Dead when fp32.
// ---------------------------------------------------------------------------
#define PSTR 72
__global__ __launch_bounds__(256) void proj_mfma_bf16(
    const float* __restrict__ Op, const float* __restrict__ Mp,
    const float* __restrict__ Lp, const int NS,
    const bf16* __restrict__ WoFh, const float* __restrict__ ball2,
    bf16* __restrict__ out, const int* __restrict__ flag)
{
    if (*flag) return;
    __shared__ unsigned short Ah[32 * PSTR], Al[32 * PSTR];
    const int tid = threadIdx.x;
    const int rowBase = blockIdx.x * 32;

    {   // fused merge: 8 floats per thread (rr = tid>>3, dd = (tid&7)*8)
        const int rr = tid >> 3, dd = (tid & 7) * 8;
        const int row = rowBase + rr;
        const size_t part = (size_t)B_N * S_LEN;
        float m = -1e30f;
        #pragma unroll 4
        for (int i = 0; i < NS; ++i) m = fmaxf(m, Mp[i * part + row]);
        float denom = 0.f;
        float oacc[8] = {0.f, 0.f, 0.f, 0.f, 0.f, 0.f, 0.f, 0.f};
        #pragma unroll 4
        for (int i = 0; i < NS; ++i) {
            const float wi = exp2f(Mp[i * part + row] - m);
            denom += Lp[i * part + row] * wi;
            const float* pi = Op + (i * part + row) * DKV + dd;
            #pragma unroll
            for (int j = 0; j < 8; ++j) oacc[j] += pi[j] * wi;
        }
        const float inv = 1.0f / denom;
        union Pack8 { uint4 u; unsigned short s[8]; };
        Pack8 ph, pl;
        #pragma unroll
        for (int j = 0; j < 8; ++j) {
            const float o = oacc[j] * inv;
            ph.s[j] = f2bits(o);
            pl.s[j] = f2bits(o - bits2f(ph.s[j]));
        }
        *(uint4*)&Ah[rr * PSTR + dd] = ph.u;
        *(uint4*)&Al[rr * PSTR + dd] = pl.u;
    }
    __syncthreads();

    const int lane = tid & 63;
    const int w    = tid >> 6;
    const int quad = lane >> 4;
    const int l15  = lane & 15;
    const int wr   = w & 1;
    const int wcq  = w >> 1;

    const int aoff = (wr * 16 + l15) * PSTR + quad * 8;
    const short8 ah0 = *(const short8*)&Ah[aoff];
    const short8 ah1 = *(const short8*)&Ah[aoff + 32];
    const short8 al0 = *(const short8*)&Al[aoff];
    const short8 al1 = *(const short8*)&Al[aoff + 32];

    floatx4 acc[16];
    #pragma unroll
    for (int ct = 0; ct < 16; ++ct) acc[ct] = (floatx4){0.f, 0.f, 0.f, 0.f};

    #pragma unroll
    for (int ct = 0; ct < 16; ++ct) {
        const int ctile = wcq * 16 + ct;
        const size_t o0 = (((size_t)ctile * 2 + 0) * 64 + lane) * 8;
        const size_t o1 = (((size_t)ctile * 2 + 1) * 64 + lane) * 8;
        const short8 bh0 = *(const short8*)&WoFh[o0];
        const short8 bh1 = *(const short8*)&WoFh[o1];
        acc[ct] = MFMA(ah0, bh0, acc[ct]);
        acc[ct] = MFMA(ah1, bh1, acc[ct]);
        acc[ct] = MFMA(al0, bh0, acc[ct]);
        acc[ct] = MFMA(al1, bh1, acc[ct]);
    }

    #pragma unroll
    for (int ct = 0; ct < 16; ++ct) {
        const int col = wcq * 256 + ct * 16 + l15;
        const float bias = ball2[col];
        #pragma unroll
        for (int r = 0; r < 4; ++r) {
            const int row = rowBase + wr * 16 + quad * 4 + r;
            out[(size_t)row * D_MODEL + col] = __float2bfloat16(acc[ct][r] + bias);
        }
    }
}

// ---------------------------------------------------------------------------
// Kernel 3 (fp32 LIVE path): merge fused + 6-term hi/lo proj, fp32 output.
// ---------------------------------------------------------------------------
__global__ __launch_bounds__(512) void proj_mfma_f32(
    const float* __restrict__ Op, const float* __restrict__ Mp,
    const float* __restrict__ Lp, const int NS,
    const bf16* __restrict__ WoFh, const bf16* __restrict__ WoFl,
    const float* __restrict__ ball2, float* __restrict__ out,
    const int* __restrict__ flag)
{
    if (!*flag) return;
    __shared__ unsigned short Ah[32 * PSTR], Al[32 * PSTR];
    const int tid = threadIdx.x;
    const int rowBase = blockIdx.x * 32;

    {   // fused merge: 4 floats per thread (rr = tid>>4, dd = (tid&15)*4)
        const int rr = tid >> 4, dd = (tid & 15) * 4;
        const int row = rowBase + rr;
        const size_t part = (size_t)B_N * S_LEN;
        float m = -1e30f;
        #pragma unroll 4
        for (int i = 0; i < NS; ++i) m = fmaxf(m, Mp[i * part + row]);
        float denom = 0.f;
        float oacc[4] = {0.f, 0.f, 0.f, 0.f};
        #pragma unroll 4
        for (int i = 0; i < NS; ++i) {
            const float wi = exp2f(Mp[i * part + row] - m);
            denom += Lp[i * part + row] * wi;
            const float4 v = *(const float4*)&Op[(i * part + row) * DKV + dd];
            oacc[0] += v.x * wi; oacc[1] += v.y * wi;
            oacc[2] += v.z * wi; oacc[3] += v.w * wi;
        }
        const float inv = 1.0f / denom;
        union Pack4 { uint2 u; unsigned short s[4]; };
        Pack4 ph, pl;
        #pragma unroll
        for (int j = 0; j < 4; ++j) {
            const float o = oacc[j] * inv;
            ph.s[j] = f2bits(o);
            pl.s[j] = f2bits(o - bits2f(ph.s[j]));
        }
        *(uint2*)&Ah[rr * PSTR + dd] = ph.u;
        *(uint2*)&Al[rr * PSTR + dd] = pl.u;
    }
    __syncthreads();

    const int lane = tid & 63;
    const int w    = tid >> 6;           // 0..7
    const int quad = lane >> 4;
    const int l15  = lane & 15;
    const int wr   = w & 1;
    const int wcq  = w >> 1;             // 0..3 col quarter (128 cols)

    const int aoff = (wr * 16 + l15) * PSTR + quad * 8;
    const short8 ah0 = *(const short8*)&Ah[aoff];
    const short8 ah1 = *(const short8*)&Ah[aoff + 32];
    const short8 al0 = *(const short8*)&Al[aoff];
    const short8 al1 = *(const short8*)&Al[aoff + 32];

    floatx4 acc[8];
    #pragma unroll
    for (int ct = 0; ct < 8; ++ct) acc[ct] = (floatx4){0.f, 0.f, 0.f, 0.f};

    #pragma unroll
    for (int ct = 0; ct < 8; ++ct) {
        const int ctile = wcq * 8 + ct;
        const size_t o0 = (((size_t)ctile * 2 + 0) * 64 + lane) * 8;
        const size_t o1 = (((size_t)ctile * 2 + 1) * 64 + lane) * 8;
        const short8 bh0 = *(const short8*)&WoFh[o0];
        const short8 bh1 = *(const short8*)&WoFh[o1];
        const short8 bl0 = *(const short8*)&WoFl[o0];
        const short8 bl1 = *(const short8*)&WoFl[o1];
        acc[ct] = MFMA(ah0, bh0, acc[ct]);
        acc[ct] = MFMA(ah1, bh1, acc[ct]);
        acc[ct] = MFMA(ah0, bl0, acc[ct]);
        acc[ct] = MFMA(ah1, bl1, acc[ct]);
        acc[ct] = MFMA(al0, bh0, acc[ct]);
        acc[ct] = MFMA(al1, bh1, acc[ct]);
    }

    #pragma unroll
    for (int ct = 0; ct < 8; ++ct) {
        const int col = wcq * 128 + ct * 16 + l15;
        const float bias = ball2[col];
        #pragma unroll
        for (int r = 0; r < 4; ++r) {
            const int row = rowBase + wr * 16 + quad * 4 + r;
            out[(size_t)row * D_MODEL + col] = acc[ct][r] + bias;
        }
    }
}

extern "C" void kernel_launch(void* const* d_in, const int* in_sizes, int n_in,
                              void* d_out, int out_size, void* d_ws, size_t ws_size,
                              hipStream_t stream) {
    const void* x  = d_in[0];
    const void* Wq = d_in[1];
    const void* bq = d_in[2];
    const void* Wk = d_in[3];
    const void* bk = d_in[4];
    const void* Wv = d_in[5];
    const void* bv = d_in[6];
    const void* Wo = d_in[7];
    const void* bo = d_in[8];

    const int rows = B_N * S_LEN;                 // 16384
    // split-K factor: 4 needs ~24 MB workspace; fall back to 2 if tight
    const int NS = (ws_size >= (size_t)30 * 1024 * 1024) ? 4 : 2;

    char* p = (char*)d_ws;
    int*  flag = (int*)p;                          p += 256;
    bf16* Qb = (bf16*)p;                           p += (size_t)rows * DKV * 2;   // 2 MB
    bf16* Kb = (bf16*)p;                           p += (size_t)rows * DKV * 2;
    bf16* Vt = (bf16*)p;                           p += (size_t)rows * DKV * 2;
    bf16* Wfh = (bf16*)p;                          p += (size_t)12 * 16 * 64 * 8 * 2;  // 196.6 KB
    bf16* Wfl = (bf16*)p;                          p += (size_t)12 * 16 * 64 * 8 * 2;
    float* ball = (float*)p;                       p += 1024;
    bf16* WoFh = (bf16*)p;                         p += (size_t)32 * 2 * 64 * 8 * 2;   // 64 KB
    bf16* WoFl = (bf16*)p;                         p += (size_t)32 * 2 * 64 * 8 * 2;
    float* ball2 = (float*)p;                      p += D_MODEL * 4;
    float* Op = (float*)p;                         p += (size_t)NS * rows * DKV * 4; // 8/16 MB
    float* Mp = (float*)p;                         p += (size_t)NS * rows * 4;
    float* Lp = (float*)p;                         p += (size_t)NS * rows * 4;

    detect_kernel<<<1, 64, 0, stream>>>(x, flag);
    wprep_qkv_frag<<<12, 512, 0, stream>>>(Wq, bq, Wk, bk, Wv, bv, Wfh, Wfl, ball, flag);
    wprep_o_frag<<<32, 512, 0, stream>>>(Wo, bo, WoFh, WoFl, ball2, flag);
    qkv_mfma_bf16<<<512, 256, 0, stream>>>(x, Wfh, ball, Qb, Kb, Vt, flag);
    qkv_mfma_f32<<<512, 512, 0, stream>>>(x, Wfh, Wfl, ball, Qb, Kb, Vt, flag);
    attn_mfma<<<256 * NS, 256, 0, stream>>>(Qb, Kb, Vt, Op, Mp, Lp, NS);
    proj_mfma_bf16<<<512, 256, 0, stream>>>(Op, Mp, Lp, NS, WoFh, ball2, (bf16*)d_out, flag);
    proj_mfma_f32<<<512, 512, 0, stream>>>(Op, Mp, Lp, NS, WoFh, WoFl, ball2, (float*)d_out, flag);
}

// Round 10
// 171.784 us; speedup vs baseline: 3.0042x; 1.0071x over previous
//
#include <hip/hip_runtime.h>
#include <hip/hip_bf16.h>

#define S_LEN 4096
#define D_MODEL 512
#define DKV 64
#define B_N 4
#define STR 72    // K-tile LDS row stride (elems)
#define VSTR 136  // V/P LDS row stride (elems), 128 keys + pad

typedef __hip_bfloat16 bf16;
typedef __attribute__((ext_vector_type(8))) short short8;   // 8 bf16 (4 VGPRs)
typedef __attribute__((ext_vector_type(4))) float floatx4;  // MFMA C/D

#define MFMA(a, b, c) __builtin_amdgcn_mfma_f32_16x16x32_bf16(a, b, c, 0, 0, 0)

__device__ __forceinline__ float b2f(bf16 v) { return __bfloat162float(v); }

__device__ __forceinline__ unsigned short f2bits(float v) {
    union { bf16 h; unsigned short u; } cv;
    cv.h = __float2bfloat16(v);
    return cv.u;
}
__device__ __forceinline__ float bits2f(unsigned short u) {
    union { bf16 h; unsigned short u; } cv;
    cv.u = u;
    return b2f(cv.h);
}

// ---------------------------------------------------------------------------
// Kernel 0: dtype detect (value-based; proven). flag=1 -> fp32 inputs.
// ---------------------------------------------------------------------------
__global__ __launch_bounds__(64) void detect_kernel(const void* x, int* flag) {
    const int lane = threadIdx.x;
    const bf16* xb = (const bf16*)x;
    int bad = 0;
    for (int k = lane; k < 4096; k += 64) {
        float v = fabsf(b2f(xb[2 * k]));
        if (!(v < 64.f)) bad++;
    }
    #pragma unroll
    for (int off = 32; off >= 1; off >>= 1) bad += __shfl_xor(bad, off);
    if (lane == 0) *flag = (bad > 100) ? 1 : 0;
}

// ---------------------------------------------------------------------------
// Kernel 1a (unified W prep): blocks 0..11 -> Wq/Wk/Wv fragment-pack (16 cols
// each, hi/lo); blocks 12..43 -> Wo fragment-pack. Proven layouts from R6.
// ---------------------------------------------------------------------------
__global__ __launch_bounds__(512) void wprep_kernel(
    const void* __restrict__ Wq, const void* __restrict__ bq,
    const void* __restrict__ Wk, const void* __restrict__ bk,
    const void* __restrict__ Wv, const void* __restrict__ bv,
    const void* __restrict__ Wo, const void* __restrict__ bo,
    bf16* __restrict__ Wfh, bf16* __restrict__ Wfl, float* __restrict__ ball,
    bf16* __restrict__ WoFh, bf16* __restrict__ WoFl, float* __restrict__ ball2,
    const int* __restrict__ flag)
{
    __shared__ float xs[16][513];        // [col][k], padded
    const int blk = blockIdx.x;
    const int tid = threadIdx.x;
    const int f32 = *flag;
    union Pack8 { uint4 u; unsigned short s[8]; };

    if (blk < 12) {                      // ---- QKV W prep ----
        const int ct = blk;
        const int c0 = ct * 16;
        const int g = c0 >> 6;           // 0=Q 1=K 2=V
        const int cc0 = c0 & 63;
        const void* W    = (g == 0) ? Wq : (g == 1) ? Wk : Wv;
        const void* bias = (g == 0) ? bq : (g == 1) ? bk : bv;

        #pragma unroll
        for (int i = 0; i < 16; ++i) {
            const int idx = tid + 512 * i;   // 0..8191
            const int d = idx >> 4, j = idx & 15;
            const float v = f32 ? ((const float*)W)[(size_t)d * DKV + cc0 + j]
                                : b2f(((const bf16*)W)[(size_t)d * DKV + cc0 + j]);
            xs[j][d] = v;
        }
        __syncthreads();

        #pragma unroll
        for (int rep = 0; rep < 2; ++rep) {
            const int f = tid + rep * 512;   // fragment id: kt*64 + lane
            const int kt = f >> 6, lane = f & 63;
            const int quad = lane >> 4, l15 = lane & 15;
            Pack8 ph, pl;
            #pragma unroll
            for (int j = 0; j < 8; ++j) {
                const float v = xs[l15][kt * 32 + quad * 8 + j];
                const unsigned short hb = f2bits(v);
                ph.s[j] = hb;
                pl.s[j] = f2bits(v - bits2f(hb));
            }
            const size_t o = (((size_t)ct * 16 + kt) * 64 + lane) * 8;
            *(uint4*)&Wfh[o] = ph.u;
            *(uint4*)&Wfl[o] = pl.u;
        }
        if (tid < 16)
            ball[c0 + tid] = f32 ? ((const float*)bias)[cc0 + tid]
                                 : b2f(((const bf16*)bias)[cc0 + tid]);
    } else {                             // ---- Wo prep ----
        const int ctile = blk - 12;      // 0..31
        const int c0 = ctile * 16;

        #pragma unroll
        for (int rep = 0; rep < 2; ++rep) {
            const int idx = tid + rep * 512; // 0..1023
            const int d = idx >> 4, j = idx & 15;
            const float v = f32 ? ((const float*)Wo)[(size_t)d * D_MODEL + c0 + j]
                                : b2f(((const bf16*)Wo)[(size_t)d * D_MODEL + c0 + j]);
            xs[j][d] = v;
        }
        __syncthreads();

        if (tid < 128) {
            const int kc = tid >> 6, lane = tid & 63;
            const int quad = lane >> 4, l15 = lane & 15;
            Pack8 ph, pl;
            #pragma unroll
            for (int j = 0; j < 8; ++j) {
                const float v = xs[l15][kc * 32 + quad * 8 + j];
                const unsigned short hb = f2bits(v);
                ph.s[j] = hb;
                pl.s[j] = f2bits(v - bits2f(hb));
            }
            const size_t o = (((size_t)ctile * 2 + kc) * 64 + lane) * 8;
            *(uint4*)&WoFh[o] = ph.u;
            *(uint4*)&WoFl[o] = pl.u;
        }
        if (tid < 16)
            ball2[c0 + tid] = f32 ? ((const float*)bo)[c0 + tid]
                                  : b2f(((const bf16*)bo)[c0 + tid]);
    }
}

// ---------------------------------------------------------------------------
// Kernel 1b (unified QKV projection): block-uniform branch on dtype.
// fp32: 3-term hi/lo split; bf16: single term (x, W exact in bf16).
// 512 blocks x 32 rows, 512 threads = 8 waves (2 row-halves x 4 col-quarters).
// Fragment-packed W: every B-load is a coalesced 1 KB wave load.
// ---------------------------------------------------------------------------
__global__ __launch_bounds__(512) void qkv_mfma(
    const void* __restrict__ x,
    const bf16* __restrict__ Wfh, const bf16* __restrict__ Wfl,
    const float* __restrict__ ball,
    bf16* __restrict__ Qb, bf16* __restrict__ Kb, bf16* __restrict__ Vt,
    const int* __restrict__ flag)
{
    __shared__ unsigned short hiA[32 * D_MODEL];   // 32 KB
    __shared__ unsigned short loA[32 * D_MODEL];   // 32 KB (unused in bf16 path)
    const int tid = threadIdx.x;
    const int rowBase = blockIdx.x * 32;
    const int f32 = *flag;

    union Pack8 { uint4 u; unsigned short s[8]; };
    if (f32) {
        const float* xr = (const float*)x + (size_t)rowBase * D_MODEL;
        #pragma unroll
        for (int i = 0; i < 4; ++i) {
            const int idx = tid + 512 * i;       // 2048 8-elem chunks
            const int r = idx >> 6;
            const int c0 = (idx & 63) << 3;
            const float4 v0 = *(const float4*)&xr[r * D_MODEL + c0];
            const float4 v1 = *(const float4*)&xr[r * D_MODEL + c0 + 4];
            const float vv[8] = {v0.x, v0.y, v0.z, v0.w, v1.x, v1.y, v1.z, v1.w};
            Pack8 ph, pl;
            #pragma unroll
            for (int j = 0; j < 8; ++j) {
                const unsigned short hb = f2bits(vv[j]);
                ph.s[j] = hb;
                pl.s[j] = f2bits(vv[j] - bits2f(hb));
            }
            const int boff = (c0 * 2) ^ ((r & 7) << 4);
            *(uint4*)((char*)hiA + r * 1024 + boff) = ph.u;
            *(uint4*)((char*)loA + r * 1024 + boff) = pl.u;
        }
    } else {
        const unsigned short* xr = (const unsigned short*)x + (size_t)rowBase * D_MODEL;
        #pragma unroll
        for (int i = 0; i < 4; ++i) {
            const int idx = tid + 512 * i;
            const int r = idx >> 6;
            const int c0 = (idx & 63) << 3;
            const uint4 hv = *(const uint4*)&xr[r * D_MODEL + c0];
            const int boff = (c0 * 2) ^ ((r & 7) << 4);
            *(uint4*)((char*)hiA + r * 1024 + boff) = hv;
        }
    }
    __syncthreads();

    const int lane = tid & 63;
    const int w    = tid >> 6;           // 0..7
    const int quad = lane >> 4;
    const int l15  = lane & 15;
    const int wr   = w & 1;              // row half (16 rows)
    const int wq   = w >> 1;             // col quarter (48 cols = 3 tiles)
    const int arow = wr * 16 + l15;
    const char* hib = (const char*)hiA + arow * 1024;
    const char* lob = (const char*)loA + arow * 1024;
    const int swz = (arow & 7) << 4;

    floatx4 acc[3];
    #pragma unroll
    for (int ct = 0; ct < 3; ++ct) acc[ct] = (floatx4){0.f, 0.f, 0.f, 0.f};

    if (f32) {
        for (int kt = 0; kt < 16; ++kt) {
            const int boff = (kt * 64 + quad * 16) ^ swz;
            const short8 ah = *(const short8*)(hib + boff);
            const short8 al = *(const short8*)(lob + boff);
            #pragma unroll
            for (int ct = 0; ct < 3; ++ct) {
                const size_t fo = (((size_t)(wq * 3 + ct) * 16 + kt) * 64 + lane) * 8;
                const short8 bh = *(const short8*)&Wfh[fo];
                const short8 bl = *(const short8*)&Wfl[fo];
                acc[ct] = MFMA(ah, bh, acc[ct]);
                acc[ct] = MFMA(ah, bl, acc[ct]);
                acc[ct] = MFMA(al, bh, acc[ct]);
            }
        }
    } else {
        for (int kt = 0; kt < 16; ++kt) {
            const int boff = (kt * 64 + quad * 16) ^ swz;
            const short8 ah = *(const short8*)(hib + boff);
            #pragma unroll
            for (int ct = 0; ct < 3; ++ct) {
                const size_t fo = (((size_t)(wq * 3 + ct) * 16 + kt) * 64 + lane) * 8;
                const short8 bh = *(const short8*)&Wfh[fo];
                acc[ct] = MFMA(ah, bh, acc[ct]);
            }
        }
    }

    #pragma unroll
    for (int ct = 0; ct < 3; ++ct) {
        const int gc = wq * 48 + ct * 16 + l15;
        const float bias = ball[gc];
        const float scale = (gc < 64) ? 0.18033688f : 1.0f;
        #pragma unroll
        for (int r = 0; r < 4; ++r) {
            const int gr = rowBase + wr * 16 + quad * 4 + r;
            const bf16 o = __float2bfloat16((acc[ct][r] + bias) * scale);
            if (gc < 64)       Qb[(size_t)gr * DKV + gc] = o;
            else if (gc < 128) Kb[(size_t)gr * DKV + (gc - 64)] = o;
            else {
                const int bb = gr >> 12, sidx = gr & (S_LEN - 1);
                Vt[((size_t)bb * DKV + (gc - 128)) * S_LEN + sidx] = o;
            }
        }
    }
}

// ---------------------------------------------------------------------------
// Kernel 2: MFMA flash attention v5. BM=128 rows/block, 8 waves, each wave
// owns 16 rows x ALL 128 keys (wave-private softmax; l via ones-MFMA).
// Each K/V tile serves 128 rows: block-iterations, barriers and staging
// traffic HALVED vs BM=64. LDS 69 KB -> 2 blocks/CU. Split-K NS parts.
// Grid 128*NS: xcd=bid&7 -> b=xcd>>1, khL=xcd&1; rest=bid>>3 -> khH,t.
// ---------------------------------------------------------------------------
__global__ __launch_bounds__(512, 2) void attn_mfma(
    const bf16* __restrict__ Qg, const bf16* __restrict__ Kg,
    const bf16* __restrict__ Vtg, float* __restrict__ Op,
    float* __restrict__ Mp, float* __restrict__ Lp, const int NS)
{
    const int bid = blockIdx.x;
    const int xcd = bid & 7;
    const int rest = bid >> 3;
    const int b   = xcd >> 1;
    const int khH = (NS == 4) ? (rest & 1) : 0;
    const int t   = 31 - ((NS == 4) ? (rest >> 1) : rest);   // 128-row tile id
    const int kh  = khH * 2 + (xcd & 1);
    const int rowBase = t * 128;
    const int tid = threadIdx.x;
    const int lane = tid & 63;
    const int w  = tid >> 6;             // wave 0..7: rows w*16..w*16+16
    const int quad = lane >> 4;
    const int l15  = lane & 15;

    __shared__ bf16 Kl[128 * STR];       // [key][dim]     18.0 KB
    __shared__ bf16 Vl[64 * VSTR];       // [vdim][key]    17.0 KB
    __shared__ bf16 Pl[128 * VSTR];      // [row][key]     34.0 KB; Q staging
    // total 69 KB -> 2 blocks/CU

    const bf16* Qb = Qg + ((size_t)b * S_LEN + rowBase) * DKV;
    const bf16* Kb = Kg + (size_t)b * S_LEN * DKV;
    const bf16* Vb = Vtg + (size_t)b * DKV * S_LEN;

    // stage Q tile (128x64) into Pl rows, load A-fragments once
    {
        const int qr = tid >> 2, qd = (tid & 3) * 16;
        *(uint4*)&Pl[qr * VSTR + qd]     = *(const uint4*)&Qb[qr * DKV + qd];
        *(uint4*)&Pl[qr * VSTR + qd + 8] = *(const uint4*)&Qb[qr * DKV + qd + 8];
    }
    __syncthreads();
    short8 qf0, qf1;
    {
        const int qoff = (w * 16 + l15) * VSTR + quad * 8;
        qf0 = *(const short8*)&Pl[qoff];
        qf1 = *(const short8*)&Pl[qoff + 32];
    }

    const short s1b = (short)0x3F80;     // bf16 1.0
    const short8 ones = {s1b, s1b, s1b, s1b, s1b, s1b, s1b, s1b};

    floatx4 acc[4];
    #pragma unroll
    for (int v = 0; v < 4; ++v) acc[v] = (floatx4){0.f, 0.f, 0.f, 0.f};
    floatx4 accl = {0.f, 0.f, 0.f, 0.f};
    float m_run[4];
    #pragma unroll
    for (int r = 0; r < 4; ++r) m_run[r] = -1e30f;

    const int kbMax = t;                 // (t*128+127)>>7
    const int kk = tid >> 2, dk = (tid & 3) * 16;   // K staging: 4 thr/row
    const int vd = tid >> 3, vk = (tid & 7) * 16;   // V staging: 8 thr/row

    uint4 kr0, kr1, vr0, vr1;
    int kb = kh;
    if (kb <= kbMax) {
        const uint4* ks = (const uint4*)&Kb[((size_t)(kb * 128 + kk)) * DKV + dk];
        kr0 = ks[0]; kr1 = ks[1];
        const uint4* vs = (const uint4*)&Vb[(size_t)vd * S_LEN + kb * 128 + vk];
        vr0 = vs[0]; vr1 = vs[1];
    }

    for (; kb <= kbMax; kb += NS) {
        __syncthreads();                 // all waves done reading Kl/Vl
        {
            uint4* kd = (uint4*)&Kl[kk * STR + dk];
            kd[0] = kr0; kd[1] = kr1;
            uint4* vdst = (uint4*)&Vl[vd * VSTR + vk];
            vdst[0] = vr0; vdst[1] = vr1;
        }
        __syncthreads();                 // staging visible
        if (kb + NS <= kbMax) {          // prefetch next tile under compute
            const uint4* ks = (const uint4*)&Kb[((size_t)((kb + NS) * 128 + kk)) * DKV + dk];
            kr0 = ks[0]; kr1 = ks[1];
            const uint4* vs = (const uint4*)&Vb[(size_t)vd * S_LEN + (kb + NS) * 128 + vk];
            vr0 = vs[0]; vr1 = vs[1];
        }

        // S = Q K^T (Q pre-scaled): eight 16x16 key-tiles per wave
        floatx4 s[8];
        #pragma unroll
        for (int jt = 0; jt < 8; ++jt) s[jt] = (floatx4){0.f, 0.f, 0.f, 0.f};
        {
            const int qk = quad * 8;
            #pragma unroll
            for (int jt = 0; jt < 8; ++jt) {
                const int kc = (jt * 16 + l15) * STR + qk;
                const short8 ba = *(const short8*)&Kl[kc];
                const short8 bb = *(const short8*)&Kl[kc + 32];
                s[jt] = MFMA(qf0, ba, s[jt]);
                s[jt] = MFMA(qf1, bb, s[jt]);
            }
        }
        if (kb == kbMax) {               // causal mask, uniform branch
            const int rowg = rowBase + w * 16 + quad * 4;
            #pragma unroll
            for (int jt = 0; jt < 8; ++jt) {
                const int kg = kb * 128 + jt * 16 + l15;
                #pragma unroll
                for (int r = 0; r < 4; ++r)
                    if (kg > rowg + r) s[jt][r] = -1e30f;
            }
        }
        // wave-private row max: in-thread tree + 16-lane butterfly
        float m4[4];
        #pragma unroll
        for (int r = 0; r < 4; ++r) {
            float mm = s[0][r];
            #pragma unroll
            for (int jt = 1; jt < 8; ++jt) mm = fmaxf(mm, s[jt][r]);
            m4[r] = mm;
        }
        #pragma unroll
        for (int off = 1; off < 16; off <<= 1) {
            #pragma unroll
            for (int r = 0; r < 4; ++r) m4[r] = fmaxf(m4[r], __shfl_xor(m4[r], off));
        }
        float alpha[4];
        #pragma unroll
        for (int r = 0; r < 4; ++r) {
            const float mnew = fmaxf(m_run[r], m4[r]);
            alpha[r] = exp2f(m_run[r] - mnew);   // -1e30 first iter -> 0
            m_run[r] = mnew;
        }
        // P = exp2(S - m); rescale accumulators; write P to wave-private rows
        #pragma unroll
        for (int r = 0; r < 4; ++r) {
            accl[r] *= alpha[r];
            #pragma unroll
            for (int v = 0; v < 4; ++v) acc[v][r] *= alpha[r];
            const int poff = (w * 16 + quad * 4 + r) * VSTR + l15;
            #pragma unroll
            for (int jt = 0; jt < 8; ++jt) {
                const float pp = exp2f(s[jt][r] - m_run[r]);
                Pl[poff + jt * 16] = __float2bfloat16(pp);
            }
        }
        // same-wave LDS RAW: drain writes; "memory" clobber orders the ds_reads
        asm volatile("s_waitcnt lgkmcnt(0)" ::: "memory");

        // O += P V (and l += P . 1 via constant ones B-frag)
        {
            const int pk = quad * 8;
            const int prow = (w * 16 + l15) * VSTR;
            short8 pa[4];
            #pragma unroll
            for (int c = 0; c < 4; ++c)
                pa[c] = *(const short8*)&Pl[prow + pk + c * 32];
            #pragma unroll
            for (int c = 0; c < 4; ++c) accl = MFMA(pa[c], ones, accl);
            #pragma unroll
            for (int v = 0; v < 4; ++v) {
                const int vrow = (v * 16 + l15) * VSTR;
                #pragma unroll
                for (int c = 0; c < 4; ++c) {
                    const short8 vb = *(const short8*)&Vl[vrow + pk + c * 32];
                    acc[v] = MFMA(pa[c], vb, acc[v]);
                }
            }
        }
    }
    // epilogue: store unnormalized O + per-row (m, l)
    #pragma unroll
    for (int r = 0; r < 4; ++r) {
        const int row = rowBase + w * 16 + quad * 4 + r;
        float* op = Op + (((size_t)kh * B_N + b) * S_LEN + row) * DKV + l15;
        #pragma unroll
        for (int v = 0; v < 4; ++v) op[v * 16] = acc[v][r];
    }
    if (l15 == 0) {
        #pragma unroll
        for (int r = 0; r < 4; ++r) {
            const int row = rowBase + w * 16 + quad * 4 + r;
            const size_t mi = ((size_t)kh * B_N + b) * S_LEN + row;
            Mp[mi] = m_run[r];
            Lp[mi] = accl[r];
        }
    }
}

// ---------------------------------------------------------------------------
// Kernel 3 (unified): fused split-K merge + output projection.
// fp32: 6-term hi/lo both operands, fp32 out; bf16: 4-term, bf16 out.
// 512 blocks x 32 rows, 512 threads = 8 waves (2 row-halves x 4 col-quarters).
// ---------------------------------------------------------------------------
#define PSTR 72
__global__ __launch_bounds__(512) void proj_mfma(
    const float* __restrict__ Op, const float* __restrict__ Mp,
    const float* __restrict__ Lp, const int NS,
    const bf16* __restrict__ WoFh, const bf16* __restrict__ WoFl,
    const float* __restrict__ ball2, void* __restrict__ out,
    const int* __restrict__ flag)
{
    __shared__ unsigned short Ah[32 * PSTR], Al[32 * PSTR];
    const int tid = threadIdx.x;
    const int rowBase = blockIdx.x * 32;
    const int f32 = *flag;

    {   // fused merge: 4 floats per thread (rr = tid>>4, dd = (tid&15)*4)
        const int rr = tid >> 4, dd = (tid & 15) * 4;
        const int row = rowBase + rr;
        const size_t part = (size_t)B_N * S_LEN;
        float m = -1e30f;
        #pragma unroll 4
        for (int i = 0; i < NS; ++i) m = fmaxf(m, Mp[i * part + row]);
        float denom = 0.f;
        float oacc[4] = {0.f, 0.f, 0.f, 0.f};
        #pragma unroll 4
        for (int i = 0; i < NS; ++i) {
            const float wi = exp2f(Mp[i * part + row] - m);
            denom += Lp[i * part + row] * wi;
            const float4 v = *(const float4*)&Op[(i * part + row) * DKV + dd];
            oacc[0] += v.x * wi; oacc[1] += v.y * wi;
            oacc[2] += v.z * wi; oacc[3] += v.w * wi;
        }
        const float inv = 1.0f / denom;
        union Pack4 { uint2 u; unsigned short s[4]; };
        Pack4 ph, pl;
        #pragma unroll
        for (int j = 0; j < 4; ++j) {
            const float o = oacc[j] * inv;
            ph.s[j] = f2bits(o);
            pl.s[j] = f2bits(o - bits2f(ph.s[j]));
        }
        *(uint2*)&Ah[rr * PSTR + dd] = ph.u;
        *(uint2*)&Al[rr * PSTR + dd] = pl.u;
    }
    __syncthreads();

    const int lane = tid & 63;
    const int w    = tid >> 6;           // 0..7
    const int quad = lane >> 4;
    const int l15  = lane & 15;
    const int wr   = w & 1;
    const int wcq  = w >> 1;             // 0..3 col quarter (128 cols)

    const int aoff = (wr * 16 + l15) * PSTR + quad * 8;
    const short8 ah0 = *(const short8*)&Ah[aoff];
    const short8 ah1 = *(const short8*)&Ah[aoff + 32];
    const short8 al0 = *(const short8*)&Al[aoff];
    const short8 al1 = *(const short8*)&Al[aoff + 32];

    floatx4 acc[8];
    #pragma unroll
    for (int ct = 0; ct < 8; ++ct) acc[ct] = (floatx4){0.f, 0.f, 0.f, 0.f};

    if (f32) {
        #pragma unroll
        for (int ct = 0; ct < 8; ++ct) {
            const int ctile = wcq * 8 + ct;
            const size_t o0 = (((size_t)ctile * 2 + 0) * 64 + lane) * 8;
            const size_t o1 = (((size_t)ctile * 2 + 1) * 64 + lane) * 8;
            const short8 bh0 = *(const short8*)&WoFh[o0];
            const short8 bh1 = *(const short8*)&WoFh[o1];
            const short8 bl0 = *(const short8*)&WoFl[o0];
            const short8 bl1 = *(const short8*)&WoFl[o1];
            acc[ct] = MFMA(ah0, bh0, acc[ct]);
            acc[ct] = MFMA(ah1, bh1, acc[ct]);
            acc[ct] = MFMA(ah0, bl0, acc[ct]);
            acc[ct] = MFMA(ah1, bl1, acc[ct]);
            acc[ct] = MFMA(al0, bh0, acc[ct]);
            acc[ct] = MFMA(al1, bh1, acc[ct]);
        }
        float* outf = (float*)out;
        #pragma unroll
        for (int ct = 0; ct < 8; ++ct) {
            const int col = wcq * 128 + ct * 16 + l15;
            const float bias = ball2[col];
            #pragma unroll
            for (int r = 0; r < 4; ++r) {
                const int row = rowBase + wr * 16 + quad * 4 + r;
                outf[(size_t)row * D_MODEL + col] = acc[ct][r] + bias;
            }
        }
    } else {
        #pragma unroll
        for (int ct = 0; ct < 8; ++ct) {
            const int ctile = wcq * 8 + ct;
            const size_t o0 = (((size_t)ctile * 2 + 0) * 64 + lane) * 8;
            const size_t o1 = (((size_t)ctile * 2 + 1) * 64 + lane) * 8;
            const short8 bh0 = *(const short8*)&WoFh[o0];
            const short8 bh1 = *(const short8*)&WoFh[o1];
            acc[ct] = MFMA(ah0, bh0, acc[ct]);
            acc[ct] = MFMA(ah1, bh1, acc[ct]);
            acc[ct] = MFMA(al0, bh0, acc[ct]);
            acc[ct] = MFMA(al1, bh1, acc[ct]);
        }
        bf16* outb = (bf16*)out;
        #pragma unroll
        for (int ct = 0; ct < 8; ++ct) {
            const int col = wcq * 128 + ct * 16 + l15;
            const float bias = ball2[col];
            #pragma unroll
            for (int r = 0; r < 4; ++r) {
                const int row = rowBase + wr * 16 + quad * 4 + r;
                outb[(size_t)row * D_MODEL + col] = __float2bfloat16(acc[ct][r] + bias);
            }
        }
    }
}

extern "C" void kernel_launch(void* const* d_in, const int* in_sizes, int n_in,
                              void* d_out, int out_size, void* d_ws, size_t ws_size,
                              hipStream_t stream) {
    const void* x  = d_in[0];
    const void* Wq = d_in[1];
    const void* bq = d_in[2];
    const void* Wk = d_in[3];
    const void* bk = d_in[4];
    const void* Wv = d_in[5];
    const void* bv = d_in[6];
    const void* Wo = d_in[7];
    const void* bo = d_in[8];

    const int rows = B_N * S_LEN;                 // 16384
    // split-K factor: 4 needs ~24 MB workspace; fall back to 2 if tight
    const int NS = (ws_size >= (size_t)30 * 1024 * 1024) ? 4 : 2;

    char* p = (char*)d_ws;
    int*  flag = (int*)p;                          p += 256;
    bf16* Qb = (bf16*)p;                           p += (size_t)rows * DKV * 2;   // 2 MB
    bf16* Kb = (bf16*)p;                           p += (size_t)rows * DKV * 2;
    bf16* Vt = (bf16*)p;                           p += (size_t)rows * DKV * 2;
    bf16* Wfh = (bf16*)p;                          p += (size_t)12 * 16 * 64 * 8 * 2;  // 196.6 KB
    bf16* Wfl = (bf16*)p;                          p += (size_t)12 * 16 * 64 * 8 * 2;
    float* ball = (float*)p;                       p += 1024;
    bf16* WoFh = (bf16*)p;                         p += (size_t)32 * 2 * 64 * 8 * 2;   // 64 KB
    bf16* WoFl = (bf16*)p;                         p += (size_t)32 * 2 * 64 * 8 * 2;
    float* ball2 = (float*)p;                      p += D_MODEL * 4;
    float* Op = (float*)p;                         p += (size_t)NS * rows * DKV * 4; // 8/16 MB
    float* Mp = (float*)p;                         p += (size_t)NS * rows * 4;
    float* Lp = (float*)p;                         p += (size_t)NS * rows * 4;

    detect_kernel<<<1, 64, 0, stream>>>(x, flag);
    wprep_kernel<<<44, 512, 0, stream>>>(Wq, bq, Wk, bk, Wv, bv, Wo, bo,
                                         Wfh, Wfl, ball, WoFh, WoFl, ball2, flag);
    qkv_mfma<<<512, 512, 0, stream>>>(x, Wfh, Wfl, ball, Qb, Kb, Vt, flag);
    attn_mfma<<<128 * NS, 512, 0, stream>>>(Qb, Kb, Vt, Op, Mp, Lp, NS);
    proj_mfma<<<512, 512, 0, stream>>>(Op, Mp, Lp, NS, WoFh, WoFl, ball2, d_out, flag);
}